// Round 11
// baseline (280.329 us; speedup 1.0000x reference)
//
#include <hip/hip_runtime.h>

// TemporalGNN: 2x TransformerConv(H=2, C=64) + edge encoder + fc head.
// Edge encoder is rank-1 (edge_attr is [E,1]): eh_l = ea[e]*u_l + c_l.
// Edge phase: stable counting-sort by dst; one wave per dst node, two 32-lane
// halves each own an edge stream; edge-encoder algebraically folded out.
// Layer-2 linears: pure-bf16 MFMA GEMM (A-lo dropped -- R10 showed the kernel
// is memory-bound, not precision-starved). One block loops over all 4 col
// quarters so the A panel is fetched from HBM once (R10 fetched it ~3x).

#define HC 128   // H*C

typedef __attribute__((ext_vector_type(8))) short bf16x8;
typedef __attribute__((ext_vector_type(4))) float f32x4;

__device__ __forceinline__ unsigned bf16_rne(float f) {
    unsigned u = __float_as_uint(f);
    return (u + 0x7fffu + ((u >> 16) & 1u)) >> 16;
}

// ---------- rank-1 edge-encoder precompute ----------
__global__ void k_uc(const float* __restrict__ We_enc, const float* __restrict__ be_enc,
                     const float* __restrict__ We1, const float* __restrict__ We2,
                     float* __restrict__ uc) {
    int c = threadIdx.x;  // 0..127
    float u1 = 0.f, c1 = 0.f, u2 = 0.f, c2 = 0.f;
    for (int j = 0; j < 64; ++j) {
        float we = We_enc[j], be = be_enc[j];
        float w1 = We1[j * HC + c], w2 = We2[j * HC + c];
        u1 += we * w1; c1 += be * w1;
        u2 += we * w2; c2 += be * w2;
    }
    uc[c] = u1; uc[HC + c] = c1; uc[2 * HC + c] = u2; uc[3 * HC + c] = c2;
}

// ---------- pack layer-2 weights to bf16, B^T layout [n=512][k=128] ----------
__global__ __launch_bounds__(256) void k_wpack(
    const float* __restrict__ Wq, const float* __restrict__ Wk,
    const float* __restrict__ Wv, const float* __restrict__ Ws,
    unsigned short* __restrict__ Bph) {
    int t = blockIdx.x * 256 + threadIdx.x;   // 0..65535
    int nn = t >> 7;        // 0..511
    int kk = t & 127;
    int mat = nn >> 7, c = nn & 127;
    const float* W = (mat == 0) ? Wq : (mat == 1) ? Wk : (mat == 2) ? Wv : Ws;
    Bph[nn * 128 + kk] = (unsigned short)bf16_rne(W[kk * 128 + c]);
}

// ---------- CSR build (stable counting sort by dst) ----------
__global__ __launch_bounds__(256) void k_hist(const int* __restrict__ ei, int* __restrict__ deg, int E) {
    int t = blockIdx.x * blockDim.x + threadIdx.x;
    if (t < E) atomicAdd(&deg[ei[E + t]], 1);
}

// 3-pass hierarchical exclusive scan: deg[n] -> rowptr[n+1].
__global__ __launch_bounds__(256) void k_scan1(const int* __restrict__ deg, int* __restrict__ bsum, int n) {
    int t = blockIdx.x * 256 + threadIdx.x;
    int v = (t < n) ? deg[t] : 0;
#pragma unroll
    for (int off = 1; off < 64; off <<= 1) v += __shfl_xor(v, off);
    __shared__ int wsum[4];
    int lane = threadIdx.x & 63, w = threadIdx.x >> 6;
    if (lane == 0) wsum[w] = v;
    __syncthreads();
    if (threadIdx.x == 0) bsum[blockIdx.x] = wsum[0] + wsum[1] + wsum[2] + wsum[3];
}

__global__ __launch_bounds__(256) void k_scan2(int* __restrict__ bsum, int nb) {
    __shared__ int sh[256];
    int t = threadIdx.x;
    int v = (t < nb) ? bsum[t] : 0;
    sh[t] = v;
    __syncthreads();
    for (int off = 1; off < 256; off <<= 1) {
        int x = (t >= off) ? sh[t - off] : 0;
        __syncthreads();
        sh[t] += x;
        __syncthreads();
    }
    if (t < nb) bsum[t] = sh[t] - v;   // exclusive
}

__global__ __launch_bounds__(256) void k_scan3(const int* __restrict__ deg, const int* __restrict__ bsum,
                                               int* __restrict__ rowptr, int n, int E) {
    int t = blockIdx.x * 256 + threadIdx.x;
    int tid = threadIdx.x;
    int v = (t < n) ? deg[t] : 0;
    __shared__ int sh[256];
    sh[tid] = v;
    __syncthreads();
    for (int off = 1; off < 256; off <<= 1) {
        int x = (tid >= off) ? sh[tid - off] : 0;
        __syncthreads();
        sh[tid] += x;
        __syncthreads();
    }
    if (t < n) rowptr[t] = bsum[blockIdx.x] + sh[tid] - v;
    if (t == 0) rowptr[n] = E;
}

__global__ __launch_bounds__(256) void k_scatter(const int* __restrict__ ei, const int* __restrict__ rowptr,
                                                 int* __restrict__ cursor, int* __restrict__ eid, int E) {
    int t = blockIdx.x * blockDim.x + threadIdx.x;
    if (t >= E) return;
    int dst = ei[E + t];
    int pos = rowptr[dst] + atomicAdd(&cursor[dst], 1);
    eid[pos] = t;
}

__global__ __launch_bounds__(256) void k_bsort(const int* __restrict__ rowptr, int* __restrict__ eid, int n) {
    int t = blockIdx.x * blockDim.x + threadIdx.x;
    if (t >= n) return;
    int b = rowptr[t], e = rowptr[t + 1];
    for (int i = b + 1; i < e; ++i) {
        int key = eid[i];
        int j = i - 1;
        while (j >= b && eid[j] > key) { eid[j + 1] = eid[j]; --j; }
        eid[j + 1] = key;
    }
}

__global__ __launch_bounds__(256) void k_gather(const int* __restrict__ eid, const int* __restrict__ ei,
                                                const float* __restrict__ ea,
                                                int* __restrict__ srcs, float* __restrict__ eas, int E) {
    int t = blockIdx.x * blockDim.x + threadIdx.x;
    if (t >= E) return;
    int id = eid[t];
    srcs[t] = ei[id];
    eas[t] = ea[id];
}

// ---------- layer-1 node linears (K=6, vector ALU) ----------
// q,o stored f32; k,v stored packed bf16 into interleaved kv rows [256 ushort].
__global__ __launch_bounds__(256) void k_lin6(
    const float* __restrict__ X, int n,
    const float* __restrict__ Wq, const float* __restrict__ bq,
    const float* __restrict__ Wk, const float* __restrict__ bk,
    const float* __restrict__ Wv, const float* __restrict__ bv,
    const float* __restrict__ Ws, const float* __restrict__ bs,
    float* __restrict__ q, unsigned short* __restrict__ kv,
    float* __restrict__ o) {
    __shared__ float xs[16][6];
    const int base = blockIdx.x * 16;
    const int tid = threadIdx.x;
    for (int i = tid; i < 16 * 6; i += 256) {
        int ni = base + i / 6;
        xs[i / 6][i % 6] = (ni < n) ? X[(size_t)ni * 6 + (i % 6)] : 0.f;
    }
    __syncthreads();
    const int c = tid & 127;
    const int m = tid >> 7;  // 0 -> (q,k), 1 -> (v,o)
    const float* WA = m ? Wv : Wq;
    const float* WB = m ? Ws : Wk;
    float accA[16], accB[16];
#pragma unroll
    for (int i = 0; i < 16; ++i) { accA[i] = 0.f; accB[i] = 0.f; }
    for (int j = 0; j < 6; ++j) {
        float w0 = WA[j * HC + c];
        float w1 = WB[j * HC + c];
#pragma unroll
        for (int i = 0; i < 16; ++i) {
            float xv = xs[i][j];
            accA[i] += xv * w0;
            accB[i] += xv * w1;
        }
    }
    if (m == 0) {
        const float bA = bq[c], bB = bk[c];
#pragma unroll
        for (int i = 0; i < 16; ++i) {
            int ni = base + i;
            if (ni < n) {
                q[(size_t)ni * HC + c] = accA[i] + bA;
                kv[(size_t)ni * 256 + c] = (unsigned short)bf16_rne(accB[i] + bB);
            }
        }
    } else {
        const float bA = bv[c], bB = bs[c];
#pragma unroll
        for (int i = 0; i < 16; ++i) {
            int ni = base + i;
            if (ni < n) {
                kv[(size_t)ni * 256 + 128 + c] = (unsigned short)bf16_rne(accA[i] + bA);
                o[(size_t)ni * HC + c] = accB[i] + bB;
            }
        }
    }
}

// ---------- layer-2 node linears: pure-bf16 MFMA GEMM, LDS-staged B ----------
// Grid (ceil(n/128)). One block loops over the 4 col quarters {q,k,v,s},
// staging each 32 KB B panel in turn; the block's A rows (32 KB bf16) are
// HBM-fetched once and L1/L2-hot for quarters 2-4.
__global__ __launch_bounds__(256, 4) void k_lin2(
    const unsigned short* __restrict__ hb, const unsigned short* __restrict__ Bph,
    const float* __restrict__ bq, const float* __restrict__ bk,
    const float* __restrict__ bv, const float* __restrict__ bs,
    float* __restrict__ q, unsigned short* __restrict__ kv,
    float* __restrict__ o, int n) {
    __shared__ unsigned short Bs[128][128];   // 32 KB
    const int tid = threadIdx.x;
    const int wid = tid >> 6, l = tid & 63;
    const int la = l & 15, lk = l >> 4;
    const int mb = blockIdx.x * 128;
    int nodeA0 = mb + wid * 32 + la;
    int nodeA1 = nodeA0 + 16;
    if (nodeA0 >= n) nodeA0 = n - 1;
    if (nodeA1 >= n) nodeA1 = n - 1;
    const int sw = (la & 7) << 3;
    const int crow0 = mb + wid * 32 + lk * 4;

    for (int cq = 0; cq < 4; ++cq) {
        if (cq) __syncthreads();   // protect previous quarter's LDS reads
        for (int i = tid; i < 128 * 16; i += 256) {
            int kk8 = i & 15;
            int nnl = i >> 4;
            bf16x8 val = *(const bf16x8*)&Bph[((size_t)(cq * 128 + nnl)) * 128 + kk8 * 8];
            int swk = (kk8 ^ (nnl & 7)) * 8;
            *(bf16x8*)&Bs[nnl][swk] = val;
        }
        __syncthreads();

        f32x4 acc0[8], acc1[8];
#pragma unroll
        for (int nt = 0; nt < 8; ++nt) {
            acc0[nt] = (f32x4){0.f, 0.f, 0.f, 0.f};
            acc1[nt] = (f32x4){0.f, 0.f, 0.f, 0.f};
        }
        bf16x8 a0[2], a1[2];
        a0[0] = *(const bf16x8*)&hb[(size_t)nodeA0 * 128 + lk * 8];
        a1[0] = *(const bf16x8*)&hb[(size_t)nodeA1 * 128 + lk * 8];
#pragma unroll
        for (int ks = 0; ks < 4; ++ks) {
            const int cur = ks & 1, nxt = cur ^ 1;
            if (ks < 3) {
                const int ko = lk * 8 + (ks + 1) * 32;
                a0[nxt] = *(const bf16x8*)&hb[(size_t)nodeA0 * 128 + ko];
                a1[nxt] = *(const bf16x8*)&hb[(size_t)nodeA1 * 128 + ko];
            }
            const int rk = (lk * 8 + ks * 32) ^ sw;
#pragma unroll
            for (int nt = 0; nt < 8; ++nt) {
                bf16x8 Bh = *(const bf16x8*)&Bs[nt * 16 + la][rk];
                acc0[nt] = __builtin_amdgcn_mfma_f32_16x16x32_bf16(a0[cur], Bh, acc0[nt], 0, 0, 0);
                acc1[nt] = __builtin_amdgcn_mfma_f32_16x16x32_bf16(a1[cur], Bh, acc1[nt], 0, 0, 0);
            }
        }
        const float* bias = (cq == 0) ? bq : (cq == 1) ? bk : (cq == 2) ? bv : bs;
#pragma unroll
        for (int nt = 0; nt < 8; ++nt) {
            const int col = nt * 16 + la;
            const float bb = bias[col];
            if (cq == 0 || cq == 3) {
                float* out = (cq == 0) ? q : o;
#pragma unroll
                for (int j = 0; j < 4; ++j) {
                    int n0 = crow0 + j;
                    if (n0 < n) out[(size_t)n0 * 128 + col] = acc0[nt][j] + bb;
                    int n1 = n0 + 16;
                    if (n1 < n) out[(size_t)n1 * 128 + col] = acc1[nt][j] + bb;
                }
            } else {
                const int co = (cq == 1) ? col : 128 + col;
#pragma unroll
                for (int j = 0; j < 4; ++j) {
                    int n0 = crow0 + j;
                    if (n0 < n) kv[(size_t)n0 * 256 + co] = (unsigned short)bf16_rne(acc0[nt][j] + bb);
                    int n1 = n0 + 16;
                    if (n1 < n) kv[(size_t)n1 * 256 + co] = (unsigned short)bf16_rne(acc1[nt][j] + bb);
                }
            }
        }
    }
}

// ---------- fused online-softmax attention, one wave per dst node ----------
// Wave = two 32-lane halves, each owning one edge stream (even/odd edges).
// Within a half: lanes 0-15 = head0, 16-31 = head1; lane holds 4 channels.
// Edge-encoder folded out: a = (q.k + ea*qu + qc)/8; V-side via sea.
// MODE 1: relu(attn+skip) -> single bf16 h. MODE 0: f32 into io.
template <int MODE>
__global__ __launch_bounds__(256) void k_attn(
    const float* __restrict__ q, const unsigned short* __restrict__ kvp,
    const int* __restrict__ rowptr, const int* __restrict__ srcs, const float* __restrict__ eas,
    const float* __restrict__ ucu, const float* __restrict__ ucc,
    float* __restrict__ io, unsigned short* __restrict__ hb, int n) {
    int wid = (int)((blockIdx.x * (size_t)blockDim.x + threadIdx.x) >> 6);
    int lane = threadIdx.x & 63;
    if (wid >= n) return;
    const int half = lane >> 5;       // edge stream (0=even edges, 1=odd)
    const int hl = lane & 31;
    const int ch = hl * 4;            // 4 channels; hl 0-15 head0, 16-31 head1

    float4 qr = *(const float4*)&q[(size_t)wid * 128 + ch];
    float4 uu = *(const float4*)&ucu[ch];
    float4 cc = *(const float4*)&ucc[ch];

    // per-head scalars qu = q.u, qc = q.c (reduced over the 16-lane head group)
    float qu = qr.x * uu.x + qr.y * uu.y + qr.z * uu.z + qr.w * uu.w;
    float qc = qr.x * cc.x + qr.y * cc.y + qr.z * cc.z + qr.w * cc.w;
#pragma unroll
    for (int off = 1; off < 16; off <<= 1) {
        qu += __shfl_xor(qu, off);
        qc += __shfl_xor(qc, off);
    }

    int b = rowptr[wid], e = rowptr[wid + 1];
    float m = -3.0e38f, s = 0.f, sea = 0.f;
    float av0 = 0.f, av1 = 0.f, av2 = 0.f, av3 = 0.f;

    if (b < e) {
        int pi = b + half;
        bool val = pi < e;
        int pc = val ? pi : e - 1;
        int src = srcs[pc];
        float eav = eas[pc];
        const unsigned short* row = &kvp[(size_t)src * 256 + ch];
        uint2 ku = *(const uint2*)row;
        uint2 vu = *(const uint2*)(row + 128);
        for (int p = b; p < e; p += 2) {
            // prefetch next pair
            int pn = p + 2 + half;
            bool valn = pn < e;
            int pcn = valn ? pn : e - 1;
            int srcn = srcs[pcn];
            float eavn = eas[pcn];
            const unsigned short* rown = &kvp[(size_t)srcn * 256 + ch];
            uint2 kun = *(const uint2*)rown;
            uint2 vun = *(const uint2*)(rown + 128);

            float k0 = __uint_as_float(ku.x << 16);
            float k1 = __uint_as_float(ku.x & 0xffff0000u);
            float k2 = __uint_as_float(ku.y << 16);
            float k3 = __uint_as_float(ku.y & 0xffff0000u);
            float d = qr.x * k0 + qr.y * k1 + qr.z * k2 + qr.w * k3;
#pragma unroll
            for (int off = 1; off < 16; off <<= 1) d += __shfl_xor(d, off);
            float a = val ? (d + fmaf(eav, qu, qc)) * 0.125f : -INFINITY;
            float nm = fmaxf(m, a);
            float sc = __expf(m - nm);
            float pw = __expf(a - nm);
            float v0 = __uint_as_float(vu.x << 16);
            float v1 = __uint_as_float(vu.x & 0xffff0000u);
            float v2 = __uint_as_float(vu.y << 16);
            float v3 = __uint_as_float(vu.y & 0xffff0000u);
            s = fmaf(s, sc, pw);
            sea = fmaf(sea, sc, pw * eav);
            av0 = fmaf(av0, sc, pw * v0);
            av1 = fmaf(av1, sc, pw * v1);
            av2 = fmaf(av2, sc, pw * v2);
            av3 = fmaf(av3, sc, pw * v3);
            m = nm;
            ku = kun; vu = vun; eav = eavn; val = valn;
        }
    }

    // merge the two edge streams (safe when one/both empty: m stays -3e38)
    {
        float om = __shfl_xor(m, 32);
        float os = __shfl_xor(s, 32);
        float osea = __shfl_xor(sea, 32);
        float o0 = __shfl_xor(av0, 32);
        float o1 = __shfl_xor(av1, 32);
        float o2 = __shfl_xor(av2, 32);
        float o3 = __shfl_xor(av3, 32);
        float nm = fmaxf(m, om);
        float scS = __expf(m - nm);
        float scO = __expf(om - nm);
        s = s * scS + os * scO;
        sea = sea * scS + osea * scO;
        av0 = av0 * scS + o0 * scO;
        av1 = av1 * scS + o1 * scO;
        av2 = av2 * scS + o2 * scO;
        av3 = av3 * scS + o3 * scO;
    }

    if (half == 0) {
        float inv = 1.f / (s + 1e-16f);
        float4 skip = *(const float4*)&io[(size_t)wid * 128 + ch];
        float r0 = (av0 + uu.x * sea + cc.x * s) * inv + skip.x;
        float r1 = (av1 + uu.y * sea + cc.y * s) * inv + skip.y;
        float r2 = (av2 + uu.z * sea + cc.z * s) * inv + skip.z;
        float r3 = (av3 + uu.w * sea + cc.w * s) * inv + skip.w;
        if (MODE == 1) {
            r0 = fmaxf(r0, 0.f); r1 = fmaxf(r1, 0.f);
            r2 = fmaxf(r2, 0.f); r3 = fmaxf(r3, 0.f);
            ushort4 hv = make_ushort4((unsigned short)bf16_rne(r0),
                                      (unsigned short)bf16_rne(r1),
                                      (unsigned short)bf16_rne(r2),
                                      (unsigned short)bf16_rne(r3));
            *(ushort4*)&hb[(size_t)wid * 128 + ch] = hv;
        } else {
            *(float4*)&io[(size_t)wid * 128 + ch] = make_float4(r0, r1, r2, r3);
        }
    }
}

// ---------- fc head (relu fused), one wave per node ----------
__global__ __launch_bounds__(256) void k_fc(
    const float* __restrict__ h, const float* __restrict__ Wfc,
    const float* __restrict__ bfc, float* __restrict__ out, int n) {
    int w = (int)((blockIdx.x * (size_t)blockDim.x + threadIdx.x) >> 6);
    int lane = threadIdx.x & 63;
    if (w >= n) return;
    const float2* h2 = (const float2*)h;
    const float2* w2 = (const float2*)Wfc;
    float2 hv = h2[(size_t)w * 64 + lane];
    float2 wv = w2[lane];
    float vsum = fmaxf(hv.x, 0.f) * wv.x + fmaxf(hv.y, 0.f) * wv.y;
#pragma unroll
    for (int off = 1; off < 64; off <<= 1) vsum += __shfl_xor(vsum, off);
    if (lane == 0) out[w] = vsum + bfc[0];
}

extern "C" void kernel_launch(void* const* d_in, const int* in_sizes, int n_in,
                              void* d_out, int out_size, void* d_ws, size_t ws_size,
                              hipStream_t stream) {
    const float* x      = (const float*)d_in[0];
    const int*   ei     = (const int*)d_in[1];
    const float* ea     = (const float*)d_in[2];
    const float* We_enc = (const float*)d_in[3];
    const float* be_enc = (const float*)d_in[4];
    const float* Wq1 = (const float*)d_in[5],  *bq1 = (const float*)d_in[6];
    const float* Wk1 = (const float*)d_in[7],  *bk1 = (const float*)d_in[8];
    const float* Wv1 = (const float*)d_in[9],  *bv1 = (const float*)d_in[10];
    const float* We1 = (const float*)d_in[11];
    const float* Ws1 = (const float*)d_in[12], *bs1 = (const float*)d_in[13];
    const float* Wq2 = (const float*)d_in[14], *bq2 = (const float*)d_in[15];
    const float* Wk2 = (const float*)d_in[16], *bk2 = (const float*)d_in[17];
    const float* Wv2 = (const float*)d_in[18], *bv2 = (const float*)d_in[19];
    const float* We2 = (const float*)d_in[20];
    const float* Ws2 = (const float*)d_in[21], *bs2 = (const float*)d_in[22];
    const float* Wfc = (const float*)d_in[23], *bfc = (const float*)d_in[24];

    const int n = in_sizes[0] / 6;   // 50000
    const int E = in_sizes[2];       // 409600

    float* ws = (float*)d_ws;
    size_t off = 0;
    float* qb = ws + off; off += (size_t)n * HC;
    float* Bb = ws + off; off += (size_t)n * HC;   // skip-init / h buffer
    unsigned short* kv16 = (unsigned short*)(ws + off); off += (size_t)n * HC;  // interleaved k|v bf16
    int* rowptr = (int*)(ws + off); off += (size_t)(n + 1);
    int* deg    = (int*)(ws + off); off += (size_t)n;   // also scatter cursor
    int* bsum   = (int*)(ws + off); off += 256;
    int* eid    = (int*)(ws + off); off += (size_t)E;
    int* srcs   = (int*)(ws + off); off += (size_t)E;
    float* eas  = ws + off; off += (size_t)E;
    float* uc   = ws + off; off += 512;
    unsigned short* hb16 = (unsigned short*)(ws + off); off += (size_t)n * HC / 2;  // h as bf16
    unsigned short* Bph = (unsigned short*)(ws + off); off += 512 * 128 / 2;

    const int eb = (E + 255) / 256;
    const int nb = (n + 255) / 256;
    const int wb = (int)(((size_t)n * 64 + 255) / 256);

    hipLaunchKernelGGL(k_uc, dim3(1), dim3(128), 0, stream, We_enc, be_enc, We1, We2, uc);
    hipLaunchKernelGGL(k_wpack, dim3(256), dim3(256), 0, stream, Wq2, Wk2, Wv2, Ws2, Bph);

    // ---- CSR build (shared by both layers) ----
    hipMemsetAsync(deg, 0, (size_t)n * sizeof(int), stream);
    hipLaunchKernelGGL(k_hist, dim3(eb), dim3(256), 0, stream, ei, deg, E);
    hipLaunchKernelGGL(k_scan1, dim3(nb), dim3(256), 0, stream, deg, bsum, n);
    hipLaunchKernelGGL(k_scan2, dim3(1), dim3(256), 0, stream, bsum, nb);
    hipLaunchKernelGGL(k_scan3, dim3(nb), dim3(256), 0, stream, deg, bsum, rowptr, n, E);
    hipMemsetAsync(deg, 0, (size_t)n * sizeof(int), stream);  // reuse as cursor
    hipLaunchKernelGGL(k_scatter, dim3(eb), dim3(256), 0, stream, ei, rowptr, deg, eid, E);
    hipLaunchKernelGGL(k_bsort, dim3(nb), dim3(256), 0, stream, rowptr, eid, n);
    hipLaunchKernelGGL(k_gather, dim3(eb), dim3(256), 0, stream, eid, ei, ea, srcs, eas, E);

    // ---- layer 1 ----
    hipLaunchKernelGGL(k_lin6, dim3((n + 15) / 16), dim3(256), 0, stream,
                       x, n, Wq1, bq1, Wk1, bk1, Wv1, bv1, Ws1, bs1, qb, kv16, Bb);
    hipLaunchKernelGGL((k_attn<1>), dim3(wb), dim3(256), 0, stream,
                       qb, kv16, rowptr, srcs, eas, uc, uc + HC, Bb, hb16, n);

    // ---- layer 2 (pure-bf16 MFMA GEMM; writes q f32, k/v bf16, skip into Bb) ----
    hipLaunchKernelGGL(k_lin2, dim3((n + 127) / 128), dim3(256), 0, stream,
                       hb16, Bph, bq2, bk2, bv2, bs2, qb, kv16, Bb, n);
    hipLaunchKernelGGL((k_attn<0>), dim3(wb), dim3(256), 0, stream,
                       qb, kv16, rowptr, srcs, eas, uc + 2 * HC, uc + 3 * HC, Bb,
                       (unsigned short*)nullptr, n);

    // ---- fc head ----
    hipLaunchKernelGGL(k_fc, dim3(wb), dim3(256), 0, stream, Bb, Wfc, bfc, (float*)d_out, n);
}

// Round 12
// 231.742 us; speedup vs baseline: 1.2097x; 1.2097x over previous
//
#include <hip/hip_runtime.h>

// TemporalGNN: 2x TransformerConv(H=2, C=64) + edge encoder + fc head.
// Edge encoder is rank-1 (edge_attr is [E,1]): eh_l = ea[e]*u_l + c_l.
// Edge phase: stable counting-sort by dst; one wave per dst node, two 32-lane
// halves each own an edge stream; edge-encoder algebraically folded out.
// Layer-2 linears: pure-bf16 MFMA GEMM; block = 64 nodes, loops over the 4
// col quarters with A held in registers (fetched from HBM once). R11's
// 128-node tile starved the machine (391 blocks -> 15% occupancy, 1.5 TB/s);
// 782 blocks restores ~3 blocks/CU while keeping the 1x A-fetch.

#define HC 128   // H*C

typedef __attribute__((ext_vector_type(8))) short bf16x8;
typedef __attribute__((ext_vector_type(4))) float f32x4;

__device__ __forceinline__ unsigned bf16_rne(float f) {
    unsigned u = __float_as_uint(f);
    return (u + 0x7fffu + ((u >> 16) & 1u)) >> 16;
}

// ---------- rank-1 edge-encoder precompute ----------
__global__ void k_uc(const float* __restrict__ We_enc, const float* __restrict__ be_enc,
                     const float* __restrict__ We1, const float* __restrict__ We2,
                     float* __restrict__ uc) {
    int c = threadIdx.x;  // 0..127
    float u1 = 0.f, c1 = 0.f, u2 = 0.f, c2 = 0.f;
    for (int j = 0; j < 64; ++j) {
        float we = We_enc[j], be = be_enc[j];
        float w1 = We1[j * HC + c], w2 = We2[j * HC + c];
        u1 += we * w1; c1 += be * w1;
        u2 += we * w2; c2 += be * w2;
    }
    uc[c] = u1; uc[HC + c] = c1; uc[2 * HC + c] = u2; uc[3 * HC + c] = c2;
}

// ---------- pack layer-2 weights to bf16, B^T layout [n=512][k=128] ----------
__global__ __launch_bounds__(256) void k_wpack(
    const float* __restrict__ Wq, const float* __restrict__ Wk,
    const float* __restrict__ Wv, const float* __restrict__ Ws,
    unsigned short* __restrict__ Bph) {
    int t = blockIdx.x * 256 + threadIdx.x;   // 0..65535
    int nn = t >> 7;        // 0..511
    int kk = t & 127;
    int mat = nn >> 7, c = nn & 127;
    const float* W = (mat == 0) ? Wq : (mat == 1) ? Wk : (mat == 2) ? Wv : Ws;
    Bph[nn * 128 + kk] = (unsigned short)bf16_rne(W[kk * 128 + c]);
}

// ---------- CSR build (stable counting sort by dst) ----------
__global__ __launch_bounds__(256) void k_hist(const int* __restrict__ ei, int* __restrict__ deg, int E) {
    int t = blockIdx.x * blockDim.x + threadIdx.x;
    if (t < E) atomicAdd(&deg[ei[E + t]], 1);
}

// 3-pass hierarchical exclusive scan: deg[n] -> rowptr[n+1].
__global__ __launch_bounds__(256) void k_scan1(const int* __restrict__ deg, int* __restrict__ bsum, int n) {
    int t = blockIdx.x * 256 + threadIdx.x;
    int v = (t < n) ? deg[t] : 0;
#pragma unroll
    for (int off = 1; off < 64; off <<= 1) v += __shfl_xor(v, off);
    __shared__ int wsum[4];
    int lane = threadIdx.x & 63, w = threadIdx.x >> 6;
    if (lane == 0) wsum[w] = v;
    __syncthreads();
    if (threadIdx.x == 0) bsum[blockIdx.x] = wsum[0] + wsum[1] + wsum[2] + wsum[3];
}

__global__ __launch_bounds__(256) void k_scan2(int* __restrict__ bsum, int nb) {
    __shared__ int sh[256];
    int t = threadIdx.x;
    int v = (t < nb) ? bsum[t] : 0;
    sh[t] = v;
    __syncthreads();
    for (int off = 1; off < 256; off <<= 1) {
        int x = (t >= off) ? sh[t - off] : 0;
        __syncthreads();
        sh[t] += x;
        __syncthreads();
    }
    if (t < nb) bsum[t] = sh[t] - v;   // exclusive
}

__global__ __launch_bounds__(256) void k_scan3(const int* __restrict__ deg, const int* __restrict__ bsum,
                                               int* __restrict__ rowptr, int n, int E) {
    int t = blockIdx.x * 256 + threadIdx.x;
    int tid = threadIdx.x;
    int v = (t < n) ? deg[t] : 0;
    __shared__ int sh[256];
    sh[tid] = v;
    __syncthreads();
    for (int off = 1; off < 256; off <<= 1) {
        int x = (tid >= off) ? sh[tid - off] : 0;
        __syncthreads();
        sh[tid] += x;
        __syncthreads();
    }
    if (t < n) rowptr[t] = bsum[blockIdx.x] + sh[tid] - v;
    if (t == 0) rowptr[n] = E;
}

__global__ __launch_bounds__(256) void k_scatter(const int* __restrict__ ei, const int* __restrict__ rowptr,
                                                 int* __restrict__ cursor, int* __restrict__ eid, int E) {
    int t = blockIdx.x * blockDim.x + threadIdx.x;
    if (t >= E) return;
    int dst = ei[E + t];
    int pos = rowptr[dst] + atomicAdd(&cursor[dst], 1);
    eid[pos] = t;
}

__global__ __launch_bounds__(256) void k_bsort(const int* __restrict__ rowptr, int* __restrict__ eid, int n) {
    int t = blockIdx.x * blockDim.x + threadIdx.x;
    if (t >= n) return;
    int b = rowptr[t], e = rowptr[t + 1];
    for (int i = b + 1; i < e; ++i) {
        int key = eid[i];
        int j = i - 1;
        while (j >= b && eid[j] > key) { eid[j + 1] = eid[j]; --j; }
        eid[j + 1] = key;
    }
}

__global__ __launch_bounds__(256) void k_gather(const int* __restrict__ eid, const int* __restrict__ ei,
                                                const float* __restrict__ ea,
                                                int* __restrict__ srcs, float* __restrict__ eas, int E) {
    int t = blockIdx.x * blockDim.x + threadIdx.x;
    if (t >= E) return;
    int id = eid[t];
    srcs[t] = ei[id];
    eas[t] = ea[id];
}

// ---------- layer-1 node linears (K=6, vector ALU) ----------
// q,o stored f32; k,v stored packed bf16 into interleaved kv rows [256 ushort].
__global__ __launch_bounds__(256) void k_lin6(
    const float* __restrict__ X, int n,
    const float* __restrict__ Wq, const float* __restrict__ bq,
    const float* __restrict__ Wk, const float* __restrict__ bk,
    const float* __restrict__ Wv, const float* __restrict__ bv,
    const float* __restrict__ Ws, const float* __restrict__ bs,
    float* __restrict__ q, unsigned short* __restrict__ kv,
    float* __restrict__ o) {
    __shared__ float xs[16][6];
    const int base = blockIdx.x * 16;
    const int tid = threadIdx.x;
    for (int i = tid; i < 16 * 6; i += 256) {
        int ni = base + i / 6;
        xs[i / 6][i % 6] = (ni < n) ? X[(size_t)ni * 6 + (i % 6)] : 0.f;
    }
    __syncthreads();
    const int c = tid & 127;
    const int m = tid >> 7;  // 0 -> (q,k), 1 -> (v,o)
    const float* WA = m ? Wv : Wq;
    const float* WB = m ? Ws : Wk;
    float accA[16], accB[16];
#pragma unroll
    for (int i = 0; i < 16; ++i) { accA[i] = 0.f; accB[i] = 0.f; }
    for (int j = 0; j < 6; ++j) {
        float w0 = WA[j * HC + c];
        float w1 = WB[j * HC + c];
#pragma unroll
        for (int i = 0; i < 16; ++i) {
            float xv = xs[i][j];
            accA[i] += xv * w0;
            accB[i] += xv * w1;
        }
    }
    if (m == 0) {
        const float bA = bq[c], bB = bk[c];
#pragma unroll
        for (int i = 0; i < 16; ++i) {
            int ni = base + i;
            if (ni < n) {
                q[(size_t)ni * HC + c] = accA[i] + bA;
                kv[(size_t)ni * 256 + c] = (unsigned short)bf16_rne(accB[i] + bB);
            }
        }
    } else {
        const float bA = bv[c], bB = bs[c];
#pragma unroll
        for (int i = 0; i < 16; ++i) {
            int ni = base + i;
            if (ni < n) {
                kv[(size_t)ni * 256 + 128 + c] = (unsigned short)bf16_rne(accA[i] + bA);
                o[(size_t)ni * HC + c] = accB[i] + bB;
            }
        }
    }
}

// ---------- layer-2 node linears: pure-bf16 MFMA GEMM, LDS-staged B ----------
// Grid (ceil(n/64)). Block = 64 nodes (4 waves x 16). A rows held in
// registers across the 4-quarter loop (HBM-fetched once); each quarter
// stages its 32 KB B panel in LDS.
__global__ __launch_bounds__(256, 4) void k_lin2(
    const unsigned short* __restrict__ hb, const unsigned short* __restrict__ Bph,
    const float* __restrict__ bq, const float* __restrict__ bk,
    const float* __restrict__ bv, const float* __restrict__ bs,
    float* __restrict__ q, unsigned short* __restrict__ kv,
    float* __restrict__ o, int n) {
    __shared__ unsigned short Bs[128][128];   // 32 KB
    const int tid = threadIdx.x;
    const int wid = tid >> 6, l = tid & 63;
    const int la = l & 15, lk = l >> 4;
    const int mb = blockIdx.x * 64;
    int nodeA = mb + wid * 16 + la;
    if (nodeA >= n) nodeA = n - 1;
    const int sw = (la & 7) << 3;
    const int crow0 = mb + wid * 16 + lk * 4;

    // A fragment in registers, loaded once for all 4 quarters
    bf16x8 areg[4];
#pragma unroll
    for (int ks = 0; ks < 4; ++ks)
        areg[ks] = *(const bf16x8*)&hb[(size_t)nodeA * 128 + lk * 8 + ks * 32];

    for (int cq = 0; cq < 4; ++cq) {
        if (cq) __syncthreads();   // protect previous quarter's LDS reads
        for (int i = tid; i < 128 * 16; i += 256) {
            int kk8 = i & 15;
            int nnl = i >> 4;
            bf16x8 val = *(const bf16x8*)&Bph[((size_t)(cq * 128 + nnl)) * 128 + kk8 * 8];
            int swk = (kk8 ^ (nnl & 7)) * 8;
            *(bf16x8*)&Bs[nnl][swk] = val;
        }
        __syncthreads();

        f32x4 acc[8];
#pragma unroll
        for (int nt = 0; nt < 8; ++nt) acc[nt] = (f32x4){0.f, 0.f, 0.f, 0.f};
#pragma unroll
        for (int ks = 0; ks < 4; ++ks) {
            const int rk = (lk * 8 + ks * 32) ^ sw;
#pragma unroll
            for (int nt = 0; nt < 8; ++nt) {
                bf16x8 Bh = *(const bf16x8*)&Bs[nt * 16 + la][rk];
                acc[nt] = __builtin_amdgcn_mfma_f32_16x16x32_bf16(areg[ks], Bh, acc[nt], 0, 0, 0);
            }
        }
        const float* bias = (cq == 0) ? bq : (cq == 1) ? bk : (cq == 2) ? bv : bs;
#pragma unroll
        for (int nt = 0; nt < 8; ++nt) {
            const int col = nt * 16 + la;
            const float bb = bias[col];
            if (cq == 0 || cq == 3) {
                float* out = (cq == 0) ? q : o;
#pragma unroll
                for (int j = 0; j < 4; ++j) {
                    int n0 = crow0 + j;
                    if (n0 < n) out[(size_t)n0 * 128 + col] = acc[nt][j] + bb;
                }
            } else {
                const int co = (cq == 1) ? col : 128 + col;
#pragma unroll
                for (int j = 0; j < 4; ++j) {
                    int n0 = crow0 + j;
                    if (n0 < n) kv[(size_t)n0 * 256 + co] = (unsigned short)bf16_rne(acc[nt][j] + bb);
                }
            }
        }
    }
}

// ---------- fused online-softmax attention, one wave per dst node ----------
// Wave = two 32-lane halves, each owning one edge stream (even/odd edges).
// Within a half: lanes 0-15 = head0, 16-31 = head1; lane holds 4 channels.
// Edge-encoder folded out: a = (q.k + ea*qu + qc)/8; V-side via sea.
// MODE 1: relu(attn+skip) -> single bf16 h. MODE 0: f32 into io.
template <int MODE>
__global__ __launch_bounds__(256) void k_attn(
    const float* __restrict__ q, const unsigned short* __restrict__ kvp,
    const int* __restrict__ rowptr, const int* __restrict__ srcs, const float* __restrict__ eas,
    const float* __restrict__ ucu, const float* __restrict__ ucc,
    float* __restrict__ io, unsigned short* __restrict__ hb, int n) {
    int wid = (int)((blockIdx.x * (size_t)blockDim.x + threadIdx.x) >> 6);
    int lane = threadIdx.x & 63;
    if (wid >= n) return;
    const int half = lane >> 5;       // edge stream (0=even edges, 1=odd)
    const int hl = lane & 31;
    const int ch = hl * 4;            // 4 channels; hl 0-15 head0, 16-31 head1

    float4 qr = *(const float4*)&q[(size_t)wid * 128 + ch];
    float4 uu = *(const float4*)&ucu[ch];
    float4 cc = *(const float4*)&ucc[ch];

    // per-head scalars qu = q.u, qc = q.c (reduced over the 16-lane head group)
    float qu = qr.x * uu.x + qr.y * uu.y + qr.z * uu.z + qr.w * uu.w;
    float qc = qr.x * cc.x + qr.y * cc.y + qr.z * cc.z + qr.w * cc.w;
#pragma unroll
    for (int off = 1; off < 16; off <<= 1) {
        qu += __shfl_xor(qu, off);
        qc += __shfl_xor(qc, off);
    }

    int b = rowptr[wid], e = rowptr[wid + 1];
    float m = -3.0e38f, s = 0.f, sea = 0.f;
    float av0 = 0.f, av1 = 0.f, av2 = 0.f, av3 = 0.f;

    if (b < e) {
        int pi = b + half;
        bool val = pi < e;
        int pc = val ? pi : e - 1;
        int src = srcs[pc];
        float eav = eas[pc];
        const unsigned short* row = &kvp[(size_t)src * 256 + ch];
        uint2 ku = *(const uint2*)row;
        uint2 vu = *(const uint2*)(row + 128);
        for (int p = b; p < e; p += 2) {
            // prefetch next pair
            int pn = p + 2 + half;
            bool valn = pn < e;
            int pcn = valn ? pn : e - 1;
            int srcn = srcs[pcn];
            float eavn = eas[pcn];
            const unsigned short* rown = &kvp[(size_t)srcn * 256 + ch];
            uint2 kun = *(const uint2*)rown;
            uint2 vun = *(const uint2*)(rown + 128);

            float k0 = __uint_as_float(ku.x << 16);
            float k1 = __uint_as_float(ku.x & 0xffff0000u);
            float k2 = __uint_as_float(ku.y << 16);
            float k3 = __uint_as_float(ku.y & 0xffff0000u);
            float d = qr.x * k0 + qr.y * k1 + qr.z * k2 + qr.w * k3;
#pragma unroll
            for (int off = 1; off < 16; off <<= 1) d += __shfl_xor(d, off);
            float a = val ? (d + fmaf(eav, qu, qc)) * 0.125f : -INFINITY;
            float nm = fmaxf(m, a);
            float sc = __expf(m - nm);
            float pw = __expf(a - nm);
            float v0 = __uint_as_float(vu.x << 16);
            float v1 = __uint_as_float(vu.x & 0xffff0000u);
            float v2 = __uint_as_float(vu.y << 16);
            float v3 = __uint_as_float(vu.y & 0xffff0000u);
            s = fmaf(s, sc, pw);
            sea = fmaf(sea, sc, pw * eav);
            av0 = fmaf(av0, sc, pw * v0);
            av1 = fmaf(av1, sc, pw * v1);
            av2 = fmaf(av2, sc, pw * v2);
            av3 = fmaf(av3, sc, pw * v3);
            m = nm;
            ku = kun; vu = vun; eav = eavn; val = valn;
        }
    }

    // merge the two edge streams (safe when one/both empty: m stays -3e38)
    {
        float om = __shfl_xor(m, 32);
        float os = __shfl_xor(s, 32);
        float osea = __shfl_xor(sea, 32);
        float o0 = __shfl_xor(av0, 32);
        float o1 = __shfl_xor(av1, 32);
        float o2 = __shfl_xor(av2, 32);
        float o3 = __shfl_xor(av3, 32);
        float nm = fmaxf(m, om);
        float scS = __expf(m - nm);
        float scO = __expf(om - nm);
        s = s * scS + os * scO;
        sea = sea * scS + osea * scO;
        av0 = av0 * scS + o0 * scO;
        av1 = av1 * scS + o1 * scO;
        av2 = av2 * scS + o2 * scO;
        av3 = av3 * scS + o3 * scO;
    }

    if (half == 0) {
        float inv = 1.f / (s + 1e-16f);
        float4 skip = *(const float4*)&io[(size_t)wid * 128 + ch];
        float r0 = (av0 + uu.x * sea + cc.x * s) * inv + skip.x;
        float r1 = (av1 + uu.y * sea + cc.y * s) * inv + skip.y;
        float r2 = (av2 + uu.z * sea + cc.z * s) * inv + skip.z;
        float r3 = (av3 + uu.w * sea + cc.w * s) * inv + skip.w;
        if (MODE == 1) {
            r0 = fmaxf(r0, 0.f); r1 = fmaxf(r1, 0.f);
            r2 = fmaxf(r2, 0.f); r3 = fmaxf(r3, 0.f);
            ushort4 hv = make_ushort4((unsigned short)bf16_rne(r0),
                                      (unsigned short)bf16_rne(r1),
                                      (unsigned short)bf16_rne(r2),
                                      (unsigned short)bf16_rne(r3));
            *(ushort4*)&hb[(size_t)wid * 128 + ch] = hv;
        } else {
            *(float4*)&io[(size_t)wid * 128 + ch] = make_float4(r0, r1, r2, r3);
        }
    }
}

// ---------- fc head (relu fused), one wave per node ----------
__global__ __launch_bounds__(256) void k_fc(
    const float* __restrict__ h, const float* __restrict__ Wfc,
    const float* __restrict__ bfc, float* __restrict__ out, int n) {
    int w = (int)((blockIdx.x * (size_t)blockDim.x + threadIdx.x) >> 6);
    int lane = threadIdx.x & 63;
    if (w >= n) return;
    const float2* h2 = (const float2*)h;
    const float2* w2 = (const float2*)Wfc;
    float2 hv = h2[(size_t)w * 64 + lane];
    float2 wv = w2[lane];
    float vsum = fmaxf(hv.x, 0.f) * wv.x + fmaxf(hv.y, 0.f) * wv.y;
#pragma unroll
    for (int off = 1; off < 64; off <<= 1) vsum += __shfl_xor(vsum, off);
    if (lane == 0) out[w] = vsum + bfc[0];
}

extern "C" void kernel_launch(void* const* d_in, const int* in_sizes, int n_in,
                              void* d_out, int out_size, void* d_ws, size_t ws_size,
                              hipStream_t stream) {
    const float* x      = (const float*)d_in[0];
    const int*   ei     = (const int*)d_in[1];
    const float* ea     = (const float*)d_in[2];
    const float* We_enc = (const float*)d_in[3];
    const float* be_enc = (const float*)d_in[4];
    const float* Wq1 = (const float*)d_in[5],  *bq1 = (const float*)d_in[6];
    const float* Wk1 = (const float*)d_in[7],  *bk1 = (const float*)d_in[8];
    const float* Wv1 = (const float*)d_in[9],  *bv1 = (const float*)d_in[10];
    const float* We1 = (const float*)d_in[11];
    const float* Ws1 = (const float*)d_in[12], *bs1 = (const float*)d_in[13];
    const float* Wq2 = (const float*)d_in[14], *bq2 = (const float*)d_in[15];
    const float* Wk2 = (const float*)d_in[16], *bk2 = (const float*)d_in[17];
    const float* Wv2 = (const float*)d_in[18], *bv2 = (const float*)d_in[19];
    const float* We2 = (const float*)d_in[20];
    const float* Ws2 = (const float*)d_in[21], *bs2 = (const float*)d_in[22];
    const float* Wfc = (const float*)d_in[23], *bfc = (const float*)d_in[24];

    const int n = in_sizes[0] / 6;   // 50000
    const int E = in_sizes[2];       // 409600

    float* ws = (float*)d_ws;
    size_t off = 0;
    float* qb = ws + off; off += (size_t)n * HC;
    float* Bb = ws + off; off += (size_t)n * HC;   // skip-init / h buffer
    unsigned short* kv16 = (unsigned short*)(ws + off); off += (size_t)n * HC;  // interleaved k|v bf16
    int* rowptr = (int*)(ws + off); off += (size_t)(n + 1);
    int* deg    = (int*)(ws + off); off += (size_t)n;   // also scatter cursor
    int* bsum   = (int*)(ws + off); off += 256;
    int* eid    = (int*)(ws + off); off += (size_t)E;
    int* srcs   = (int*)(ws + off); off += (size_t)E;
    float* eas  = ws + off; off += (size_t)E;
    float* uc   = ws + off; off += 512;
    unsigned short* hb16 = (unsigned short*)(ws + off); off += (size_t)n * HC / 2;  // h as bf16
    unsigned short* Bph = (unsigned short*)(ws + off); off += 512 * 128 / 2;

    const int eb = (E + 255) / 256;
    const int nb = (n + 255) / 256;
    const int wb = (int)(((size_t)n * 64 + 255) / 256);

    hipLaunchKernelGGL(k_uc, dim3(1), dim3(128), 0, stream, We_enc, be_enc, We1, We2, uc);
    hipLaunchKernelGGL(k_wpack, dim3(256), dim3(256), 0, stream, Wq2, Wk2, Wv2, Ws2, Bph);

    // ---- CSR build (shared by both layers) ----
    hipMemsetAsync(deg, 0, (size_t)n * sizeof(int), stream);
    hipLaunchKernelGGL(k_hist, dim3(eb), dim3(256), 0, stream, ei, deg, E);
    hipLaunchKernelGGL(k_scan1, dim3(nb), dim3(256), 0, stream, deg, bsum, n);
    hipLaunchKernelGGL(k_scan2, dim3(1), dim3(256), 0, stream, bsum, nb);
    hipLaunchKernelGGL(k_scan3, dim3(nb), dim3(256), 0, stream, deg, bsum, rowptr, n, E);
    hipMemsetAsync(deg, 0, (size_t)n * sizeof(int), stream);  // reuse as cursor
    hipLaunchKernelGGL(k_scatter, dim3(eb), dim3(256), 0, stream, ei, rowptr, deg, eid, E);
    hipLaunchKernelGGL(k_bsort, dim3(nb), dim3(256), 0, stream, rowptr, eid, n);
    hipLaunchKernelGGL(k_gather, dim3(eb), dim3(256), 0, stream, eid, ei, ea, srcs, eas, E);

    // ---- layer 1 ----
    hipLaunchKernelGGL(k_lin6, dim3((n + 15) / 16), dim3(256), 0, stream,
                       x, n, Wq1, bq1, Wk1, bk1, Wv1, bv1, Ws1, bs1, qb, kv16, Bb);
    hipLaunchKernelGGL((k_attn<1>), dim3(wb), dim3(256), 0, stream,
                       qb, kv16, rowptr, srcs, eas, uc, uc + HC, Bb, hb16, n);

    // ---- layer 2 (pure-bf16 MFMA GEMM; writes q f32, k/v bf16, skip into Bb) ----
    hipLaunchKernelGGL(k_lin2, dim3((n + 63) / 64), dim3(256), 0, stream,
                       hb16, Bph, bq2, bk2, bv2, bs2, qb, kv16, Bb, n);
    hipLaunchKernelGGL((k_attn<0>), dim3(wb), dim3(256), 0, stream,
                       qb, kv16, rowptr, srcs, eas, uc + 2 * HC, uc + 3 * HC, Bb,
                       (unsigned short*)nullptr, n);

    // ---- fc head ----
    hipLaunchKernelGGL(k_fc, dim3(wb), dim3(256), 0, stream, Bb, Wfc, bfc, (float*)d_out, n);
}

// Round 13
// 227.164 us; speedup vs baseline: 1.2340x; 1.0202x over previous
//
#include <hip/hip_runtime.h>

// TemporalGNN: 2x TransformerConv(H=2, C=64) + edge encoder + fc head.
// Edge encoder is rank-1 (edge_attr is [E,1]): eh_l = ea[e]*u_l + c_l.
// Edge phase: stable counting-sort by dst; one wave per dst node; 4 edge
// streams (2 per 32-lane half, in-register merge then cross-half shfl) for
// doubled ILP + 8 gather rows in flight. fc head fused into layer-2 attn.
// Layer-2 linears: pure-bf16 MFMA GEMM, 64-node blocks, A in registers
// across the 4 col-quarter loop (HBM-fetched once).

#define HC 128   // H*C

typedef __attribute__((ext_vector_type(8))) short bf16x8;
typedef __attribute__((ext_vector_type(4))) float f32x4;

__device__ __forceinline__ unsigned bf16_rne(float f) {
    unsigned u = __float_as_uint(f);
    return (u + 0x7fffu + ((u >> 16) & 1u)) >> 16;
}

// ---------- rank-1 edge-encoder precompute ----------
__global__ void k_uc(const float* __restrict__ We_enc, const float* __restrict__ be_enc,
                     const float* __restrict__ We1, const float* __restrict__ We2,
                     float* __restrict__ uc) {
    int c = threadIdx.x;  // 0..127
    float u1 = 0.f, c1 = 0.f, u2 = 0.f, c2 = 0.f;
    for (int j = 0; j < 64; ++j) {
        float we = We_enc[j], be = be_enc[j];
        float w1 = We1[j * HC + c], w2 = We2[j * HC + c];
        u1 += we * w1; c1 += be * w1;
        u2 += we * w2; c2 += be * w2;
    }
    uc[c] = u1; uc[HC + c] = c1; uc[2 * HC + c] = u2; uc[3 * HC + c] = c2;
}

// ---------- pack layer-2 weights to bf16, B^T layout [n=512][k=128] ----------
__global__ __launch_bounds__(256) void k_wpack(
    const float* __restrict__ Wq, const float* __restrict__ Wk,
    const float* __restrict__ Wv, const float* __restrict__ Ws,
    unsigned short* __restrict__ Bph) {
    int t = blockIdx.x * 256 + threadIdx.x;   // 0..65535
    int nn = t >> 7;        // 0..511
    int kk = t & 127;
    int mat = nn >> 7, c = nn & 127;
    const float* W = (mat == 0) ? Wq : (mat == 1) ? Wk : (mat == 2) ? Wv : Ws;
    Bph[nn * 128 + kk] = (unsigned short)bf16_rne(W[kk * 128 + c]);
}

// ---------- CSR build (stable counting sort by dst) ----------
__global__ __launch_bounds__(256) void k_hist(const int* __restrict__ ei, int* __restrict__ deg, int E) {
    int t = blockIdx.x * blockDim.x + threadIdx.x;
    if (t < E) atomicAdd(&deg[ei[E + t]], 1);
}

// 3-pass hierarchical exclusive scan: deg[n] -> rowptr[n+1].
__global__ __launch_bounds__(256) void k_scan1(const int* __restrict__ deg, int* __restrict__ bsum, int n) {
    int t = blockIdx.x * 256 + threadIdx.x;
    int v = (t < n) ? deg[t] : 0;
#pragma unroll
    for (int off = 1; off < 64; off <<= 1) v += __shfl_xor(v, off);
    __shared__ int wsum[4];
    int lane = threadIdx.x & 63, w = threadIdx.x >> 6;
    if (lane == 0) wsum[w] = v;
    __syncthreads();
    if (threadIdx.x == 0) bsum[blockIdx.x] = wsum[0] + wsum[1] + wsum[2] + wsum[3];
}

__global__ __launch_bounds__(256) void k_scan2(int* __restrict__ bsum, int nb) {
    __shared__ int sh[256];
    int t = threadIdx.x;
    int v = (t < nb) ? bsum[t] : 0;
    sh[t] = v;
    __syncthreads();
    for (int off = 1; off < 256; off <<= 1) {
        int x = (t >= off) ? sh[t - off] : 0;
        __syncthreads();
        sh[t] += x;
        __syncthreads();
    }
    if (t < nb) bsum[t] = sh[t] - v;   // exclusive
}

// scan3 also zeroes deg (reused as the scatter cursor) -- saves a memset.
__global__ __launch_bounds__(256) void k_scan3(int* __restrict__ deg, const int* __restrict__ bsum,
                                               int* __restrict__ rowptr, int n, int E) {
    int t = blockIdx.x * 256 + threadIdx.x;
    int tid = threadIdx.x;
    int v = (t < n) ? deg[t] : 0;
    __shared__ int sh[256];
    sh[tid] = v;
    __syncthreads();
    for (int off = 1; off < 256; off <<= 1) {
        int x = (tid >= off) ? sh[tid - off] : 0;
        __syncthreads();
        sh[tid] += x;
        __syncthreads();
    }
    if (t < n) { rowptr[t] = bsum[blockIdx.x] + sh[tid] - v; deg[t] = 0; }
    if (t == 0) rowptr[n] = E;
}

__global__ __launch_bounds__(256) void k_scatter(const int* __restrict__ ei, const int* __restrict__ rowptr,
                                                 int* __restrict__ cursor, int* __restrict__ eid, int E) {
    int t = blockIdx.x * blockDim.x + threadIdx.x;
    if (t >= E) return;
    int dst = ei[E + t];
    int pos = rowptr[dst] + atomicAdd(&cursor[dst], 1);
    eid[pos] = t;
}

// per-bucket insertion sort by edge id (stable) + fused srcs/eas gather.
__global__ __launch_bounds__(256) void k_bsortg(
    const int* __restrict__ rowptr, int* __restrict__ eid,
    const int* __restrict__ ei, const float* __restrict__ ea,
    int* __restrict__ srcs, float* __restrict__ eas, int n) {
    int t = blockIdx.x * blockDim.x + threadIdx.x;
    if (t >= n) return;
    int b = rowptr[t], e = rowptr[t + 1];
    for (int i = b + 1; i < e; ++i) {
        int key = eid[i];
        int j = i - 1;
        while (j >= b && eid[j] > key) { eid[j + 1] = eid[j]; --j; }
        eid[j + 1] = key;
    }
    for (int i = b; i < e; ++i) {
        int id = eid[i];
        srcs[i] = ei[id];
        eas[i] = ea[id];
    }
}

// ---------- layer-1 node linears (K=6, vector ALU) ----------
// q,o stored f32; k,v stored packed bf16 into interleaved kv rows [256 ushort].
__global__ __launch_bounds__(256) void k_lin6(
    const float* __restrict__ X, int n,
    const float* __restrict__ Wq, const float* __restrict__ bq,
    const float* __restrict__ Wk, const float* __restrict__ bk,
    const float* __restrict__ Wv, const float* __restrict__ bv,
    const float* __restrict__ Ws, const float* __restrict__ bs,
    float* __restrict__ q, unsigned short* __restrict__ kv,
    float* __restrict__ o) {
    __shared__ float xs[16][6];
    const int base = blockIdx.x * 16;
    const int tid = threadIdx.x;
    for (int i = tid; i < 16 * 6; i += 256) {
        int ni = base + i / 6;
        xs[i / 6][i % 6] = (ni < n) ? X[(size_t)ni * 6 + (i % 6)] : 0.f;
    }
    __syncthreads();
    const int c = tid & 127;
    const int m = tid >> 7;  // 0 -> (q,k), 1 -> (v,o)
    const float* WA = m ? Wv : Wq;
    const float* WB = m ? Ws : Wk;
    float accA[16], accB[16];
#pragma unroll
    for (int i = 0; i < 16; ++i) { accA[i] = 0.f; accB[i] = 0.f; }
    for (int j = 0; j < 6; ++j) {
        float w0 = WA[j * HC + c];
        float w1 = WB[j * HC + c];
#pragma unroll
        for (int i = 0; i < 16; ++i) {
            float xv = xs[i][j];
            accA[i] += xv * w0;
            accB[i] += xv * w1;
        }
    }
    if (m == 0) {
        const float bA = bq[c], bB = bk[c];
#pragma unroll
        for (int i = 0; i < 16; ++i) {
            int ni = base + i;
            if (ni < n) {
                q[(size_t)ni * HC + c] = accA[i] + bA;
                kv[(size_t)ni * 256 + c] = (unsigned short)bf16_rne(accB[i] + bB);
            }
        }
    } else {
        const float bA = bv[c], bB = bs[c];
#pragma unroll
        for (int i = 0; i < 16; ++i) {
            int ni = base + i;
            if (ni < n) {
                kv[(size_t)ni * 256 + 128 + c] = (unsigned short)bf16_rne(accA[i] + bA);
                o[(size_t)ni * HC + c] = accB[i] + bB;
            }
        }
    }
}

// ---------- layer-2 node linears: pure-bf16 MFMA GEMM, LDS-staged B ----------
__global__ __launch_bounds__(256, 4) void k_lin2(
    const unsigned short* __restrict__ hb, const unsigned short* __restrict__ Bph,
    const float* __restrict__ bq, const float* __restrict__ bk,
    const float* __restrict__ bv, const float* __restrict__ bs,
    float* __restrict__ q, unsigned short* __restrict__ kv,
    float* __restrict__ o, int n) {
    __shared__ unsigned short Bs[128][128];   // 32 KB
    const int tid = threadIdx.x;
    const int wid = tid >> 6, l = tid & 63;
    const int la = l & 15, lk = l >> 4;
    const int mb = blockIdx.x * 64;
    int nodeA = mb + wid * 16 + la;
    if (nodeA >= n) nodeA = n - 1;
    const int sw = (la & 7) << 3;
    const int crow0 = mb + wid * 16 + lk * 4;

    bf16x8 areg[4];
#pragma unroll
    for (int ks = 0; ks < 4; ++ks)
        areg[ks] = *(const bf16x8*)&hb[(size_t)nodeA * 128 + lk * 8 + ks * 32];

    for (int cq = 0; cq < 4; ++cq) {
        if (cq) __syncthreads();
        for (int i = tid; i < 128 * 16; i += 256) {
            int kk8 = i & 15;
            int nnl = i >> 4;
            bf16x8 val = *(const bf16x8*)&Bph[((size_t)(cq * 128 + nnl)) * 128 + kk8 * 8];
            int swk = (kk8 ^ (nnl & 7)) * 8;
            *(bf16x8*)&Bs[nnl][swk] = val;
        }
        __syncthreads();

        f32x4 acc[8];
#pragma unroll
        for (int nt = 0; nt < 8; ++nt) acc[nt] = (f32x4){0.f, 0.f, 0.f, 0.f};
#pragma unroll
        for (int ks = 0; ks < 4; ++ks) {
            const int rk = (lk * 8 + ks * 32) ^ sw;
#pragma unroll
            for (int nt = 0; nt < 8; ++nt) {
                bf16x8 Bh = *(const bf16x8*)&Bs[nt * 16 + la][rk];
                acc[nt] = __builtin_amdgcn_mfma_f32_16x16x32_bf16(areg[ks], Bh, acc[nt], 0, 0, 0);
            }
        }
        const float* bias = (cq == 0) ? bq : (cq == 1) ? bk : (cq == 2) ? bv : bs;
#pragma unroll
        for (int nt = 0; nt < 8; ++nt) {
            const int col = nt * 16 + la;
            const float bb = bias[col];
            if (cq == 0 || cq == 3) {
                float* out = (cq == 0) ? q : o;
#pragma unroll
                for (int j = 0; j < 4; ++j) {
                    int n0 = crow0 + j;
                    if (n0 < n) out[(size_t)n0 * 128 + col] = acc[nt][j] + bb;
                }
            } else {
                const int co = (cq == 1) ? col : 128 + col;
#pragma unroll
                for (int j = 0; j < 4; ++j) {
                    int n0 = crow0 + j;
                    if (n0 < n) kv[(size_t)n0 * 256 + co] = (unsigned short)bf16_rne(acc[nt][j] + bb);
                }
            }
        }
    }
}

// ---------- fused online-softmax attention, one wave per dst node ----------
// Wave = two 32-lane halves; each half owns TWO edge streams (4 total):
// stream (half,s) takes edges b + 4t + 2s + half. In-register merge of the
// half's two streams, then cross-half shfl merge.
// Lane = 4 channels (hl 0-15 head0, 16-31 head1).
// Edge-encoder folded out: a = (q.k + ea*qu + qc)/8; V-side via sea.
// MODE 1: relu(attn+skip) -> bf16 h. MODE 0: fc head fused, writes out[wid].
#define UPD(mS, sS, seaS, a0S, a1S, a2S, a3S, kuS, vuS, eaS, vS)          \
    do {                                                                  \
        float k0 = __uint_as_float((kuS).x << 16);                        \
        float k1 = __uint_as_float((kuS).x & 0xffff0000u);                \
        float k2 = __uint_as_float((kuS).y << 16);                        \
        float k3 = __uint_as_float((kuS).y & 0xffff0000u);                \
        float d = qr.x * k0 + qr.y * k1 + qr.z * k2 + qr.w * k3;          \
        d += __shfl_xor(d, 1); d += __shfl_xor(d, 2);                     \
        d += __shfl_xor(d, 4); d += __shfl_xor(d, 8);                     \
        float a = (vS) ? (d + fmaf(eaS, qu, qc)) * 0.125f : -INFINITY;    \
        float nm = fmaxf(mS, a);                                          \
        float sc = __expf(mS - nm);                                       \
        float pw = __expf(a - nm);                                        \
        float v0 = __uint_as_float((vuS).x << 16);                        \
        float v1 = __uint_as_float((vuS).x & 0xffff0000u);                \
        float v2 = __uint_as_float((vuS).y << 16);                        \
        float v3 = __uint_as_float((vuS).y & 0xffff0000u);                \
        sS = fmaf(sS, sc, pw);                                            \
        seaS = fmaf(seaS, sc, pw * (eaS));                                \
        a0S = fmaf(a0S, sc, pw * v0);                                     \
        a1S = fmaf(a1S, sc, pw * v1);                                     \
        a2S = fmaf(a2S, sc, pw * v2);                                     \
        a3S = fmaf(a3S, sc, pw * v3);                                     \
        mS = nm;                                                          \
    } while (0)

template <int MODE>
__global__ __launch_bounds__(256) void k_attn(
    const float* __restrict__ q, const unsigned short* __restrict__ kvp,
    const int* __restrict__ rowptr, const int* __restrict__ srcs, const float* __restrict__ eas,
    const float* __restrict__ ucu, const float* __restrict__ ucc,
    const float* __restrict__ io, unsigned short* __restrict__ hb,
    const float* __restrict__ Wfc, const float* __restrict__ bfc,
    float* __restrict__ out, int n) {
    int wid = (int)((blockIdx.x * (size_t)blockDim.x + threadIdx.x) >> 6);
    int lane = threadIdx.x & 63;
    if (wid >= n) return;
    const int half = lane >> 5;
    const int hl = lane & 31;
    const int ch = hl * 4;

    float4 qr = *(const float4*)&q[(size_t)wid * 128 + ch];
    float4 uu = *(const float4*)&ucu[ch];
    float4 cc = *(const float4*)&ucc[ch];

    // per-head scalars (16-lane head-group reduce; note QK dot reduce below
    // uses masks 1,2,4,8 which stay inside the 16-lane head group)
    float qu = qr.x * uu.x + qr.y * uu.y + qr.z * uu.z + qr.w * uu.w;
    float qc = qr.x * cc.x + qr.y * cc.y + qr.z * cc.z + qr.w * cc.w;
#pragma unroll
    for (int off = 1; off < 16; off <<= 1) {
        qu += __shfl_xor(qu, off);
        qc += __shfl_xor(qc, off);
    }

    int b = rowptr[wid], e = rowptr[wid + 1];
    float mX = -3.0e38f, sX = 0.f, seaX = 0.f, aX0 = 0.f, aX1 = 0.f, aX2 = 0.f, aX3 = 0.f;
    float mY = -3.0e38f, sY = 0.f, seaY = 0.f, aY0 = 0.f, aY1 = 0.f, aY2 = 0.f, aY3 = 0.f;

    if (b < e) {
        int pX = b + half;       bool vX = pX < e; int cX = vX ? pX : e - 1;
        int pY = b + 2 + half;   bool vY = pY < e; int cY = vY ? pY : e - 1;
        int sx = srcs[cX], sy = srcs[cY];
        float eaX = eas[cX], eaY = eas[cY];
        const unsigned short* rX = &kvp[(size_t)sx * 256 + ch];
        const unsigned short* rY = &kvp[(size_t)sy * 256 + ch];
        uint2 kuX = *(const uint2*)rX, vuX = *(const uint2*)(rX + 128);
        uint2 kuY = *(const uint2*)rY, vuY = *(const uint2*)(rY + 128);
        for (int p = b; p < e; p += 4) {
            // prefetch iteration p+4
            int pXn = p + 4 + half;  bool vXn = pXn < e; int cXn = vXn ? pXn : e - 1;
            int pYn = p + 6 + half;  bool vYn = pYn < e; int cYn = vYn ? pYn : e - 1;
            int sxn = srcs[cXn], syn = srcs[cYn];
            float eaXn = eas[cXn], eaYn = eas[cYn];
            const unsigned short* rXn = &kvp[(size_t)sxn * 256 + ch];
            const unsigned short* rYn = &kvp[(size_t)syn * 256 + ch];
            uint2 kuXn = *(const uint2*)rXn, vuXn = *(const uint2*)(rXn + 128);
            uint2 kuYn = *(const uint2*)rYn, vuYn = *(const uint2*)(rYn + 128);

            UPD(mX, sX, seaX, aX0, aX1, aX2, aX3, kuX, vuX, eaX, vX);
            UPD(mY, sY, seaY, aY0, aY1, aY2, aY3, kuY, vuY, eaY, vY);

            kuX = kuXn; vuX = vuXn; eaX = eaXn; vX = vXn;
            kuY = kuYn; vuY = vuYn; eaY = eaYn; vY = vYn;
        }
    }

    // merge Y into X (in-register)
    {
        float nm = fmaxf(mX, mY);
        float scX = __expf(mX - nm);
        float scY = __expf(mY - nm);
        sX = sX * scX + sY * scY;
        seaX = seaX * scX + seaY * scY;
        aX0 = aX0 * scX + aY0 * scY;
        aX1 = aX1 * scX + aY1 * scY;
        aX2 = aX2 * scX + aY2 * scY;
        aX3 = aX3 * scX + aY3 * scY;
        mX = nm;
    }
    // cross-half merge
    {
        float om = __shfl_xor(mX, 32);
        float os = __shfl_xor(sX, 32);
        float osea = __shfl_xor(seaX, 32);
        float o0 = __shfl_xor(aX0, 32);
        float o1 = __shfl_xor(aX1, 32);
        float o2 = __shfl_xor(aX2, 32);
        float o3 = __shfl_xor(aX3, 32);
        float nm = fmaxf(mX, om);
        float scS = __expf(mX - nm);
        float scO = __expf(om - nm);
        sX = sX * scS + os * scO;
        seaX = seaX * scS + osea * scO;
        aX0 = aX0 * scS + o0 * scO;
        aX1 = aX1 * scS + o1 * scO;
        aX2 = aX2 * scS + o2 * scO;
        aX3 = aX3 * scS + o3 * scO;
    }

    float inv = 1.f / (sX + 1e-16f);
    float4 skip = *(const float4*)&io[(size_t)wid * 128 + ch];
    float r0 = (aX0 + uu.x * seaX + cc.x * sX) * inv + skip.x;
    float r1 = (aX1 + uu.y * seaX + cc.y * sX) * inv + skip.y;
    float r2 = (aX2 + uu.z * seaX + cc.z * sX) * inv + skip.z;
    float r3 = (aX3 + uu.w * seaX + cc.w * sX) * inv + skip.w;
    r0 = fmaxf(r0, 0.f); r1 = fmaxf(r1, 0.f);
    r2 = fmaxf(r2, 0.f); r3 = fmaxf(r3, 0.f);

    if (MODE == 1) {
        if (half == 0) {
            ushort4 hv = make_ushort4((unsigned short)bf16_rne(r0),
                                      (unsigned short)bf16_rne(r1),
                                      (unsigned short)bf16_rne(r2),
                                      (unsigned short)bf16_rne(r3));
            *(ushort4*)&hb[(size_t)wid * 128 + ch] = hv;
        }
    } else {
        // fused fc head: out[wid] = relu(h) . Wfc + bfc
        float4 wf = *(const float4*)&Wfc[ch];
        float rr = r0 * wf.x + r1 * wf.y + r2 * wf.z + r3 * wf.w;
#pragma unroll
        for (int off = 1; off < 32; off <<= 1) rr += __shfl_xor(rr, off);
        if (lane == 0) out[wid] = rr + bfc[0];
    }
}

extern "C" void kernel_launch(void* const* d_in, const int* in_sizes, int n_in,
                              void* d_out, int out_size, void* d_ws, size_t ws_size,
                              hipStream_t stream) {
    const float* x      = (const float*)d_in[0];
    const int*   ei     = (const int*)d_in[1];
    const float* ea     = (const float*)d_in[2];
    const float* We_enc = (const float*)d_in[3];
    const float* be_enc = (const float*)d_in[4];
    const float* Wq1 = (const float*)d_in[5],  *bq1 = (const float*)d_in[6];
    const float* Wk1 = (const float*)d_in[7],  *bk1 = (const float*)d_in[8];
    const float* Wv1 = (const float*)d_in[9],  *bv1 = (const float*)d_in[10];
    const float* We1 = (const float*)d_in[11];
    const float* Ws1 = (const float*)d_in[12], *bs1 = (const float*)d_in[13];
    const float* Wq2 = (const float*)d_in[14], *bq2 = (const float*)d_in[15];
    const float* Wk2 = (const float*)d_in[16], *bk2 = (const float*)d_in[17];
    const float* Wv2 = (const float*)d_in[18], *bv2 = (const float*)d_in[19];
    const float* We2 = (const float*)d_in[20];
    const float* Ws2 = (const float*)d_in[21], *bs2 = (const float*)d_in[22];
    const float* Wfc = (const float*)d_in[23], *bfc = (const float*)d_in[24];

    const int n = in_sizes[0] / 6;   // 50000
    const int E = in_sizes[2];       // 409600

    float* ws = (float*)d_ws;
    size_t off = 0;
    float* qb = ws + off; off += (size_t)n * HC;
    float* Bb = ws + off; off += (size_t)n * HC;   // skip buffer
    unsigned short* kv16 = (unsigned short*)(ws + off); off += (size_t)n * HC;  // interleaved k|v bf16
    int* rowptr = (int*)(ws + off); off += (size_t)(n + 1);
    int* deg    = (int*)(ws + off); off += (size_t)n;   // also scatter cursor
    int* bsum   = (int*)(ws + off); off += 256;
    int* eid    = (int*)(ws + off); off += (size_t)E;
    int* srcs   = (int*)(ws + off); off += (size_t)E;
    float* eas  = ws + off; off += (size_t)E;
    float* uc   = ws + off; off += 512;
    unsigned short* hb16 = (unsigned short*)(ws + off); off += (size_t)n * HC / 2;  // h as bf16
    unsigned short* Bph = (unsigned short*)(ws + off); off += 512 * 128 / 2;

    const int eb = (E + 255) / 256;
    const int nb = (n + 255) / 256;
    const int wb = (int)(((size_t)n * 64 + 255) / 256);

    hipLaunchKernelGGL(k_uc, dim3(1), dim3(128), 0, stream, We_enc, be_enc, We1, We2, uc);
    hipLaunchKernelGGL(k_wpack, dim3(256), dim3(256), 0, stream, Wq2, Wk2, Wv2, Ws2, Bph);

    // ---- CSR build (shared by both layers) ----
    hipMemsetAsync(deg, 0, (size_t)n * sizeof(int), stream);
    hipLaunchKernelGGL(k_hist, dim3(eb), dim3(256), 0, stream, ei, deg, E);
    hipLaunchKernelGGL(k_scan1, dim3(nb), dim3(256), 0, stream, deg, bsum, n);
    hipLaunchKernelGGL(k_scan2, dim3(1), dim3(256), 0, stream, bsum, nb);
    hipLaunchKernelGGL(k_scan3, dim3(nb), dim3(256), 0, stream, deg, bsum, rowptr, n, E);
    hipLaunchKernelGGL(k_scatter, dim3(eb), dim3(256), 0, stream, ei, rowptr, deg, eid, E);
    hipLaunchKernelGGL(k_bsortg, dim3(nb), dim3(256), 0, stream, rowptr, eid, ei, ea, srcs, eas, n);

    // ---- layer 1 ----
    hipLaunchKernelGGL(k_lin6, dim3((n + 15) / 16), dim3(256), 0, stream,
                       x, n, Wq1, bq1, Wk1, bk1, Wv1, bv1, Ws1, bs1, qb, kv16, Bb);
    hipLaunchKernelGGL((k_attn<1>), dim3(wb), dim3(256), 0, stream,
                       qb, kv16, rowptr, srcs, eas, uc, uc + HC, Bb, hb16,
                       Wfc, bfc, (float*)d_out, n);

    // ---- layer 2 (pure-bf16 MFMA GEMM; writes q f32, k/v bf16, skip into Bb) ----
    hipLaunchKernelGGL(k_lin2, dim3((n + 63) / 64), dim3(256), 0, stream,
                       hb16, Bph, bq2, bk2, bv2, bs2, qb, kv16, Bb, n);
    // ---- layer-2 attn with fused fc head ----
    hipLaunchKernelGGL((k_attn<0>), dim3(wb), dim3(256), 0, stream,
                       qb, kv16, rowptr, srcs, eas, uc + 2 * HC, uc + 3 * HC, Bb,
                       (unsigned short*)nullptr, Wfc, bfc, (float*)d_out, n);
}

// Round 14
// 218.549 us; speedup vs baseline: 1.2827x; 1.0394x over previous
//
#include <hip/hip_runtime.h>

// TemporalGNN: 2x TransformerConv(H=2, C=64) + edge encoder + fc head.
// Edge encoder rank-1 folded out of the edge loop: a=(q.k+ea*qu+qc)/8.
// Edge phase: counting-sort by dst; one wave per dst node; wave = 4 x 16-lane
// groups, each group owns one edge stream (lane = 8 channels, dot2-bf16 QK),
// merged via shfl_xor(16)+shfl_xor(32). q/k/v all packed bf16.
// Layer-2 linears: pure-bf16 MFMA GEMM, 64-node blocks, A in registers
// across the 4 col-quarter loop. fc head fused into layer-2 attn.

#define HC 128   // H*C

typedef __attribute__((ext_vector_type(8))) short bf16x8;
typedef __attribute__((ext_vector_type(4))) float f32x4;
#if __has_builtin(__builtin_amdgcn_fdot2_f32_bf16)
typedef __attribute__((ext_vector_type(2))) __bf16 bf16x2;
#define HAS_DOT2 1
#else
#define HAS_DOT2 0
#endif

__device__ __forceinline__ unsigned bf16_rne(float f) {
    unsigned u = __float_as_uint(f);
    return (u + 0x7fffu + ((u >> 16) & 1u)) >> 16;
}
__device__ __forceinline__ float blo(unsigned u) { return __uint_as_float(u << 16); }
__device__ __forceinline__ float bhi(unsigned u) { return __uint_as_float(u & 0xffff0000u); }

// ---------- rank-1 edge-encoder precompute ----------
__global__ void k_uc(const float* __restrict__ We_enc, const float* __restrict__ be_enc,
                     const float* __restrict__ We1, const float* __restrict__ We2,
                     float* __restrict__ uc) {
    int c = threadIdx.x;  // 0..127
    float u1 = 0.f, c1 = 0.f, u2 = 0.f, c2 = 0.f;
    for (int j = 0; j < 64; ++j) {
        float we = We_enc[j], be = be_enc[j];
        float w1 = We1[j * HC + c], w2 = We2[j * HC + c];
        u1 += we * w1; c1 += be * w1;
        u2 += we * w2; c2 += be * w2;
    }
    uc[c] = u1; uc[HC + c] = c1; uc[2 * HC + c] = u2; uc[3 * HC + c] = c2;
}

// ---------- pack layer-2 weights to bf16, B^T layout [n=512][k=128] ----------
__global__ __launch_bounds__(256) void k_wpack(
    const float* __restrict__ Wq, const float* __restrict__ Wk,
    const float* __restrict__ Wv, const float* __restrict__ Ws,
    unsigned short* __restrict__ Bph) {
    int t = blockIdx.x * 256 + threadIdx.x;   // 0..65535
    int nn = t >> 7;        // 0..511
    int kk = t & 127;
    int mat = nn >> 7, c = nn & 127;
    const float* W = (mat == 0) ? Wq : (mat == 1) ? Wk : (mat == 2) ? Wv : Ws;
    Bph[nn * 128 + kk] = (unsigned short)bf16_rne(W[kk * 128 + c]);
}

// ---------- CSR build (stable counting sort by dst) ----------
__global__ __launch_bounds__(256) void k_hist(const int* __restrict__ ei, int* __restrict__ deg, int E) {
    int t = blockIdx.x * blockDim.x + threadIdx.x;
    if (t < E) atomicAdd(&deg[ei[E + t]], 1);
}

__global__ __launch_bounds__(256) void k_scan1(const int* __restrict__ deg, int* __restrict__ bsum, int n) {
    int t = blockIdx.x * 256 + threadIdx.x;
    int v = (t < n) ? deg[t] : 0;
#pragma unroll
    for (int off = 1; off < 64; off <<= 1) v += __shfl_xor(v, off);
    __shared__ int wsum[4];
    int lane = threadIdx.x & 63, w = threadIdx.x >> 6;
    if (lane == 0) wsum[w] = v;
    __syncthreads();
    if (threadIdx.x == 0) bsum[blockIdx.x] = wsum[0] + wsum[1] + wsum[2] + wsum[3];
}

__global__ __launch_bounds__(256) void k_scan2(int* __restrict__ bsum, int nb) {
    __shared__ int sh[256];
    int t = threadIdx.x;
    int v = (t < nb) ? bsum[t] : 0;
    sh[t] = v;
    __syncthreads();
    for (int off = 1; off < 256; off <<= 1) {
        int x = (t >= off) ? sh[t - off] : 0;
        __syncthreads();
        sh[t] += x;
        __syncthreads();
    }
    if (t < nb) bsum[t] = sh[t] - v;   // exclusive
}

// scan3 also zeroes deg (reused as the scatter cursor).
__global__ __launch_bounds__(256) void k_scan3(int* __restrict__ deg, const int* __restrict__ bsum,
                                               int* __restrict__ rowptr, int n, int E) {
    int t = blockIdx.x * 256 + threadIdx.x;
    int tid = threadIdx.x;
    int v = (t < n) ? deg[t] : 0;
    __shared__ int sh[256];
    sh[tid] = v;
    __syncthreads();
    for (int off = 1; off < 256; off <<= 1) {
        int x = (tid >= off) ? sh[tid - off] : 0;
        __syncthreads();
        sh[tid] += x;
        __syncthreads();
    }
    if (t < n) { rowptr[t] = bsum[blockIdx.x] + sh[tid] - v; deg[t] = 0; }
    if (t == 0) rowptr[n] = E;
}

__global__ __launch_bounds__(256) void k_scatter(const int* __restrict__ ei, const int* __restrict__ rowptr,
                                                 int* __restrict__ cursor, int* __restrict__ eid, int E) {
    int t = blockIdx.x * blockDim.x + threadIdx.x;
    if (t >= E) return;
    int dst = ei[E + t];
    int pos = rowptr[dst] + atomicAdd(&cursor[dst], 1);
    eid[pos] = t;
}

// per-bucket insertion sort by edge id (stable) + fused srcs/eas gather.
__global__ __launch_bounds__(256) void k_bsortg(
    const int* __restrict__ rowptr, int* __restrict__ eid,
    const int* __restrict__ ei, const float* __restrict__ ea,
    int* __restrict__ srcs, float* __restrict__ eas, int n) {
    int t = blockIdx.x * blockDim.x + threadIdx.x;
    if (t >= n) return;
    int b = rowptr[t], e = rowptr[t + 1];
    for (int i = b + 1; i < e; ++i) {
        int key = eid[i];
        int j = i - 1;
        while (j >= b && eid[j] > key) { eid[j + 1] = eid[j]; --j; }
        eid[j + 1] = key;
    }
    for (int i = b; i < e; ++i) {
        int id = eid[i];
        srcs[i] = ei[id];
        eas[i] = ea[id];
    }
}

// ---------- layer-1 node linears (K=6, vector ALU) ----------
// q bf16, k/v bf16 interleaved; o (skip) f32.
__global__ __launch_bounds__(256) void k_lin6(
    const float* __restrict__ X, int n,
    const float* __restrict__ Wq, const float* __restrict__ bq,
    const float* __restrict__ Wk, const float* __restrict__ bk,
    const float* __restrict__ Wv, const float* __restrict__ bv,
    const float* __restrict__ Ws, const float* __restrict__ bs,
    unsigned short* __restrict__ q16, unsigned short* __restrict__ kv,
    float* __restrict__ o) {
    __shared__ float xs[16][6];
    const int base = blockIdx.x * 16;
    const int tid = threadIdx.x;
    for (int i = tid; i < 16 * 6; i += 256) {
        int ni = base + i / 6;
        xs[i / 6][i % 6] = (ni < n) ? X[(size_t)ni * 6 + (i % 6)] : 0.f;
    }
    __syncthreads();
    const int c = tid & 127;
    const int m = tid >> 7;  // 0 -> (q,k), 1 -> (v,o)
    const float* WA = m ? Wv : Wq;
    const float* WB = m ? Ws : Wk;
    float accA[16], accB[16];
#pragma unroll
    for (int i = 0; i < 16; ++i) { accA[i] = 0.f; accB[i] = 0.f; }
    for (int j = 0; j < 6; ++j) {
        float w0 = WA[j * HC + c];
        float w1 = WB[j * HC + c];
#pragma unroll
        for (int i = 0; i < 16; ++i) {
            float xv = xs[i][j];
            accA[i] += xv * w0;
            accB[i] += xv * w1;
        }
    }
    if (m == 0) {
        const float bA = bq[c], bB = bk[c];
#pragma unroll
        for (int i = 0; i < 16; ++i) {
            int ni = base + i;
            if (ni < n) {
                q16[(size_t)ni * HC + c] = (unsigned short)bf16_rne(accA[i] + bA);
                kv[(size_t)ni * 256 + c] = (unsigned short)bf16_rne(accB[i] + bB);
            }
        }
    } else {
        const float bA = bv[c], bB = bs[c];
#pragma unroll
        for (int i = 0; i < 16; ++i) {
            int ni = base + i;
            if (ni < n) {
                kv[(size_t)ni * 256 + 128 + c] = (unsigned short)bf16_rne(accA[i] + bA);
                o[(size_t)ni * HC + c] = accB[i] + bB;
            }
        }
    }
}

// ---------- layer-2 node linears: pure-bf16 MFMA GEMM, LDS-staged B ----------
__global__ __launch_bounds__(256, 4) void k_lin2(
    const unsigned short* __restrict__ hb, const unsigned short* __restrict__ Bph,
    const float* __restrict__ bq, const float* __restrict__ bk,
    const float* __restrict__ bv, const float* __restrict__ bs,
    unsigned short* __restrict__ q16, unsigned short* __restrict__ kv,
    float* __restrict__ o, int n) {
    __shared__ unsigned short Bs[128][128];   // 32 KB
    const int tid = threadIdx.x;
    const int wid = tid >> 6, l = tid & 63;
    const int la = l & 15, lk = l >> 4;
    const int mb = blockIdx.x * 64;
    int nodeA = mb + wid * 16 + la;
    if (nodeA >= n) nodeA = n - 1;
    const int sw = (la & 7) << 3;
    const int crow0 = mb + wid * 16 + lk * 4;

    bf16x8 areg[4];
#pragma unroll
    for (int ks = 0; ks < 4; ++ks)
        areg[ks] = *(const bf16x8*)&hb[(size_t)nodeA * 128 + lk * 8 + ks * 32];

    for (int cq = 0; cq < 4; ++cq) {
        if (cq) __syncthreads();
        for (int i = tid; i < 128 * 16; i += 256) {
            int kk8 = i & 15;
            int nnl = i >> 4;
            bf16x8 val = *(const bf16x8*)&Bph[((size_t)(cq * 128 + nnl)) * 128 + kk8 * 8];
            int swk = (kk8 ^ (nnl & 7)) * 8;
            *(bf16x8*)&Bs[nnl][swk] = val;
        }
        __syncthreads();

        f32x4 acc[8];
#pragma unroll
        for (int nt = 0; nt < 8; ++nt) acc[nt] = (f32x4){0.f, 0.f, 0.f, 0.f};
#pragma unroll
        for (int ks = 0; ks < 4; ++ks) {
            const int rk = (lk * 8 + ks * 32) ^ sw;
#pragma unroll
            for (int nt = 0; nt < 8; ++nt) {
                bf16x8 Bh = *(const bf16x8*)&Bs[nt * 16 + la][rk];
                acc[nt] = __builtin_amdgcn_mfma_f32_16x16x32_bf16(areg[ks], Bh, acc[nt], 0, 0, 0);
            }
        }
        const float* bias = (cq == 0) ? bq : (cq == 1) ? bk : (cq == 2) ? bv : bs;
#pragma unroll
        for (int nt = 0; nt < 8; ++nt) {
            const int col = nt * 16 + la;
            const float bb = bias[col];
            if (cq == 3) {
#pragma unroll
                for (int j = 0; j < 4; ++j) {
                    int n0 = crow0 + j;
                    if (n0 < n) o[(size_t)n0 * 128 + col] = acc[nt][j] + bb;
                }
            } else if (cq == 0) {
#pragma unroll
                for (int j = 0; j < 4; ++j) {
                    int n0 = crow0 + j;
                    if (n0 < n) q16[(size_t)n0 * 128 + col] = (unsigned short)bf16_rne(acc[nt][j] + bb);
                }
            } else {
                const int co = (cq == 1) ? col : 128 + col;
#pragma unroll
                for (int j = 0; j < 4; ++j) {
                    int n0 = crow0 + j;
                    if (n0 < n) kv[(size_t)n0 * 256 + co] = (unsigned short)bf16_rne(acc[nt][j] + bb);
                }
            }
        }
    }
}

// ---------- fused online-softmax attention, one wave per dst node ----------
// Wave = 4 x 16-lane groups; group g = (half<<1)|sub owns edge stream
// p + half + 2*sub. Lane owns 8 channels (hl 0-7 head0, 8-15 head1; per-head
// scalars live on 8-lane subgroups, reduce masks 1,2,4).
// QK dot via v_dot2_f32_bf16 when available. q/k/v packed bf16.
// MODE 1: relu(attn+skip) -> bf16 h. MODE 0: fc head fused, writes out[wid].
template <int MODE>
__global__ __launch_bounds__(256) void k_attn(
    const unsigned short* __restrict__ q16, const unsigned short* __restrict__ kvp,
    const int* __restrict__ rowptr, const int* __restrict__ srcs, const float* __restrict__ eas,
    const float* __restrict__ ucu, const float* __restrict__ ucc,
    const float* __restrict__ io, unsigned short* __restrict__ hb,
    const float* __restrict__ Wfc, const float* __restrict__ bfc,
    float* __restrict__ out, int n) {
    int wid = (int)((blockIdx.x * (size_t)blockDim.x + threadIdx.x) >> 6);
    int lane = threadIdx.x & 63;
    if (wid >= n) return;
    const int half = lane >> 5;
    const int sub = (lane >> 4) & 1;
    const int grp = lane >> 4;          // 0..3 edge stream
    const int hl = lane & 15;
    const int ch = hl * 8;
    const int strm = half + 2 * sub;    // edge offset within a 4-pack

    uint4 qp = *(const uint4*)&q16[(size_t)wid * 128 + ch];   // 8 bf16
    float qf0 = blo(qp.x), qf1 = bhi(qp.x), qf2 = blo(qp.y), qf3 = bhi(qp.y);
    float qf4 = blo(qp.z), qf5 = bhi(qp.z), qf6 = blo(qp.w), qf7 = bhi(qp.w);
    float4 uuA = *(const float4*)&ucu[ch], uuB = *(const float4*)&ucu[ch + 4];
    float4 ccA = *(const float4*)&ucc[ch], ccB = *(const float4*)&ucc[ch + 4];

    float qu = qf0 * uuA.x + qf1 * uuA.y + qf2 * uuA.z + qf3 * uuA.w
             + qf4 * uuB.x + qf5 * uuB.y + qf6 * uuB.z + qf7 * uuB.w;
    float qc = qf0 * ccA.x + qf1 * ccA.y + qf2 * ccA.z + qf3 * ccA.w
             + qf4 * ccB.x + qf5 * ccB.y + qf6 * ccB.z + qf7 * ccB.w;
#pragma unroll
    for (int off = 1; off < 8; off <<= 1) {
        qu += __shfl_xor(qu, off);
        qc += __shfl_xor(qc, off);
    }

    int b = rowptr[wid], e = rowptr[wid + 1];
    float m = -3.0e38f, s = 0.f, sea = 0.f;
    float av0 = 0.f, av1 = 0.f, av2 = 0.f, av3 = 0.f;
    float av4 = 0.f, av5 = 0.f, av6 = 0.f, av7 = 0.f;

    if (b < e) {
        int pi = b + strm;
        bool val = pi < e;
        int pc = val ? pi : e - 1;
        int src = srcs[pc];
        float eav = eas[pc];
        const unsigned short* row = &kvp[(size_t)src * 256 + ch];
        uint4 ku = *(const uint4*)row;
        uint4 vu = *(const uint4*)(row + 128);
        for (int p = b; p < e; p += 4) {
            int pn = p + 4 + strm;
            bool valn = pn < e;
            int pcn = valn ? pn : e - 1;
            int srcn = srcs[pcn];
            float eavn = eas[pcn];
            const unsigned short* rown = &kvp[(size_t)srcn * 256 + ch];
            uint4 kun = *(const uint4*)rown;
            uint4 vun = *(const uint4*)(rown + 128);

            float d;
#if HAS_DOT2
            d = __builtin_amdgcn_fdot2_f32_bf16(
                    __builtin_bit_cast(bf16x2, ku.x), __builtin_bit_cast(bf16x2, qp.x),
                __builtin_amdgcn_fdot2_f32_bf16(
                    __builtin_bit_cast(bf16x2, ku.y), __builtin_bit_cast(bf16x2, qp.y),
                __builtin_amdgcn_fdot2_f32_bf16(
                    __builtin_bit_cast(bf16x2, ku.z), __builtin_bit_cast(bf16x2, qp.z),
                __builtin_amdgcn_fdot2_f32_bf16(
                    __builtin_bit_cast(bf16x2, ku.w), __builtin_bit_cast(bf16x2, qp.w),
                    0.f, false), false), false), false);
#else
            d = qf0 * blo(ku.x) + qf1 * bhi(ku.x) + qf2 * blo(ku.y) + qf3 * bhi(ku.y)
              + qf4 * blo(ku.z) + qf5 * bhi(ku.z) + qf6 * blo(ku.w) + qf7 * bhi(ku.w);
#endif
            d += __shfl_xor(d, 1); d += __shfl_xor(d, 2); d += __shfl_xor(d, 4);
            float a = val ? (d + fmaf(eav, qu, qc)) * 0.125f : -INFINITY;
            float nm = fmaxf(m, a);
            float sc = __expf(m - nm);
            float pw = __expf(a - nm);
            s = fmaf(s, sc, pw);
            sea = fmaf(sea, sc, pw * eav);
            av0 = fmaf(av0, sc, pw * blo(vu.x));
            av1 = fmaf(av1, sc, pw * bhi(vu.x));
            av2 = fmaf(av2, sc, pw * blo(vu.y));
            av3 = fmaf(av3, sc, pw * bhi(vu.y));
            av4 = fmaf(av4, sc, pw * blo(vu.z));
            av5 = fmaf(av5, sc, pw * bhi(vu.z));
            av6 = fmaf(av6, sc, pw * blo(vu.w));
            av7 = fmaf(av7, sc, pw * bhi(vu.w));
            m = nm;
            ku = kun; vu = vun; eav = eavn; val = valn;
        }
    }

    // merge streams: sub (xor 16) then half (xor 32); NaN-free (m >= -3e38)
#pragma unroll
    for (int M = 16; M <= 32; M <<= 1) {
        float om = __shfl_xor(m, M);
        float os = __shfl_xor(s, M);
        float osea = __shfl_xor(sea, M);
        float o0 = __shfl_xor(av0, M), o1 = __shfl_xor(av1, M);
        float o2 = __shfl_xor(av2, M), o3 = __shfl_xor(av3, M);
        float o4 = __shfl_xor(av4, M), o5 = __shfl_xor(av5, M);
        float o6 = __shfl_xor(av6, M), o7 = __shfl_xor(av7, M);
        float nm = fmaxf(m, om);
        float scS = __expf(m - nm);
        float scO = __expf(om - nm);
        s = s * scS + os * scO;
        sea = sea * scS + osea * scO;
        av0 = av0 * scS + o0 * scO; av1 = av1 * scS + o1 * scO;
        av2 = av2 * scS + o2 * scO; av3 = av3 * scS + o3 * scO;
        av4 = av4 * scS + o4 * scO; av5 = av5 * scS + o5 * scO;
        av6 = av6 * scS + o6 * scO; av7 = av7 * scS + o7 * scO;
        m = nm;
    }

    float inv = 1.f / (s + 1e-16f);
    float4 skA = *(const float4*)&io[(size_t)wid * 128 + ch];
    float4 skB = *(const float4*)&io[(size_t)wid * 128 + ch + 4];
    float r0 = fmaxf((av0 + uuA.x * sea + ccA.x * s) * inv + skA.x, 0.f);
    float r1 = fmaxf((av1 + uuA.y * sea + ccA.y * s) * inv + skA.y, 0.f);
    float r2 = fmaxf((av2 + uuA.z * sea + ccA.z * s) * inv + skA.z, 0.f);
    float r3 = fmaxf((av3 + uuA.w * sea + ccA.w * s) * inv + skA.w, 0.f);
    float r4 = fmaxf((av4 + uuB.x * sea + ccB.x * s) * inv + skB.x, 0.f);
    float r5 = fmaxf((av5 + uuB.y * sea + ccB.y * s) * inv + skB.y, 0.f);
    float r6 = fmaxf((av6 + uuB.z * sea + ccB.z * s) * inv + skB.z, 0.f);
    float r7 = fmaxf((av7 + uuB.w * sea + ccB.w * s) * inv + skB.w, 0.f);

    if (MODE == 1) {
        if (grp == 0) {
            uint4 hv;
            hv.x = bf16_rne(r0) | (bf16_rne(r1) << 16);
            hv.y = bf16_rne(r2) | (bf16_rne(r3) << 16);
            hv.z = bf16_rne(r4) | (bf16_rne(r5) << 16);
            hv.w = bf16_rne(r6) | (bf16_rne(r7) << 16);
            *(uint4*)&hb[(size_t)wid * 128 + ch] = hv;
        }
    } else {
        float4 wfA = *(const float4*)&Wfc[ch];
        float4 wfB = *(const float4*)&Wfc[ch + 4];
        float rr = r0 * wfA.x + r1 * wfA.y + r2 * wfA.z + r3 * wfA.w
                 + r4 * wfB.x + r5 * wfB.y + r6 * wfB.z + r7 * wfB.w;
#pragma unroll
        for (int off = 1; off < 16; off <<= 1) rr += __shfl_xor(rr, off);
        if (lane == 0) out[wid] = rr + bfc[0];
    }
}

extern "C" void kernel_launch(void* const* d_in, const int* in_sizes, int n_in,
                              void* d_out, int out_size, void* d_ws, size_t ws_size,
                              hipStream_t stream) {
    const float* x      = (const float*)d_in[0];
    const int*   ei     = (const int*)d_in[1];
    const float* ea     = (const float*)d_in[2];
    const float* We_enc = (const float*)d_in[3];
    const float* be_enc = (const float*)d_in[4];
    const float* Wq1 = (const float*)d_in[5],  *bq1 = (const float*)d_in[6];
    const float* Wk1 = (const float*)d_in[7],  *bk1 = (const float*)d_in[8];
    const float* Wv1 = (const float*)d_in[9],  *bv1 = (const float*)d_in[10];
    const float* We1 = (const float*)d_in[11];
    const float* Ws1 = (const float*)d_in[12], *bs1 = (const float*)d_in[13];
    const float* Wq2 = (const float*)d_in[14], *bq2 = (const float*)d_in[15];
    const float* Wk2 = (const float*)d_in[16], *bk2 = (const float*)d_in[17];
    const float* Wv2 = (const float*)d_in[18], *bv2 = (const float*)d_in[19];
    const float* We2 = (const float*)d_in[20];
    const float* Ws2 = (const float*)d_in[21], *bs2 = (const float*)d_in[22];
    const float* Wfc = (const float*)d_in[23], *bfc = (const float*)d_in[24];

    const int n = in_sizes[0] / 6;   // 50000
    const int E = in_sizes[2];       // 409600

    float* ws = (float*)d_ws;
    size_t off = 0;
    unsigned short* qb16 = (unsigned short*)(ws + off); off += (size_t)n * HC / 2;  // q bf16
    float* Bb = ws + off; off += (size_t)n * HC;   // skip buffer (f32)
    unsigned short* kv16 = (unsigned short*)(ws + off); off += (size_t)n * HC;  // interleaved k|v bf16
    int* rowptr = (int*)(ws + off); off += (size_t)(n + 1);
    int* deg    = (int*)(ws + off); off += (size_t)n;   // also scatter cursor
    int* bsum   = (int*)(ws + off); off += 256;
    int* eid    = (int*)(ws + off); off += (size_t)E;
    int* srcs   = (int*)(ws + off); off += (size_t)E;
    float* eas  = ws + off; off += (size_t)E;
    float* uc   = ws + off; off += 512;
    unsigned short* hb16 = (unsigned short*)(ws + off); off += (size_t)n * HC / 2;  // h as bf16
    unsigned short* Bph = (unsigned short*)(ws + off); off += 512 * 128 / 2;

    const int eb = (E + 255) / 256;
    const int nb = (n + 255) / 256;
    const int wb = (int)(((size_t)n * 64 + 255) / 256);

    hipLaunchKernelGGL(k_uc, dim3(1), dim3(128), 0, stream, We_enc, be_enc, We1, We2, uc);
    hipLaunchKernelGGL(k_wpack, dim3(256), dim3(256), 0, stream, Wq2, Wk2, Wv2, Ws2, Bph);

    // ---- CSR build (shared by both layers) ----
    hipMemsetAsync(deg, 0, (size_t)n * sizeof(int), stream);
    hipLaunchKernelGGL(k_hist, dim3(eb), dim3(256), 0, stream, ei, deg, E);
    hipLaunchKernelGGL(k_scan1, dim3(nb), dim3(256), 0, stream, deg, bsum, n);
    hipLaunchKernelGGL(k_scan2, dim3(1), dim3(256), 0, stream, bsum, nb);
    hipLaunchKernelGGL(k_scan3, dim3(nb), dim3(256), 0, stream, deg, bsum, rowptr, n, E);
    hipLaunchKernelGGL(k_scatter, dim3(eb), dim3(256), 0, stream, ei, rowptr, deg, eid, E);
    hipLaunchKernelGGL(k_bsortg, dim3(nb), dim3(256), 0, stream, rowptr, eid, ei, ea, srcs, eas, n);

    // ---- layer 1 ----
    hipLaunchKernelGGL(k_lin6, dim3((n + 15) / 16), dim3(256), 0, stream,
                       x, n, Wq1, bq1, Wk1, bk1, Wv1, bv1, Ws1, bs1, qb16, kv16, Bb);
    hipLaunchKernelGGL((k_attn<1>), dim3(wb), dim3(256), 0, stream,
                       qb16, kv16, rowptr, srcs, eas, uc, uc + HC, Bb, hb16,
                       Wfc, bfc, (float*)d_out, n);

    // ---- layer 2 (pure-bf16 MFMA GEMM; q/k/v bf16, skip f32 into Bb) ----
    hipLaunchKernelGGL(k_lin2, dim3((n + 63) / 64), dim3(256), 0, stream,
                       hb16, Bph, bq2, bk2, bv2, bs2, qb16, kv16, Bb, n);
    // ---- layer-2 attn with fused fc head ----
    hipLaunchKernelGGL((k_attn<0>), dim3(wb), dim3(256), 0, stream,
                       qb16, kv16, rowptr, srcs, eas, uc + 2 * HC, uc + 3 * HC, Bb,
                       (unsigned short*)nullptr, Wfc, bfc, (float*)d_out, n);
}

// Round 15
// 199.071 us; speedup vs baseline: 1.4082x; 1.0978x over previous
//
#include <hip/hip_runtime.h>

// TemporalGNN: 2x TransformerConv(H=2, C=64) + edge encoder + fc head.
// Edge encoder rank-1 folded out of the edge loop: a=(q.k+ea*qu+qc)/8.
// Edge phase: counting-sort by dst (unordered within bucket -- rounding-level
// nondeterminism only); one wave per dst node; 4 x 16-lane edge streams,
// dot2-bf16 QK, 2-deep gather prefetch. q/k/v/skip all packed bf16.
// Layer-2 linears: pure-bf16 MFMA GEMM, 64-node blocks, A in registers
// across the 4 col-quarter loop. fc head fused into layer-2 attn.

#define HC 128   // H*C

typedef __attribute__((ext_vector_type(8))) short bf16x8;
typedef __attribute__((ext_vector_type(4))) float f32x4;
#if __has_builtin(__builtin_amdgcn_fdot2_f32_bf16)
typedef __attribute__((ext_vector_type(2))) __bf16 bf16x2;
#define HAS_DOT2 1
#else
#define HAS_DOT2 0
#endif

__device__ __forceinline__ unsigned bf16_rne(float f) {
    unsigned u = __float_as_uint(f);
    return (u + 0x7fffu + ((u >> 16) & 1u)) >> 16;
}
__device__ __forceinline__ float blo(unsigned u) { return __uint_as_float(u << 16); }
__device__ __forceinline__ float bhi(unsigned u) { return __uint_as_float(u & 0xffff0000u); }

// ---------- rank-1 edge-encoder precompute ----------
__global__ void k_uc(const float* __restrict__ We_enc, const float* __restrict__ be_enc,
                     const float* __restrict__ We1, const float* __restrict__ We2,
                     float* __restrict__ uc) {
    int c = threadIdx.x;  // 0..127
    float u1 = 0.f, c1 = 0.f, u2 = 0.f, c2 = 0.f;
    for (int j = 0; j < 64; ++j) {
        float we = We_enc[j], be = be_enc[j];
        float w1 = We1[j * HC + c], w2 = We2[j * HC + c];
        u1 += we * w1; c1 += be * w1;
        u2 += we * w2; c2 += be * w2;
    }
    uc[c] = u1; uc[HC + c] = c1; uc[2 * HC + c] = u2; uc[3 * HC + c] = c2;
}

// ---------- pack layer-2 weights to bf16, B^T layout [n=512][k=128] ----------
__global__ __launch_bounds__(256) void k_wpack(
    const float* __restrict__ Wq, const float* __restrict__ Wk,
    const float* __restrict__ Wv, const float* __restrict__ Ws,
    unsigned short* __restrict__ Bph) {
    int t = blockIdx.x * 256 + threadIdx.x;   // 0..65535
    int nn = t >> 7;        // 0..511
    int kk = t & 127;
    int mat = nn >> 7, c = nn & 127;
    const float* W = (mat == 0) ? Wq : (mat == 1) ? Wk : (mat == 2) ? Wv : Ws;
    Bph[nn * 128 + kk] = (unsigned short)bf16_rne(W[kk * 128 + c]);
}

// ---------- CSR build (counting sort by dst; bucket order = atomic order) ----------
__global__ __launch_bounds__(256) void k_hist(const int* __restrict__ ei, int* __restrict__ deg, int E) {
    int t = blockIdx.x * blockDim.x + threadIdx.x;
    if (t < E) atomicAdd(&deg[ei[E + t]], 1);
}

__global__ __launch_bounds__(256) void k_scan1(const int* __restrict__ deg, int* __restrict__ bsum, int n) {
    int t = blockIdx.x * 256 + threadIdx.x;
    int v = (t < n) ? deg[t] : 0;
#pragma unroll
    for (int off = 1; off < 64; off <<= 1) v += __shfl_xor(v, off);
    __shared__ int wsum[4];
    int lane = threadIdx.x & 63, w = threadIdx.x >> 6;
    if (lane == 0) wsum[w] = v;
    __syncthreads();
    if (threadIdx.x == 0) bsum[blockIdx.x] = wsum[0] + wsum[1] + wsum[2] + wsum[3];
}

__global__ __launch_bounds__(256) void k_scan2(int* __restrict__ bsum, int nb) {
    __shared__ int sh[256];
    int t = threadIdx.x;
    int v = (t < nb) ? bsum[t] : 0;
    sh[t] = v;
    __syncthreads();
    for (int off = 1; off < 256; off <<= 1) {
        int x = (t >= off) ? sh[t - off] : 0;
        __syncthreads();
        sh[t] += x;
        __syncthreads();
    }
    if (t < nb) bsum[t] = sh[t] - v;   // exclusive
}

// scan3 also zeroes deg (reused as the scatter cursor).
__global__ __launch_bounds__(256) void k_scan3(int* __restrict__ deg, const int* __restrict__ bsum,
                                               int* __restrict__ rowptr, int n, int E) {
    int t = blockIdx.x * 256 + threadIdx.x;
    int tid = threadIdx.x;
    int v = (t < n) ? deg[t] : 0;
    __shared__ int sh[256];
    sh[tid] = v;
    __syncthreads();
    for (int off = 1; off < 256; off <<= 1) {
        int x = (tid >= off) ? sh[tid - off] : 0;
        __syncthreads();
        sh[tid] += x;
        __syncthreads();
    }
    if (t < n) { rowptr[t] = bsum[blockIdx.x] + sh[tid] - v; deg[t] = 0; }
    if (t == 0) rowptr[n] = E;
}

// fused scatter + gather: srcs/eas written directly in bucket slots.
__global__ __launch_bounds__(256) void k_scatter(
    const int* __restrict__ ei, const float* __restrict__ ea,
    const int* __restrict__ rowptr, int* __restrict__ cursor,
    int* __restrict__ srcs, float* __restrict__ eas, int E) {
    int t = blockIdx.x * blockDim.x + threadIdx.x;
    if (t >= E) return;
    int dst = ei[E + t];
    int pos = rowptr[dst] + atomicAdd(&cursor[dst], 1);
    srcs[pos] = ei[t];
    eas[pos] = ea[t];
}

// ---------- layer-1 node linears (K=6, vector ALU) ----------
// q bf16, k/v bf16 interleaved, skip bf16.
__global__ __launch_bounds__(256) void k_lin6(
    const float* __restrict__ X, int n,
    const float* __restrict__ Wq, const float* __restrict__ bq,
    const float* __restrict__ Wk, const float* __restrict__ bk,
    const float* __restrict__ Wv, const float* __restrict__ bv,
    const float* __restrict__ Ws, const float* __restrict__ bs,
    unsigned short* __restrict__ q16, unsigned short* __restrict__ kv,
    unsigned short* __restrict__ sk) {
    __shared__ float xs[16][6];
    const int base = blockIdx.x * 16;
    const int tid = threadIdx.x;
    for (int i = tid; i < 16 * 6; i += 256) {
        int ni = base + i / 6;
        xs[i / 6][i % 6] = (ni < n) ? X[(size_t)ni * 6 + (i % 6)] : 0.f;
    }
    __syncthreads();
    const int c = tid & 127;
    const int m = tid >> 7;  // 0 -> (q,k), 1 -> (v,sk)
    const float* WA = m ? Wv : Wq;
    const float* WB = m ? Ws : Wk;
    float accA[16], accB[16];
#pragma unroll
    for (int i = 0; i < 16; ++i) { accA[i] = 0.f; accB[i] = 0.f; }
    for (int j = 0; j < 6; ++j) {
        float w0 = WA[j * HC + c];
        float w1 = WB[j * HC + c];
#pragma unroll
        for (int i = 0; i < 16; ++i) {
            float xv = xs[i][j];
            accA[i] += xv * w0;
            accB[i] += xv * w1;
        }
    }
    if (m == 0) {
        const float bA = bq[c], bB = bk[c];
#pragma unroll
        for (int i = 0; i < 16; ++i) {
            int ni = base + i;
            if (ni < n) {
                q16[(size_t)ni * HC + c] = (unsigned short)bf16_rne(accA[i] + bA);
                kv[(size_t)ni * 256 + c] = (unsigned short)bf16_rne(accB[i] + bB);
            }
        }
    } else {
        const float bA = bv[c], bB = bs[c];
#pragma unroll
        for (int i = 0; i < 16; ++i) {
            int ni = base + i;
            if (ni < n) {
                kv[(size_t)ni * 256 + 128 + c] = (unsigned short)bf16_rne(accA[i] + bA);
                sk[(size_t)ni * HC + c] = (unsigned short)bf16_rne(accB[i] + bB);
            }
        }
    }
}

// ---------- layer-2 node linears: pure-bf16 MFMA GEMM, LDS-staged B ----------
__global__ __launch_bounds__(256, 4) void k_lin2(
    const unsigned short* __restrict__ hb, const unsigned short* __restrict__ Bph,
    const float* __restrict__ bq, const float* __restrict__ bk,
    const float* __restrict__ bv, const float* __restrict__ bs,
    unsigned short* __restrict__ q16, unsigned short* __restrict__ kv,
    unsigned short* __restrict__ sk, int n) {
    __shared__ unsigned short Bs[128][128];   // 32 KB
    const int tid = threadIdx.x;
    const int wid = tid >> 6, l = tid & 63;
    const int la = l & 15, lk = l >> 4;
    const int mb = blockIdx.x * 64;
    int nodeA = mb + wid * 16 + la;
    if (nodeA >= n) nodeA = n - 1;
    const int sw = (la & 7) << 3;
    const int crow0 = mb + wid * 16 + lk * 4;

    bf16x8 areg[4];
#pragma unroll
    for (int ks = 0; ks < 4; ++ks)
        areg[ks] = *(const bf16x8*)&hb[(size_t)nodeA * 128 + lk * 8 + ks * 32];

    for (int cq = 0; cq < 4; ++cq) {
        if (cq) __syncthreads();
        for (int i = tid; i < 128 * 16; i += 256) {
            int kk8 = i & 15;
            int nnl = i >> 4;
            bf16x8 val = *(const bf16x8*)&Bph[((size_t)(cq * 128 + nnl)) * 128 + kk8 * 8];
            int swk = (kk8 ^ (nnl & 7)) * 8;
            *(bf16x8*)&Bs[nnl][swk] = val;
        }
        __syncthreads();

        f32x4 acc[8];
#pragma unroll
        for (int nt = 0; nt < 8; ++nt) acc[nt] = (f32x4){0.f, 0.f, 0.f, 0.f};
#pragma unroll
        for (int ks = 0; ks < 4; ++ks) {
            const int rk = (lk * 8 + ks * 32) ^ sw;
#pragma unroll
            for (int nt = 0; nt < 8; ++nt) {
                bf16x8 Bh = *(const bf16x8*)&Bs[nt * 16 + la][rk];
                acc[nt] = __builtin_amdgcn_mfma_f32_16x16x32_bf16(areg[ks], Bh, acc[nt], 0, 0, 0);
            }
        }
        const float* bias = (cq == 0) ? bq : (cq == 1) ? bk : (cq == 2) ? bv : bs;
#pragma unroll
        for (int nt = 0; nt < 8; ++nt) {
            const int col = nt * 16 + la;
            const float bb = bias[col];
            if (cq == 0 || cq == 3) {
                unsigned short* out = (cq == 0) ? q16 : sk;
#pragma unroll
                for (int j = 0; j < 4; ++j) {
                    int n0 = crow0 + j;
                    if (n0 < n) out[(size_t)n0 * 128 + col] = (unsigned short)bf16_rne(acc[nt][j] + bb);
                }
            } else {
                const int co = (cq == 1) ? col : 128 + col;
#pragma unroll
                for (int j = 0; j < 4; ++j) {
                    int n0 = crow0 + j;
                    if (n0 < n) kv[(size_t)n0 * 256 + co] = (unsigned short)bf16_rne(acc[nt][j] + bb);
                }
            }
        }
    }
}

// ---------- fused online-softmax attention, one wave per dst node ----------
// Wave = 4 x 16-lane groups (edge streams); lane = 8 channels.
// 2-deep gather prefetch (all loads in flight for deg<=8 nodes).
// MODE 1: relu(attn+skip) -> bf16 h. MODE 0: fc head fused, writes out[wid].
template <int MODE>
__global__ __launch_bounds__(256) void k_attn(
    const unsigned short* __restrict__ q16, const unsigned short* __restrict__ kvp,
    const int* __restrict__ rowptr, const int* __restrict__ srcs, const float* __restrict__ eas,
    const float* __restrict__ ucu, const float* __restrict__ ucc,
    const unsigned short* __restrict__ io, unsigned short* __restrict__ hb,
    const float* __restrict__ Wfc, const float* __restrict__ bfc,
    float* __restrict__ out, int n) {
    int wid = (int)((blockIdx.x * (size_t)blockDim.x + threadIdx.x) >> 6);
    int lane = threadIdx.x & 63;
    if (wid >= n) return;
    const int grp = lane >> 4;          // 0..3 edge stream
    const int hl = lane & 15;
    const int ch = hl * 8;

    uint4 qp = *(const uint4*)&q16[(size_t)wid * 128 + ch];   // 8 bf16
    float qu, qc;
    {
        float qf0 = blo(qp.x), qf1 = bhi(qp.x), qf2 = blo(qp.y), qf3 = bhi(qp.y);
        float qf4 = blo(qp.z), qf5 = bhi(qp.z), qf6 = blo(qp.w), qf7 = bhi(qp.w);
        float4 uA = *(const float4*)&ucu[ch], uB = *(const float4*)&ucu[ch + 4];
        float4 cA = *(const float4*)&ucc[ch], cB = *(const float4*)&ucc[ch + 4];
        qu = qf0 * uA.x + qf1 * uA.y + qf2 * uA.z + qf3 * uA.w
           + qf4 * uB.x + qf5 * uB.y + qf6 * uB.z + qf7 * uB.w;
        qc = qf0 * cA.x + qf1 * cA.y + qf2 * cA.z + qf3 * cA.w
           + qf4 * cB.x + qf5 * cB.y + qf6 * cB.z + qf7 * cB.w;
#pragma unroll
        for (int off = 1; off < 8; off <<= 1) {
            qu += __shfl_xor(qu, off);
            qc += __shfl_xor(qc, off);
        }
    }

    int b = rowptr[wid], e = rowptr[wid + 1];
    float m = -3.0e38f, s = 0.f, sea = 0.f;
    float av0 = 0.f, av1 = 0.f, av2 = 0.f, av3 = 0.f;
    float av4 = 0.f, av5 = 0.f, av6 = 0.f, av7 = 0.f;

    if (b < e) {
        // 2-deep pipeline: cur = iter p, nxt = iter p+4
        int p0 = b + grp;          bool v0 = p0 < e; int c0 = v0 ? p0 : e - 1;
        int p1 = b + 4 + grp;      bool v1 = p1 < e; int c1 = v1 ? p1 : e - 1;
        int s0 = srcs[c0], s1 = srcs[c1];
        float ea0 = eas[c0], ea1 = eas[c1];
        const unsigned short* r0p = &kvp[(size_t)s0 * 256 + ch];
        const unsigned short* r1p = &kvp[(size_t)s1 * 256 + ch];
        uint4 ku0 = *(const uint4*)r0p, vu0 = *(const uint4*)(r0p + 128);
        uint4 ku1 = *(const uint4*)r1p, vu1 = *(const uint4*)(r1p + 128);
        for (int p = b; p < e; p += 4) {
            // prefetch iter p+8
            int p2 = p + 8 + grp;
            bool v2 = p2 < e; int c2 = v2 ? p2 : e - 1;
            int s2 = srcs[c2];
            float ea2 = eas[c2];
            const unsigned short* r2p = &kvp[(size_t)s2 * 256 + ch];
            uint4 ku2 = *(const uint4*)r2p, vu2 = *(const uint4*)(r2p + 128);

            float d;
#if HAS_DOT2
            d = __builtin_amdgcn_fdot2_f32_bf16(
                    __builtin_bit_cast(bf16x2, ku0.x), __builtin_bit_cast(bf16x2, qp.x),
                __builtin_amdgcn_fdot2_f32_bf16(
                    __builtin_bit_cast(bf16x2, ku0.y), __builtin_bit_cast(bf16x2, qp.y),
                __builtin_amdgcn_fdot2_f32_bf16(
                    __builtin_bit_cast(bf16x2, ku0.z), __builtin_bit_cast(bf16x2, qp.z),
                __builtin_amdgcn_fdot2_f32_bf16(
                    __builtin_bit_cast(bf16x2, ku0.w), __builtin_bit_cast(bf16x2, qp.w),
                    0.f, false), false), false), false);
#else
            d = blo(qp.x) * blo(ku0.x) + bhi(qp.x) * bhi(ku0.x)
              + blo(qp.y) * blo(ku0.y) + bhi(qp.y) * bhi(ku0.y)
              + blo(qp.z) * blo(ku0.z) + bhi(qp.z) * bhi(ku0.z)
              + blo(qp.w) * blo(ku0.w) + bhi(qp.w) * bhi(ku0.w);
#endif
            d += __shfl_xor(d, 1); d += __shfl_xor(d, 2); d += __shfl_xor(d, 4);
            float a = v0 ? (d + fmaf(ea0, qu, qc)) * 0.125f : -INFINITY;
            float nm = fmaxf(m, a);
            float sc = __expf(m - nm);
            float pw = __expf(a - nm);
            s = fmaf(s, sc, pw);
            sea = fmaf(sea, sc, pw * ea0);
            av0 = fmaf(av0, sc, pw * blo(vu0.x));
            av1 = fmaf(av1, sc, pw * bhi(vu0.x));
            av2 = fmaf(av2, sc, pw * blo(vu0.y));
            av3 = fmaf(av3, sc, pw * bhi(vu0.y));
            av4 = fmaf(av4, sc, pw * blo(vu0.z));
            av5 = fmaf(av5, sc, pw * bhi(vu0.z));
            av6 = fmaf(av6, sc, pw * blo(vu0.w));
            av7 = fmaf(av7, sc, pw * bhi(vu0.w));
            m = nm;
            ku0 = ku1; vu0 = vu1; ea0 = ea1; v0 = v1;
            ku1 = ku2; vu1 = vu2; ea1 = ea2; v1 = v2;
        }
    }

    // merge streams: xor 16 then xor 32; NaN-free (m >= -3e38)
#pragma unroll
    for (int M = 16; M <= 32; M <<= 1) {
        float om = __shfl_xor(m, M);
        float os = __shfl_xor(s, M);
        float osea = __shfl_xor(sea, M);
        float o0 = __shfl_xor(av0, M), o1 = __shfl_xor(av1, M);
        float o2 = __shfl_xor(av2, M), o3 = __shfl_xor(av3, M);
        float o4 = __shfl_xor(av4, M), o5 = __shfl_xor(av5, M);
        float o6 = __shfl_xor(av6, M), o7 = __shfl_xor(av7, M);
        float nm = fmaxf(m, om);
        float scS = __expf(m - nm);
        float scO = __expf(om - nm);
        s = s * scS + os * scO;
        sea = sea * scS + osea * scO;
        av0 = av0 * scS + o0 * scO; av1 = av1 * scS + o1 * scO;
        av2 = av2 * scS + o2 * scO; av3 = av3 * scS + o3 * scO;
        av4 = av4 * scS + o4 * scO; av5 = av5 * scS + o5 * scO;
        av6 = av6 * scS + o6 * scO; av7 = av7 * scS + o7 * scO;
        m = nm;
    }

    float4 uuA = *(const float4*)&ucu[ch], uuB = *(const float4*)&ucu[ch + 4];
    float4 ccA = *(const float4*)&ucc[ch], ccB = *(const float4*)&ucc[ch + 4];
    float inv = 1.f / (s + 1e-16f);
    uint4 skp = *(const uint4*)&io[(size_t)wid * 128 + ch];
    float r0 = fmaxf((av0 + uuA.x * sea + ccA.x * s) * inv + blo(skp.x), 0.f);
    float r1 = fmaxf((av1 + uuA.y * sea + ccA.y * s) * inv + bhi(skp.x), 0.f);
    float r2 = fmaxf((av2 + uuA.z * sea + ccA.z * s) * inv + blo(skp.y), 0.f);
    float r3 = fmaxf((av3 + uuA.w * sea + ccA.w * s) * inv + bhi(skp.y), 0.f);
    float r4 = fmaxf((av4 + uuB.x * sea + ccB.x * s) * inv + blo(skp.z), 0.f);
    float r5 = fmaxf((av5 + uuB.y * sea + ccB.y * s) * inv + bhi(skp.z), 0.f);
    float r6 = fmaxf((av6 + uuB.z * sea + ccB.z * s) * inv + blo(skp.w), 0.f);
    float r7 = fmaxf((av7 + uuB.w * sea + ccB.w * s) * inv + bhi(skp.w), 0.f);

    if (MODE == 1) {
        if (grp == 0) {
            uint4 hv;
            hv.x = bf16_rne(r0) | (bf16_rne(r1) << 16);
            hv.y = bf16_rne(r2) | (bf16_rne(r3) << 16);
            hv.z = bf16_rne(r4) | (bf16_rne(r5) << 16);
            hv.w = bf16_rne(r6) | (bf16_rne(r7) << 16);
            *(uint4*)&hb[(size_t)wid * 128 + ch] = hv;
        }
    } else {
        float4 wfA = *(const float4*)&Wfc[ch];
        float4 wfB = *(const float4*)&Wfc[ch + 4];
        float rr = r0 * wfA.x + r1 * wfA.y + r2 * wfA.z + r3 * wfA.w
                 + r4 * wfB.x + r5 * wfB.y + r6 * wfB.z + r7 * wfB.w;
#pragma unroll
        for (int off = 1; off < 16; off <<= 1) rr += __shfl_xor(rr, off);
        if (lane == 0) out[wid] = rr + bfc[0];
    }
}

extern "C" void kernel_launch(void* const* d_in, const int* in_sizes, int n_in,
                              void* d_out, int out_size, void* d_ws, size_t ws_size,
                              hipStream_t stream) {
    const float* x      = (const float*)d_in[0];
    const int*   ei     = (const int*)d_in[1];
    const float* ea     = (const float*)d_in[2];
    const float* We_enc = (const float*)d_in[3];
    const float* be_enc = (const float*)d_in[4];
    const float* Wq1 = (const float*)d_in[5],  *bq1 = (const float*)d_in[6];
    const float* Wk1 = (const float*)d_in[7],  *bk1 = (const float*)d_in[8];
    const float* Wv1 = (const float*)d_in[9],  *bv1 = (const float*)d_in[10];
    const float* We1 = (const float*)d_in[11];
    const float* Ws1 = (const float*)d_in[12], *bs1 = (const float*)d_in[13];
    const float* Wq2 = (const float*)d_in[14], *bq2 = (const float*)d_in[15];
    const float* Wk2 = (const float*)d_in[16], *bk2 = (const float*)d_in[17];
    const float* Wv2 = (const float*)d_in[18], *bv2 = (const float*)d_in[19];
    const float* We2 = (const float*)d_in[20];
    const float* Ws2 = (const float*)d_in[21], *bs2 = (const float*)d_in[22];
    const float* Wfc = (const float*)d_in[23], *bfc = (const float*)d_in[24];

    const int n = in_sizes[0] / 6;   // 50000
    const int E = in_sizes[2];       // 409600

    float* ws = (float*)d_ws;
    size_t off = 0;
    unsigned short* qb16 = (unsigned short*)(ws + off); off += (size_t)n * HC / 2;  // q bf16
    unsigned short* sk16 = (unsigned short*)(ws + off); off += (size_t)n * HC / 2;  // skip bf16
    unsigned short* kv16 = (unsigned short*)(ws + off); off += (size_t)n * HC;      // k|v bf16
    int* rowptr = (int*)(ws + off); off += (size_t)(n + 1);
    int* deg    = (int*)(ws + off); off += (size_t)n;   // also scatter cursor
    int* bsum   = (int*)(ws + off); off += 256;
    int* srcs   = (int*)(ws + off); off += (size_t)E;
    float* eas  = ws + off; off += (size_t)E;
    float* uc   = ws + off; off += 512;
    unsigned short* hb16 = (unsigned short*)(ws + off); off += (size_t)n * HC / 2;  // h bf16
    unsigned short* Bph = (unsigned short*)(ws + off); off += 512 * 128 / 2;

    const int eb = (E + 255) / 256;
    const int nb = (n + 255) / 256;
    const int wb = (int)(((size_t)n * 64 + 255) / 256);

    hipLaunchKernelGGL(k_uc, dim3(1), dim3(128), 0, stream, We_enc, be_enc, We1, We2, uc);
    hipLaunchKernelGGL(k_wpack, dim3(256), dim3(256), 0, stream, Wq2, Wk2, Wv2, Ws2, Bph);

    // ---- CSR build (shared by both layers) ----
    hipMemsetAsync(deg, 0, (size_t)n * sizeof(int), stream);
    hipLaunchKernelGGL(k_hist, dim3(eb), dim3(256), 0, stream, ei, deg, E);
    hipLaunchKernelGGL(k_scan1, dim3(nb), dim3(256), 0, stream, deg, bsum, n);
    hipLaunchKernelGGL(k_scan2, dim3(1), dim3(256), 0, stream, bsum, nb);
    hipLaunchKernelGGL(k_scan3, dim3(nb), dim3(256), 0, stream, deg, bsum, rowptr, n, E);
    hipLaunchKernelGGL(k_scatter, dim3(eb), dim3(256), 0, stream, ei, ea, rowptr, deg, srcs, eas, E);

    // ---- layer 1 ----
    hipLaunchKernelGGL(k_lin6, dim3((n + 15) / 16), dim3(256), 0, stream,
                       x, n, Wq1, bq1, Wk1, bk1, Wv1, bv1, Ws1, bs1, qb16, kv16, sk16);
    hipLaunchKernelGGL((k_attn<1>), dim3(wb), dim3(256), 0, stream,
                       qb16, kv16, rowptr, srcs, eas, uc, uc + HC, sk16, hb16,
                       Wfc, bfc, (float*)d_out, n);

    // ---- layer 2 (pure-bf16 MFMA GEMM; q/k/v/skip all bf16) ----
    hipLaunchKernelGGL(k_lin2, dim3((n + 63) / 64), dim3(256), 0, stream,
                       hb16, Bph, bq2, bk2, bv2, bs2, qb16, kv16, sk16, n);
    // ---- layer-2 attn with fused fc head ----
    hipLaunchKernelGGL((k_attn<0>), dim3(wb), dim3(256), 0, stream,
                       qb16, kv16, rowptr, srcs, eas, uc + 2 * HC, uc + 3 * HC, sk16,
                       (unsigned short*)nullptr, Wfc, bfc, (float*)d_out, n);
}

// Round 16
// 196.236 us; speedup vs baseline: 1.4285x; 1.0144x over previous
//
#include <hip/hip_runtime.h>

// TemporalGNN: 2x TransformerConv(H=2, C=64) + edge encoder + fc head.
// Edge encoder rank-1 folded out of the edge loop: a=(q.k+ea*qu+qc)/8.
// Edge phase: counting-sort by dst; one wave per dst node; 4 x 16-lane edge
// streams, dot2-bf16 QK, 2-deep gather prefetch. NO online-max: logits are
// bounded (|a|<<80, clamped at 80), so plain sum-of-exp is overflow-safe --
// removes 1 exp + fmax per edge and breaks the serial rescale chain.
// q/k/v/skip all packed bf16. Layer-2 linears: pure-bf16 MFMA GEMM, 64-node
// blocks, A in registers across the 4 col-quarter loop. fc fused in attn<0>.

#define HC 128   // H*C

typedef __attribute__((ext_vector_type(8))) short bf16x8;
typedef __attribute__((ext_vector_type(4))) float f32x4;
#if __has_builtin(__builtin_amdgcn_fdot2_f32_bf16)
typedef __attribute__((ext_vector_type(2))) __bf16 bf16x2;
#define HAS_DOT2 1
#else
#define HAS_DOT2 0
#endif

__device__ __forceinline__ unsigned bf16_rne(float f) {
    unsigned u = __float_as_uint(f);
    return (u + 0x7fffu + ((u >> 16) & 1u)) >> 16;
}
__device__ __forceinline__ float blo(unsigned u) { return __uint_as_float(u << 16); }
__device__ __forceinline__ float bhi(unsigned u) { return __uint_as_float(u & 0xffff0000u); }

// ---------- rank-1 edge-encoder precompute ----------
__global__ void k_uc(const float* __restrict__ We_enc, const float* __restrict__ be_enc,
                     const float* __restrict__ We1, const float* __restrict__ We2,
                     float* __restrict__ uc) {
    int c = threadIdx.x;  // 0..127
    float u1 = 0.f, c1 = 0.f, u2 = 0.f, c2 = 0.f;
    for (int j = 0; j < 64; ++j) {
        float we = We_enc[j], be = be_enc[j];
        float w1 = We1[j * HC + c], w2 = We2[j * HC + c];
        u1 += we * w1; c1 += be * w1;
        u2 += we * w2; c2 += be * w2;
    }
    uc[c] = u1; uc[HC + c] = c1; uc[2 * HC + c] = u2; uc[3 * HC + c] = c2;
}

// ---------- pack layer-2 weights to bf16, B^T layout [n=512][k=128] ----------
__global__ __launch_bounds__(256) void k_wpack(
    const float* __restrict__ Wq, const float* __restrict__ Wk,
    const float* __restrict__ Wv, const float* __restrict__ Ws,
    unsigned short* __restrict__ Bph) {
    int t = blockIdx.x * 256 + threadIdx.x;   // 0..65535
    int nn = t >> 7;        // 0..511
    int kk = t & 127;
    int mat = nn >> 7, c = nn & 127;
    const float* W = (mat == 0) ? Wq : (mat == 1) ? Wk : (mat == 2) ? Wv : Ws;
    Bph[nn * 128 + kk] = (unsigned short)bf16_rne(W[kk * 128 + c]);
}

// ---------- CSR build (counting sort by dst; bucket order = atomic order) ----------
__global__ __launch_bounds__(256) void k_hist(const int* __restrict__ ei, int* __restrict__ deg, int E) {
    int t = blockIdx.x * blockDim.x + threadIdx.x;
    if (t < E) atomicAdd(&deg[ei[E + t]], 1);
}

__global__ __launch_bounds__(256) void k_scan1(const int* __restrict__ deg, int* __restrict__ bsum, int n) {
    int t = blockIdx.x * 256 + threadIdx.x;
    int v = (t < n) ? deg[t] : 0;
#pragma unroll
    for (int off = 1; off < 64; off <<= 1) v += __shfl_xor(v, off);
    __shared__ int wsum[4];
    int lane = threadIdx.x & 63, w = threadIdx.x >> 6;
    if (lane == 0) wsum[w] = v;
    __syncthreads();
    if (threadIdx.x == 0) bsum[blockIdx.x] = wsum[0] + wsum[1] + wsum[2] + wsum[3];
}

__global__ __launch_bounds__(256) void k_scan2(int* __restrict__ bsum, int nb) {
    __shared__ int sh[256];
    int t = threadIdx.x;
    int v = (t < nb) ? bsum[t] : 0;
    sh[t] = v;
    __syncthreads();
    for (int off = 1; off < 256; off <<= 1) {
        int x = (t >= off) ? sh[t - off] : 0;
        __syncthreads();
        sh[t] += x;
        __syncthreads();
    }
    if (t < nb) bsum[t] = sh[t] - v;   // exclusive
}

// scan3 also zeroes deg (reused as the scatter cursor).
__global__ __launch_bounds__(256) void k_scan3(int* __restrict__ deg, const int* __restrict__ bsum,
                                               int* __restrict__ rowptr, int n, int E) {
    int t = blockIdx.x * 256 + threadIdx.x;
    int tid = threadIdx.x;
    int v = (t < n) ? deg[t] : 0;
    __shared__ int sh[256];
    sh[tid] = v;
    __syncthreads();
    for (int off = 1; off < 256; off <<= 1) {
        int x = (tid >= off) ? sh[tid - off] : 0;
        __syncthreads();
        sh[tid] += x;
        __syncthreads();
    }
    if (t < n) { rowptr[t] = bsum[blockIdx.x] + sh[tid] - v; deg[t] = 0; }
    if (t == 0) rowptr[n] = E;
}

// fused scatter + gather: srcs/eas written directly in bucket slots.
__global__ __launch_bounds__(256) void k_scatter(
    const int* __restrict__ ei, const float* __restrict__ ea,
    const int* __restrict__ rowptr, int* __restrict__ cursor,
    int* __restrict__ srcs, float* __restrict__ eas, int E) {
    int t = blockIdx.x * blockDim.x + threadIdx.x;
    if (t >= E) return;
    int dst = ei[E + t];
    int pos = rowptr[dst] + atomicAdd(&cursor[dst], 1);
    srcs[pos] = ei[t];
    eas[pos] = ea[t];
}

// ---------- layer-1 node linears (K=6, vector ALU) ----------
// q bf16, k/v bf16 interleaved, skip bf16.
__global__ __launch_bounds__(256) void k_lin6(
    const float* __restrict__ X, int n,
    const float* __restrict__ Wq, const float* __restrict__ bq,
    const float* __restrict__ Wk, const float* __restrict__ bk,
    const float* __restrict__ Wv, const float* __restrict__ bv,
    const float* __restrict__ Ws, const float* __restrict__ bs,
    unsigned short* __restrict__ q16, unsigned short* __restrict__ kv,
    unsigned short* __restrict__ sk) {
    __shared__ float xs[16][6];
    const int base = blockIdx.x * 16;
    const int tid = threadIdx.x;
    for (int i = tid; i < 16 * 6; i += 256) {
        int ni = base + i / 6;
        xs[i / 6][i % 6] = (ni < n) ? X[(size_t)ni * 6 + (i % 6)] : 0.f;
    }
    __syncthreads();
    const int c = tid & 127;
    const int m = tid >> 7;  // 0 -> (q,k), 1 -> (v,sk)
    const float* WA = m ? Wv : Wq;
    const float* WB = m ? Ws : Wk;
    float accA[16], accB[16];
#pragma unroll
    for (int i = 0; i < 16; ++i) { accA[i] = 0.f; accB[i] = 0.f; }
    for (int j = 0; j < 6; ++j) {
        float w0 = WA[j * HC + c];
        float w1 = WB[j * HC + c];
#pragma unroll
        for (int i = 0; i < 16; ++i) {
            float xv = xs[i][j];
            accA[i] += xv * w0;
            accB[i] += xv * w1;
        }
    }
    if (m == 0) {
        const float bA = bq[c], bB = bk[c];
#pragma unroll
        for (int i = 0; i < 16; ++i) {
            int ni = base + i;
            if (ni < n) {
                q16[(size_t)ni * HC + c] = (unsigned short)bf16_rne(accA[i] + bA);
                kv[(size_t)ni * 256 + c] = (unsigned short)bf16_rne(accB[i] + bB);
            }
        }
    } else {
        const float bA = bv[c], bB = bs[c];
#pragma unroll
        for (int i = 0; i < 16; ++i) {
            int ni = base + i;
            if (ni < n) {
                kv[(size_t)ni * 256 + 128 + c] = (unsigned short)bf16_rne(accA[i] + bA);
                sk[(size_t)ni * HC + c] = (unsigned short)bf16_rne(accB[i] + bB);
            }
        }
    }
}

// ---------- layer-2 node linears: pure-bf16 MFMA GEMM, LDS-staged B ----------
__global__ __launch_bounds__(256, 4) void k_lin2(
    const unsigned short* __restrict__ hb, const unsigned short* __restrict__ Bph,
    const float* __restrict__ bq, const float* __restrict__ bk,
    const float* __restrict__ bv, const float* __restrict__ bs,
    unsigned short* __restrict__ q16, unsigned short* __restrict__ kv,
    unsigned short* __restrict__ sk, int n) {
    __shared__ unsigned short Bs[128][128];   // 32 KB
    const int tid = threadIdx.x;
    const int wid = tid >> 6, l = tid & 63;
    const int la = l & 15, lk = l >> 4;
    const int mb = blockIdx.x * 64;
    int nodeA = mb + wid * 16 + la;
    if (nodeA >= n) nodeA = n - 1;
    const int sw = (la & 7) << 3;
    const int crow0 = mb + wid * 16 + lk * 4;

    bf16x8 areg[4];
#pragma unroll
    for (int ks = 0; ks < 4; ++ks)
        areg[ks] = *(const bf16x8*)&hb[(size_t)nodeA * 128 + lk * 8 + ks * 32];

    for (int cq = 0; cq < 4; ++cq) {
        if (cq) __syncthreads();
        for (int i = tid; i < 128 * 16; i += 256) {
            int kk8 = i & 15;
            int nnl = i >> 4;
            bf16x8 val = *(const bf16x8*)&Bph[((size_t)(cq * 128 + nnl)) * 128 + kk8 * 8];
            int swk = (kk8 ^ (nnl & 7)) * 8;
            *(bf16x8*)&Bs[nnl][swk] = val;
        }
        __syncthreads();

        f32x4 acc[8];
#pragma unroll
        for (int nt = 0; nt < 8; ++nt) acc[nt] = (f32x4){0.f, 0.f, 0.f, 0.f};
#pragma unroll
        for (int ks = 0; ks < 4; ++ks) {
            const int rk = (lk * 8 + ks * 32) ^ sw;
#pragma unroll
            for (int nt = 0; nt < 8; ++nt) {
                bf16x8 Bh = *(const bf16x8*)&Bs[nt * 16 + la][rk];
                acc[nt] = __builtin_amdgcn_mfma_f32_16x16x32_bf16(areg[ks], Bh, acc[nt], 0, 0, 0);
            }
        }
        const float* bias = (cq == 0) ? bq : (cq == 1) ? bk : (cq == 2) ? bv : bs;
#pragma unroll
        for (int nt = 0; nt < 8; ++nt) {
            const int col = nt * 16 + la;
            const float bb = bias[col];
            if (cq == 0 || cq == 3) {
                unsigned short* out = (cq == 0) ? q16 : sk;
#pragma unroll
                for (int j = 0; j < 4; ++j) {
                    int n0 = crow0 + j;
                    if (n0 < n) out[(size_t)n0 * 128 + col] = (unsigned short)bf16_rne(acc[nt][j] + bb);
                }
            } else {
                const int co = (cq == 1) ? col : 128 + col;
#pragma unroll
                for (int j = 0; j < 4; ++j) {
                    int n0 = crow0 + j;
                    if (n0 < n) kv[(size_t)n0 * 256 + co] = (unsigned short)bf16_rne(acc[nt][j] + bb);
                }
            }
        }
    }
}

// ---------- fused attention (sum-of-exp, no online max), one wave/node ----------
// Wave = 4 x 16-lane groups (edge streams); lane = 8 channels.
// 2-deep gather prefetch. Logits clamped at 80 (exact when never triggered).
// MODE 1: relu(attn+skip) -> bf16 h. MODE 0: fc head fused, writes out[wid].
template <int MODE>
__global__ __launch_bounds__(256) void k_attn(
    const unsigned short* __restrict__ q16, const unsigned short* __restrict__ kvp,
    const int* __restrict__ rowptr, const int* __restrict__ srcs, const float* __restrict__ eas,
    const float* __restrict__ ucu, const float* __restrict__ ucc,
    const unsigned short* __restrict__ io, unsigned short* __restrict__ hb,
    const float* __restrict__ Wfc, const float* __restrict__ bfc,
    float* __restrict__ out, int n) {
    int wid = (int)((blockIdx.x * (size_t)blockDim.x + threadIdx.x) >> 6);
    int lane = threadIdx.x & 63;
    if (wid >= n) return;
    const int grp = lane >> 4;          // 0..3 edge stream
    const int hl = lane & 15;
    const int ch = hl * 8;

    uint4 qp = *(const uint4*)&q16[(size_t)wid * 128 + ch];   // 8 bf16
    float qu, qc;
    {
        float qf0 = blo(qp.x), qf1 = bhi(qp.x), qf2 = blo(qp.y), qf3 = bhi(qp.y);
        float qf4 = blo(qp.z), qf5 = bhi(qp.z), qf6 = blo(qp.w), qf7 = bhi(qp.w);
        float4 uA = *(const float4*)&ucu[ch], uB = *(const float4*)&ucu[ch + 4];
        float4 cA = *(const float4*)&ucc[ch], cB = *(const float4*)&ucc[ch + 4];
        qu = qf0 * uA.x + qf1 * uA.y + qf2 * uA.z + qf3 * uA.w
           + qf4 * uB.x + qf5 * uB.y + qf6 * uB.z + qf7 * uB.w;
        qc = qf0 * cA.x + qf1 * cA.y + qf2 * cA.z + qf3 * cA.w
           + qf4 * cB.x + qf5 * cB.y + qf6 * cB.z + qf7 * cB.w;
#pragma unroll
        for (int off = 1; off < 8; off <<= 1) {
            qu += __shfl_xor(qu, off);
            qc += __shfl_xor(qc, off);
        }
    }

    int b = rowptr[wid], e = rowptr[wid + 1];
    float s = 0.f, sea = 0.f;
    float av0 = 0.f, av1 = 0.f, av2 = 0.f, av3 = 0.f;
    float av4 = 0.f, av5 = 0.f, av6 = 0.f, av7 = 0.f;

    if (b < e) {
        // 2-deep pipeline: cur = iter p, nxt = iter p+4
        int p0 = b + grp;          bool v0 = p0 < e; int c0 = v0 ? p0 : e - 1;
        int p1 = b + 4 + grp;      bool v1 = p1 < e; int c1 = v1 ? p1 : e - 1;
        int s0 = srcs[c0], s1 = srcs[c1];
        float ea0 = eas[c0], ea1 = eas[c1];
        const unsigned short* r0p = &kvp[(size_t)s0 * 256 + ch];
        const unsigned short* r1p = &kvp[(size_t)s1 * 256 + ch];
        uint4 ku0 = *(const uint4*)r0p, vu0 = *(const uint4*)(r0p + 128);
        uint4 ku1 = *(const uint4*)r1p, vu1 = *(const uint4*)(r1p + 128);
        for (int p = b; p < e; p += 4) {
            // prefetch iter p+8
            int p2 = p + 8 + grp;
            bool v2 = p2 < e; int c2 = v2 ? p2 : e - 1;
            int s2 = srcs[c2];
            float ea2 = eas[c2];
            const unsigned short* r2p = &kvp[(size_t)s2 * 256 + ch];
            uint4 ku2 = *(const uint4*)r2p, vu2 = *(const uint4*)(r2p + 128);

            float d;
#if HAS_DOT2
            d = __builtin_amdgcn_fdot2_f32_bf16(
                    __builtin_bit_cast(bf16x2, ku0.x), __builtin_bit_cast(bf16x2, qp.x),
                __builtin_amdgcn_fdot2_f32_bf16(
                    __builtin_bit_cast(bf16x2, ku0.y), __builtin_bit_cast(bf16x2, qp.y),
                __builtin_amdgcn_fdot2_f32_bf16(
                    __builtin_bit_cast(bf16x2, ku0.z), __builtin_bit_cast(bf16x2, qp.z),
                __builtin_amdgcn_fdot2_f32_bf16(
                    __builtin_bit_cast(bf16x2, ku0.w), __builtin_bit_cast(bf16x2, qp.w),
                    0.f, false), false), false), false);
#else
            d = blo(qp.x) * blo(ku0.x) + bhi(qp.x) * bhi(ku0.x)
              + blo(qp.y) * blo(ku0.y) + bhi(qp.y) * bhi(ku0.y)
              + blo(qp.z) * blo(ku0.z) + bhi(qp.z) * bhi(ku0.z)
              + blo(qp.w) * blo(ku0.w) + bhi(qp.w) * bhi(ku0.w);
#endif
            d += __shfl_xor(d, 1); d += __shfl_xor(d, 2); d += __shfl_xor(d, 4);
            float a = v0 ? fminf((d + fmaf(ea0, qu, qc)) * 0.125f, 80.f) : -INFINITY;
            float pw = __expf(a);      // exp(-inf) = 0 for invalid lanes
            s += pw;
            sea = fmaf(pw, ea0, sea);
            av0 = fmaf(pw, blo(vu0.x), av0);
            av1 = fmaf(pw, bhi(vu0.x), av1);
            av2 = fmaf(pw, blo(vu0.y), av2);
            av3 = fmaf(pw, bhi(vu0.y), av3);
            av4 = fmaf(pw, blo(vu0.z), av4);
            av5 = fmaf(pw, bhi(vu0.z), av5);
            av6 = fmaf(pw, blo(vu0.w), av6);
            av7 = fmaf(pw, bhi(vu0.w), av7);
            ku0 = ku1; vu0 = vu1; ea0 = ea1; v0 = v1;
            ku1 = ku2; vu1 = vu2; ea1 = ea2; v1 = v2;
        }
    }

    // merge streams: plain sums over xor 16 then xor 32
#pragma unroll
    for (int M = 16; M <= 32; M <<= 1) {
        s += __shfl_xor(s, M);
        sea += __shfl_xor(sea, M);
        av0 += __shfl_xor(av0, M); av1 += __shfl_xor(av1, M);
        av2 += __shfl_xor(av2, M); av3 += __shfl_xor(av3, M);
        av4 += __shfl_xor(av4, M); av5 += __shfl_xor(av5, M);
        av6 += __shfl_xor(av6, M); av7 += __shfl_xor(av7, M);
    }

    float4 uuA = *(const float4*)&ucu[ch], uuB = *(const float4*)&ucu[ch + 4];
    float4 ccA = *(const float4*)&ucc[ch], ccB = *(const float4*)&ucc[ch + 4];
    float inv = 1.f / (s + 1e-16f);
    uint4 skp = *(const uint4*)&io[(size_t)wid * 128 + ch];
    float r0 = fmaxf((av0 + uuA.x * sea + ccA.x * s) * inv + blo(skp.x), 0.f);
    float r1 = fmaxf((av1 + uuA.y * sea + ccA.y * s) * inv + bhi(skp.x), 0.f);
    float r2 = fmaxf((av2 + uuA.z * sea + ccA.z * s) * inv + blo(skp.y), 0.f);
    float r3 = fmaxf((av3 + uuA.w * sea + ccA.w * s) * inv + bhi(skp.y), 0.f);
    float r4 = fmaxf((av4 + uuB.x * sea + ccB.x * s) * inv + blo(skp.z), 0.f);
    float r5 = fmaxf((av5 + uuB.y * sea + ccB.y * s) * inv + bhi(skp.z), 0.f);
    float r6 = fmaxf((av6 + uuB.z * sea + ccB.z * s) * inv + blo(skp.w), 0.f);
    float r7 = fmaxf((av7 + uuB.w * sea + ccB.w * s) * inv + bhi(skp.w), 0.f);

    if (MODE == 1) {
        if (grp == 0) {
            uint4 hv;
            hv.x = bf16_rne(r0) | (bf16_rne(r1) << 16);
            hv.y = bf16_rne(r2) | (bf16_rne(r3) << 16);
            hv.z = bf16_rne(r4) | (bf16_rne(r5) << 16);
            hv.w = bf16_rne(r6) | (bf16_rne(r7) << 16);
            *(uint4*)&hb[(size_t)wid * 128 + ch] = hv;
        }
    } else {
        float4 wfA = *(const float4*)&Wfc[ch];
        float4 wfB = *(const float4*)&Wfc[ch + 4];
        float rr = r0 * wfA.x + r1 * wfA.y + r2 * wfA.z + r3 * wfA.w
                 + r4 * wfB.x + r5 * wfB.y + r6 * wfB.z + r7 * wfB.w;
#pragma unroll
        for (int off = 1; off < 16; off <<= 1) rr += __shfl_xor(rr, off);
        if (lane == 0) out[wid] = rr + bfc[0];
    }
}

extern "C" void kernel_launch(void* const* d_in, const int* in_sizes, int n_in,
                              void* d_out, int out_size, void* d_ws, size_t ws_size,
                              hipStream_t stream) {
    const float* x      = (const float*)d_in[0];
    const int*   ei     = (const int*)d_in[1];
    const float* ea     = (const float*)d_in[2];
    const float* We_enc = (const float*)d_in[3];
    const float* be_enc = (const float*)d_in[4];
    const float* Wq1 = (const float*)d_in[5],  *bq1 = (const float*)d_in[6];
    const float* Wk1 = (const float*)d_in[7],  *bk1 = (const float*)d_in[8];
    const float* Wv1 = (const float*)d_in[9],  *bv1 = (const float*)d_in[10];
    const float* We1 = (const float*)d_in[11];
    const float* Ws1 = (const float*)d_in[12], *bs1 = (const float*)d_in[13];
    const float* Wq2 = (const float*)d_in[14], *bq2 = (const float*)d_in[15];
    const float* Wk2 = (const float*)d_in[16], *bk2 = (const float*)d_in[17];
    const float* Wv2 = (const float*)d_in[18], *bv2 = (const float*)d_in[19];
    const float* We2 = (const float*)d_in[20];
    const float* Ws2 = (const float*)d_in[21], *bs2 = (const float*)d_in[22];
    const float* Wfc = (const float*)d_in[23], *bfc = (const float*)d_in[24];

    const int n = in_sizes[0] / 6;   // 50000
    const int E = in_sizes[2];       // 409600

    float* ws = (float*)d_ws;
    size_t off = 0;
    unsigned short* qb16 = (unsigned short*)(ws + off); off += (size_t)n * HC / 2;  // q bf16
    unsigned short* sk16 = (unsigned short*)(ws + off); off += (size_t)n * HC / 2;  // skip bf16
    unsigned short* kv16 = (unsigned short*)(ws + off); off += (size_t)n * HC;      // k|v bf16
    int* rowptr = (int*)(ws + off); off += (size_t)(n + 1);
    int* deg    = (int*)(ws + off); off += (size_t)n;   // also scatter cursor
    int* bsum   = (int*)(ws + off); off += 256;
    int* srcs   = (int*)(ws + off); off += (size_t)E;
    float* eas  = ws + off; off += (size_t)E;
    float* uc   = ws + off; off += 512;
    unsigned short* hb16 = (unsigned short*)(ws + off); off += (size_t)n * HC / 2;  // h bf16
    unsigned short* Bph = (unsigned short*)(ws + off); off += 512 * 128 / 2;

    const int eb = (E + 255) / 256;
    const int nb = (n + 255) / 256;
    const int wb = (int)(((size_t)n * 64 + 255) / 256);

    hipLaunchKernelGGL(k_uc, dim3(1), dim3(128), 0, stream, We_enc, be_enc, We1, We2, uc);
    hipLaunchKernelGGL(k_wpack, dim3(256), dim3(256), 0, stream, Wq2, Wk2, Wv2, Ws2, Bph);

    // ---- CSR build (shared by both layers) ----
    hipMemsetAsync(deg, 0, (size_t)n * sizeof(int), stream);
    hipLaunchKernelGGL(k_hist, dim3(eb), dim3(256), 0, stream, ei, deg, E);
    hipLaunchKernelGGL(k_scan1, dim3(nb), dim3(256), 0, stream, deg, bsum, n);
    hipLaunchKernelGGL(k_scan2, dim3(1), dim3(256), 0, stream, bsum, nb);
    hipLaunchKernelGGL(k_scan3, dim3(nb), dim3(256), 0, stream, deg, bsum, rowptr, n, E);
    hipLaunchKernelGGL(k_scatter, dim3(eb), dim3(256), 0, stream, ei, ea, rowptr, deg, srcs, eas, E);

    // ---- layer 1 ----
    hipLaunchKernelGGL(k_lin6, dim3((n + 15) / 16), dim3(256), 0, stream,
                       x, n, Wq1, bq1, Wk1, bk1, Wv1, bv1, Ws1, bs1, qb16, kv16, sk16);
    hipLaunchKernelGGL((k_attn<1>), dim3(wb), dim3(256), 0, stream,
                       qb16, kv16, rowptr, srcs, eas, uc, uc + HC, sk16, hb16,
                       Wfc, bfc, (float*)d_out, n);

    // ---- layer 2 (pure-bf16 MFMA GEMM; q/k/v/skip all bf16) ----
    hipLaunchKernelGGL(k_lin2, dim3((n + 63) / 64), dim3(256), 0, stream,
                       hb16, Bph, bq2, bk2, bv2, bs2, qb16, kv16, sk16, n);
    // ---- layer-2 attn with fused fc head ----
    hipLaunchKernelGGL((k_attn<0>), dim3(wb), dim3(256), 0, stream,
                       qb16, kv16, rowptr, srcs, eas, uc + 2 * HC, uc + 3 * HC, sk16,
                       (unsigned short*)nullptr, Wfc, bfc, (float*)d_out, n);
}

// Round 17
// 191.010 us; speedup vs baseline: 1.4676x; 1.0274x over previous
//
#include <hip/hip_runtime.h>

// TemporalGNN: 2x TransformerConv(H=2, C=64) + edge encoder + fc head.
// Edge encoder rank-1 folded out of the edge loop: a=(q.k+ea*qu+qc)/8.
// Edge phase: counting-sort by dst; ONE WAVE PER BLOCK per dst node (indep
// retirement -> no intra-block load imbalance); 4 x 16-lane edge streams,
// dot2-bf16 QK, 2-deep gather prefetch over a 16-entry-padded (src,ea) int2
// array (no clamp bookkeeping). Sum-of-exp softmax (logits bounded, clamp 80).
// q/k/v/skip all packed bf16. Layer-2 linears: pure-bf16 MFMA GEMM, 64-node
// blocks, A in registers across the 4 col-quarter loop. fc fused in attn<0>.

#define HC 128   // H*C

typedef __attribute__((ext_vector_type(8))) short bf16x8;
typedef __attribute__((ext_vector_type(4))) float f32x4;
#if __has_builtin(__builtin_amdgcn_fdot2_f32_bf16)
typedef __attribute__((ext_vector_type(2))) __bf16 bf16x2;
#define HAS_DOT2 1
#else
#define HAS_DOT2 0
#endif

__device__ __forceinline__ unsigned bf16_rne(float f) {
    unsigned u = __float_as_uint(f);
    return (u + 0x7fffu + ((u >> 16) & 1u)) >> 16;
}
__device__ __forceinline__ float blo(unsigned u) { return __uint_as_float(u << 16); }
__device__ __forceinline__ float bhi(unsigned u) { return __uint_as_float(u & 0xffff0000u); }

// ---------- fused: rank-1 edge-encoder precompute + layer-2 weight pack ----------
// blocks 0..255: pack Wq2/Wk2/Wv2/Ws2 -> bf16 B^T [512][128]. block 256: uc.
__global__ __launch_bounds__(256) void k_prep(
    const float* __restrict__ We_enc, const float* __restrict__ be_enc,
    const float* __restrict__ We1, const float* __restrict__ We2,
    const float* __restrict__ Wq, const float* __restrict__ Wk,
    const float* __restrict__ Wv, const float* __restrict__ Ws,
    float* __restrict__ uc, unsigned short* __restrict__ Bph) {
    if (blockIdx.x == 256) {
        int c = threadIdx.x;
        if (c < 128) {
            float u1 = 0.f, c1 = 0.f, u2 = 0.f, c2 = 0.f;
            for (int j = 0; j < 64; ++j) {
                float we = We_enc[j], be = be_enc[j];
                float w1 = We1[j * HC + c], w2 = We2[j * HC + c];
                u1 += we * w1; c1 += be * w1;
                u2 += we * w2; c2 += be * w2;
            }
            uc[c] = u1; uc[HC + c] = c1; uc[2 * HC + c] = u2; uc[3 * HC + c] = c2;
        }
        return;
    }
    int t = blockIdx.x * 256 + threadIdx.x;   // 0..65535
    int nn = t >> 7;
    int kk = t & 127;
    int mat = nn >> 7, c = nn & 127;
    const float* W = (mat == 0) ? Wq : (mat == 1) ? Wk : (mat == 2) ? Wv : Ws;
    Bph[nn * 128 + kk] = (unsigned short)bf16_rne(W[kk * 128 + c]);
}

// ---------- CSR build (counting sort by dst; bucket order = atomic order) ----------
__global__ __launch_bounds__(256) void k_hist(const int* __restrict__ ei, int* __restrict__ deg, int E) {
    int t = blockIdx.x * blockDim.x + threadIdx.x;
    if (t < E) atomicAdd(&deg[ei[E + t]], 1);
}

__global__ __launch_bounds__(256) void k_scan1(const int* __restrict__ deg, int* __restrict__ bsum, int n) {
    int t = blockIdx.x * 256 + threadIdx.x;
    int v = (t < n) ? deg[t] : 0;
#pragma unroll
    for (int off = 1; off < 64; off <<= 1) v += __shfl_xor(v, off);
    __shared__ int wsum[4];
    int lane = threadIdx.x & 63, w = threadIdx.x >> 6;
    if (lane == 0) wsum[w] = v;
    __syncthreads();
    if (threadIdx.x == 0) bsum[blockIdx.x] = wsum[0] + wsum[1] + wsum[2] + wsum[3];
}

__global__ __launch_bounds__(256) void k_scan2(int* __restrict__ bsum, int nb) {
    __shared__ int sh[256];
    int t = threadIdx.x;
    int v = (t < nb) ? bsum[t] : 0;
    sh[t] = v;
    __syncthreads();
    for (int off = 1; off < 256; off <<= 1) {
        int x = (t >= off) ? sh[t - off] : 0;
        __syncthreads();
        sh[t] += x;
        __syncthreads();
    }
    if (t < nb) bsum[t] = sh[t] - v;   // exclusive
}

// scan3 also zeroes deg (reused as the scatter cursor).
__global__ __launch_bounds__(256) void k_scan3(int* __restrict__ deg, const int* __restrict__ bsum,
                                               int* __restrict__ rowptr, int n, int E) {
    int t = blockIdx.x * 256 + threadIdx.x;
    int tid = threadIdx.x;
    int v = (t < n) ? deg[t] : 0;
    __shared__ int sh[256];
    sh[tid] = v;
    __syncthreads();
    for (int off = 1; off < 256; off <<= 1) {
        int x = (tid >= off) ? sh[tid - off] : 0;
        __syncthreads();
        sh[tid] += x;
        __syncthreads();
    }
    if (t < n) { rowptr[t] = bsum[blockIdx.x] + sh[tid] - v; deg[t] = 0; }
    if (t == 0) rowptr[n] = E;
}

// fused scatter + gather: (src, ea) packed int2, written to bucket slots.
// Threads 0..15 also zero-fill the 16-entry pad so attn prefetch is unclamped.
__global__ __launch_bounds__(256) void k_scatter(
    const int* __restrict__ ei, const float* __restrict__ ea,
    const int* __restrict__ rowptr, int* __restrict__ cursor,
    int2* __restrict__ sep, int E) {
    int t = blockIdx.x * blockDim.x + threadIdx.x;
    if (t < 16 && blockIdx.x == 0) sep[E + t] = make_int2(0, 0);
    if (t >= E) return;
    int dst = ei[E + t];
    int pos = rowptr[dst] + atomicAdd(&cursor[dst], 1);
    sep[pos] = make_int2(ei[t], __float_as_int(ea[t]));
}

// ---------- layer-1 node linears (K=6, vector ALU) ----------
// q bf16, k/v bf16 interleaved, skip bf16.
__global__ __launch_bounds__(256) void k_lin6(
    const float* __restrict__ X, int n,
    const float* __restrict__ Wq, const float* __restrict__ bq,
    const float* __restrict__ Wk, const float* __restrict__ bk,
    const float* __restrict__ Wv, const float* __restrict__ bv,
    const float* __restrict__ Ws, const float* __restrict__ bs,
    unsigned short* __restrict__ q16, unsigned short* __restrict__ kv,
    unsigned short* __restrict__ sk) {
    __shared__ float xs[16][6];
    const int base = blockIdx.x * 16;
    const int tid = threadIdx.x;
    for (int i = tid; i < 16 * 6; i += 256) {
        int ni = base + i / 6;
        xs[i / 6][i % 6] = (ni < n) ? X[(size_t)ni * 6 + (i % 6)] : 0.f;
    }
    __syncthreads();
    const int c = tid & 127;
    const int m = tid >> 7;  // 0 -> (q,k), 1 -> (v,sk)
    const float* WA = m ? Wv : Wq;
    const float* WB = m ? Ws : Wk;
    float accA[16], accB[16];
#pragma unroll
    for (int i = 0; i < 16; ++i) { accA[i] = 0.f; accB[i] = 0.f; }
    for (int j = 0; j < 6; ++j) {
        float w0 = WA[j * HC + c];
        float w1 = WB[j * HC + c];
#pragma unroll
        for (int i = 0; i < 16; ++i) {
            float xv = xs[i][j];
            accA[i] += xv * w0;
            accB[i] += xv * w1;
        }
    }
    if (m == 0) {
        const float bA = bq[c], bB = bk[c];
#pragma unroll
        for (int i = 0; i < 16; ++i) {
            int ni = base + i;
            if (ni < n) {
                q16[(size_t)ni * HC + c] = (unsigned short)bf16_rne(accA[i] + bA);
                kv[(size_t)ni * 256 + c] = (unsigned short)bf16_rne(accB[i] + bB);
            }
        }
    } else {
        const float bA = bv[c], bB = bs[c];
#pragma unroll
        for (int i = 0; i < 16; ++i) {
            int ni = base + i;
            if (ni < n) {
                kv[(size_t)ni * 256 + 128 + c] = (unsigned short)bf16_rne(accA[i] + bA);
                sk[(size_t)ni * HC + c] = (unsigned short)bf16_rne(accB[i] + bB);
            }
        }
    }
}

// ---------- layer-2 node linears: pure-bf16 MFMA GEMM, LDS-staged B ----------
__global__ __launch_bounds__(256, 4) void k_lin2(
    const unsigned short* __restrict__ hb, const unsigned short* __restrict__ Bph,
    const float* __restrict__ bq, const float* __restrict__ bk,
    const float* __restrict__ bv, const float* __restrict__ bs,
    unsigned short* __restrict__ q16, unsigned short* __restrict__ kv,
    unsigned short* __restrict__ sk, int n) {
    __shared__ unsigned short Bs[128][128];   // 32 KB
    const int tid = threadIdx.x;
    const int wid = tid >> 6, l = tid & 63;
    const int la = l & 15, lk = l >> 4;
    const int mb = blockIdx.x * 64;
    int nodeA = mb + wid * 16 + la;
    if (nodeA >= n) nodeA = n - 1;
    const int sw = (la & 7) << 3;
    const int crow0 = mb + wid * 16 + lk * 4;

    bf16x8 areg[4];
#pragma unroll
    for (int ks = 0; ks < 4; ++ks)
        areg[ks] = *(const bf16x8*)&hb[(size_t)nodeA * 128 + lk * 8 + ks * 32];

    for (int cq = 0; cq < 4; ++cq) {
        if (cq) __syncthreads();
        for (int i = tid; i < 128 * 16; i += 256) {
            int kk8 = i & 15;
            int nnl = i >> 4;
            bf16x8 val = *(const bf16x8*)&Bph[((size_t)(cq * 128 + nnl)) * 128 + kk8 * 8];
            int swk = (kk8 ^ (nnl & 7)) * 8;
            *(bf16x8*)&Bs[nnl][swk] = val;
        }
        __syncthreads();

        f32x4 acc[8];
#pragma unroll
        for (int nt = 0; nt < 8; ++nt) acc[nt] = (f32x4){0.f, 0.f, 0.f, 0.f};
#pragma unroll
        for (int ks = 0; ks < 4; ++ks) {
            const int rk = (lk * 8 + ks * 32) ^ sw;
#pragma unroll
            for (int nt = 0; nt < 8; ++nt) {
                bf16x8 Bh = *(const bf16x8*)&Bs[nt * 16 + la][rk];
                acc[nt] = __builtin_amdgcn_mfma_f32_16x16x32_bf16(areg[ks], Bh, acc[nt], 0, 0, 0);
            }
        }
        const float* bias = (cq == 0) ? bq : (cq == 1) ? bk : (cq == 2) ? bv : bs;
#pragma unroll
        for (int nt = 0; nt < 8; ++nt) {
            const int col = nt * 16 + la;
            const float bb = bias[col];
            if (cq == 0 || cq == 3) {
                unsigned short* out = (cq == 0) ? q16 : sk;
#pragma unroll
                for (int j = 0; j < 4; ++j) {
                    int n0 = crow0 + j;
                    if (n0 < n) out[(size_t)n0 * 128 + col] = (unsigned short)bf16_rne(acc[nt][j] + bb);
                }
            } else {
                const int co = (cq == 1) ? col : 128 + col;
#pragma unroll
                for (int j = 0; j < 4; ++j) {
                    int n0 = crow0 + j;
                    if (n0 < n) kv[(size_t)n0 * 256 + co] = (unsigned short)bf16_rne(acc[nt][j] + bb);
                }
            }
        }
    }
}

// ---------- fused attention (sum-of-exp), ONE WAVE PER BLOCK per dst node ----------
// 4 x 16-lane edge streams; lane = 8 channels; 2-deep prefetch, no clamps
// (sep padded by 16). MODE 1: relu(attn+skip) -> bf16 h. MODE 0: fc fused.
template <int MODE>
__global__ __launch_bounds__(64) void k_attn(
    const unsigned short* __restrict__ q16, const unsigned short* __restrict__ kvp,
    const int* __restrict__ rowptr, const int2* __restrict__ sep,
    const float* __restrict__ ucu, const float* __restrict__ ucc,
    const unsigned short* __restrict__ io, unsigned short* __restrict__ hb,
    const float* __restrict__ Wfc, const float* __restrict__ bfc,
    float* __restrict__ out, int n) {
    int wid = blockIdx.x;
    int lane = threadIdx.x & 63;
    if (wid >= n) return;
    const int grp = lane >> 4;          // 0..3 edge stream
    const int hl = lane & 15;
    const int ch = hl * 8;

    uint4 qp = *(const uint4*)&q16[(size_t)wid * 128 + ch];   // 8 bf16
    float qu, qc;
    {
        float qf0 = blo(qp.x), qf1 = bhi(qp.x), qf2 = blo(qp.y), qf3 = bhi(qp.y);
        float qf4 = blo(qp.z), qf5 = bhi(qp.z), qf6 = blo(qp.w), qf7 = bhi(qp.w);
        float4 uA = *(const float4*)&ucu[ch], uB = *(const float4*)&ucu[ch + 4];
        float4 cA = *(const float4*)&ucc[ch], cB = *(const float4*)&ucc[ch + 4];
        qu = qf0 * uA.x + qf1 * uA.y + qf2 * uA.z + qf3 * uA.w
           + qf4 * uB.x + qf5 * uB.y + qf6 * uB.z + qf7 * uB.w;
        qc = qf0 * cA.x + qf1 * cA.y + qf2 * cA.z + qf3 * cA.w
           + qf4 * cB.x + qf5 * cB.y + qf6 * cB.z + qf7 * cB.w;
#pragma unroll
        for (int off = 1; off < 8; off <<= 1) {
            qu += __shfl_xor(qu, off);
            qc += __shfl_xor(qc, off);
        }
    }

    int b = rowptr[wid], e = rowptr[wid + 1];
    float s = 0.f, sea = 0.f;
    float av0 = 0.f, av1 = 0.f, av2 = 0.f, av3 = 0.f;
    float av4 = 0.f, av5 = 0.f, av6 = 0.f, av7 = 0.f;

    if (b < e) {
        // 2-deep pipeline, unclamped indices (sep padded by 16 entries)
        int p0 = b + grp;      bool v0 = p0 < e;
        int p1 = p0 + 4;       bool v1 = p1 < e;
        int2 se0 = sep[p0];
        int2 se1 = sep[p1];
        const unsigned short* r0p = &kvp[(size_t)se0.x * 256 + ch];
        const unsigned short* r1p = &kvp[(size_t)se1.x * 256 + ch];
        uint4 ku0 = *(const uint4*)r0p, vu0 = *(const uint4*)(r0p + 128);
        uint4 ku1 = *(const uint4*)r1p, vu1 = *(const uint4*)(r1p + 128);
        for (int p = b; p < e; p += 4) {
            int p2 = p + 8 + grp;
            bool v2 = p2 < e;
            int2 se2 = sep[p2];
            const unsigned short* r2p = &kvp[(size_t)se2.x * 256 + ch];
            uint4 ku2 = *(const uint4*)r2p, vu2 = *(const uint4*)(r2p + 128);

            float ea0 = __int_as_float(se0.y);
            float d;
#if HAS_DOT2
            d = __builtin_amdgcn_fdot2_f32_bf16(
                    __builtin_bit_cast(bf16x2, ku0.x), __builtin_bit_cast(bf16x2, qp.x),
                __builtin_amdgcn_fdot2_f32_bf16(
                    __builtin_bit_cast(bf16x2, ku0.y), __builtin_bit_cast(bf16x2, qp.y),
                __builtin_amdgcn_fdot2_f32_bf16(
                    __builtin_bit_cast(bf16x2, ku0.z), __builtin_bit_cast(bf16x2, qp.z),
                __builtin_amdgcn_fdot2_f32_bf16(
                    __builtin_bit_cast(bf16x2, ku0.w), __builtin_bit_cast(bf16x2, qp.w),
                    0.f, false), false), false), false);
#else
            d = blo(qp.x) * blo(ku0.x) + bhi(qp.x) * bhi(ku0.x)
              + blo(qp.y) * blo(ku0.y) + bhi(qp.y) * bhi(ku0.y)
              + blo(qp.z) * blo(ku0.z) + bhi(qp.z) * bhi(ku0.z)
              + blo(qp.w) * blo(ku0.w) + bhi(qp.w) * bhi(ku0.w);
#endif
            d += __shfl_xor(d, 1); d += __shfl_xor(d, 2); d += __shfl_xor(d, 4);
            float a = v0 ? fminf((d + fmaf(ea0, qu, qc)) * 0.125f, 80.f) : -INFINITY;
            float pw = __expf(a);      // exp(-inf) = 0 for invalid lanes
            s += pw;
            sea = fmaf(pw, ea0, sea);
            av0 = fmaf(pw, blo(vu0.x), av0);
            av1 = fmaf(pw, bhi(vu0.x), av1);
            av2 = fmaf(pw, blo(vu0.y), av2);
            av3 = fmaf(pw, bhi(vu0.y), av3);
            av4 = fmaf(pw, blo(vu0.z), av4);
            av5 = fmaf(pw, bhi(vu0.z), av5);
            av6 = fmaf(pw, blo(vu0.w), av6);
            av7 = fmaf(pw, bhi(vu0.w), av7);
            ku0 = ku1; vu0 = vu1; se0 = se1; v0 = v1;
            ku1 = ku2; vu1 = vu2; se1 = se2; v1 = v2;
        }
    }

    // merge streams: plain sums over xor 16 then xor 32
#pragma unroll
    for (int M = 16; M <= 32; M <<= 1) {
        s += __shfl_xor(s, M);
        sea += __shfl_xor(sea, M);
        av0 += __shfl_xor(av0, M); av1 += __shfl_xor(av1, M);
        av2 += __shfl_xor(av2, M); av3 += __shfl_xor(av3, M);
        av4 += __shfl_xor(av4, M); av5 += __shfl_xor(av5, M);
        av6 += __shfl_xor(av6, M); av7 += __shfl_xor(av7, M);
    }

    float4 uuA = *(const float4*)&ucu[ch], uuB = *(const float4*)&ucu[ch + 4];
    float4 ccA = *(const float4*)&ucc[ch], ccB = *(const float4*)&ucc[ch + 4];
    float inv = 1.f / (s + 1e-16f);
    uint4 skp = *(const uint4*)&io[(size_t)wid * 128 + ch];
    float r0 = fmaxf((av0 + uuA.x * sea + ccA.x * s) * inv + blo(skp.x), 0.f);
    float r1 = fmaxf((av1 + uuA.y * sea + ccA.y * s) * inv + bhi(skp.x), 0.f);
    float r2 = fmaxf((av2 + uuA.z * sea + ccA.z * s) * inv + blo(skp.y), 0.f);
    float r3 = fmaxf((av3 + uuA.w * sea + ccA.w * s) * inv + bhi(skp.y), 0.f);
    float r4 = fmaxf((av4 + uuB.x * sea + ccB.x * s) * inv + blo(skp.z), 0.f);
    float r5 = fmaxf((av5 + uuB.y * sea + ccB.y * s) * inv + bhi(skp.z), 0.f);
    float r6 = fmaxf((av6 + uuB.z * sea + ccB.z * s) * inv + blo(skp.w), 0.f);
    float r7 = fmaxf((av7 + uuB.w * sea + ccB.w * s) * inv + bhi(skp.w), 0.f);

    if (MODE == 1) {
        if (grp == 0) {
            uint4 hv;
            hv.x = bf16_rne(r0) | (bf16_rne(r1) << 16);
            hv.y = bf16_rne(r2) | (bf16_rne(r3) << 16);
            hv.z = bf16_rne(r4) | (bf16_rne(r5) << 16);
            hv.w = bf16_rne(r6) | (bf16_rne(r7) << 16);
            *(uint4*)&hb[(size_t)wid * 128 + ch] = hv;
        }
    } else {
        float4 wfA = *(const float4*)&Wfc[ch];
        float4 wfB = *(const float4*)&Wfc[ch + 4];
        float rr = r0 * wfA.x + r1 * wfA.y + r2 * wfA.z + r3 * wfA.w
                 + r4 * wfB.x + r5 * wfB.y + r6 * wfB.z + r7 * wfB.w;
#pragma unroll
        for (int off = 1; off < 16; off <<= 1) rr += __shfl_xor(rr, off);
        if (lane == 0) out[wid] = rr + bfc[0];
    }
}

extern "C" void kernel_launch(void* const* d_in, const int* in_sizes, int n_in,
                              void* d_out, int out_size, void* d_ws, size_t ws_size,
                              hipStream_t stream) {
    const float* x      = (const float*)d_in[0];
    const int*   ei     = (const int*)d_in[1];
    const float* ea     = (const float*)d_in[2];
    const float* We_enc = (const float*)d_in[3];
    const float* be_enc = (const float*)d_in[4];
    const float* Wq1 = (const float*)d_in[5],  *bq1 = (const float*)d_in[6];
    const float* Wk1 = (const float*)d_in[7],  *bk1 = (const float*)d_in[8];
    const float* Wv1 = (const float*)d_in[9],  *bv1 = (const float*)d_in[10];
    const float* We1 = (const float*)d_in[11];
    const float* Ws1 = (const float*)d_in[12], *bs1 = (const float*)d_in[13];
    const float* Wq2 = (const float*)d_in[14], *bq2 = (const float*)d_in[15];
    const float* Wk2 = (const float*)d_in[16], *bk2 = (const float*)d_in[17];
    const float* Wv2 = (const float*)d_in[18], *bv2 = (const float*)d_in[19];
    const float* We2 = (const float*)d_in[20];
    const float* Ws2 = (const float*)d_in[21], *bs2 = (const float*)d_in[22];
    const float* Wfc = (const float*)d_in[23], *bfc = (const float*)d_in[24];

    const int n = in_sizes[0] / 6;   // 50000
    const int E = in_sizes[2];       // 409600

    float* ws = (float*)d_ws;
    size_t off = 0;
    unsigned short* qb16 = (unsigned short*)(ws + off); off += (size_t)n * HC / 2;  // q bf16
    unsigned short* sk16 = (unsigned short*)(ws + off); off += (size_t)n * HC / 2;  // skip bf16
    unsigned short* kv16 = (unsigned short*)(ws + off); off += (size_t)n * HC;      // k|v bf16
    int* rowptr = (int*)(ws + off); off += (size_t)(n + 1);
    int* deg    = (int*)(ws + off); off += (size_t)n;   // also scatter cursor
    int* bsum   = (int*)(ws + off); off += 256;
    int2* sep   = (int2*)(ws + off); off += 2 * ((size_t)E + 16);   // (src, ea) packed, +16 pad
    float* uc   = ws + off; off += 512;
    unsigned short* hb16 = (unsigned short*)(ws + off); off += (size_t)n * HC / 2;  // h bf16
    unsigned short* Bph = (unsigned short*)(ws + off); off += 512 * 128 / 2;

    const int eb = (E + 255) / 256;
    const int nb = (n + 255) / 256;

    hipLaunchKernelGGL(k_prep, dim3(257), dim3(256), 0, stream,
                       We_enc, be_enc, We1, We2, Wq2, Wk2, Wv2, Ws2, uc, Bph);

    // ---- CSR build (shared by both layers) ----
    hipMemsetAsync(deg, 0, (size_t)n * sizeof(int), stream);
    hipLaunchKernelGGL(k_hist, dim3(eb), dim3(256), 0, stream, ei, deg, E);
    hipLaunchKernelGGL(k_scan1, dim3(nb), dim3(256), 0, stream, deg, bsum, n);
    hipLaunchKernelGGL(k_scan2, dim3(1), dim3(256), 0, stream, bsum, nb);
    hipLaunchKernelGGL(k_scan3, dim3(nb), dim3(256), 0, stream, deg, bsum, rowptr, n, E);
    hipLaunchKernelGGL(k_scatter, dim3(eb), dim3(256), 0, stream, ei, ea, rowptr, deg, sep, E);

    // ---- layer 1 ----
    hipLaunchKernelGGL(k_lin6, dim3((n + 15) / 16), dim3(256), 0, stream,
                       x, n, Wq1, bq1, Wk1, bk1, Wv1, bv1, Ws1, bs1, qb16, kv16, sk16);
    hipLaunchKernelGGL((k_attn<1>), dim3(n), dim3(64), 0, stream,
                       qb16, kv16, rowptr, sep, uc, uc + HC, sk16, hb16,
                       Wfc, bfc, (float*)d_out, n);

    // ---- layer 2 (pure-bf16 MFMA GEMM; q/k/v/skip all bf16) ----
    hipLaunchKernelGGL(k_lin2, dim3((n + 63) / 64), dim3(256), 0, stream,
                       hb16, Bph, bq2, bk2, bv2, bs2, qb16, kv16, sk16, n);
    // ---- layer-2 attn with fused fc head ----
    hipLaunchKernelGGL((k_attn<0>), dim3(n), dim3(64), 0, stream,
                       qb16, kv16, rowptr, sep, uc + 2 * HC, uc + 3 * HC, sk16,
                       (unsigned short*)nullptr, Wfc, bfc, (float*)d_out, n);
}

// Round 18
// 190.177 us; speedup vs baseline: 1.4740x; 1.0044x over previous
//
#include <hip/hip_runtime.h>

// TemporalGNN: 2x TransformerConv(H=2, C=64) + edge encoder + fc head.
// Edge encoder rank-1 folded out of the edge loop: a=(q.k+ea*qu+qc)/8.
// Edge phase: counting-sort by dst; ONE WAVE PER BLOCK per dst node (indep
// retirement -> no intra-block load imbalance); 4 x 16-lane edge streams,
// dot2-bf16 QK, 2-deep gather prefetch over a 16-entry-padded (src,ea) int2
// array (no clamp bookkeeping). Sum-of-exp softmax (logits bounded, clamp 80).
// q/k/v/skip all packed bf16. Layer-2 linears: pure-bf16 MFMA GEMM, 64-node
// blocks, A in registers across the 4 col-quarter loop. fc fused in attn<0>.

#define HC 128   // H*C

typedef __attribute__((ext_vector_type(8))) short bf16x8;
typedef __attribute__((ext_vector_type(4))) float f32x4;
#if __has_builtin(__builtin_amdgcn_fdot2_f32_bf16)
typedef __attribute__((ext_vector_type(2))) __bf16 bf16x2;
#define HAS_DOT2 1
#else
#define HAS_DOT2 0
#endif

__device__ __forceinline__ unsigned bf16_rne(float f) {
    unsigned u = __float_as_uint(f);
    return (u + 0x7fffu + ((u >> 16) & 1u)) >> 16;
}
__device__ __forceinline__ float blo(unsigned u) { return __uint_as_float(u << 16); }
__device__ __forceinline__ float bhi(unsigned u) { return __uint_as_float(u & 0xffff0000u); }

// ---------- fused: rank-1 edge-encoder precompute + layer-2 weight pack ----------
// blocks 0..255: pack Wq2/Wk2/Wv2/Ws2 -> bf16 B^T [512][128]. block 256: uc.
__global__ __launch_bounds__(256) void k_prep(
    const float* __restrict__ We_enc, const float* __restrict__ be_enc,
    const float* __restrict__ We1, const float* __restrict__ We2,
    const float* __restrict__ Wq, const float* __restrict__ Wk,
    const float* __restrict__ Wv, const float* __restrict__ Ws,
    float* __restrict__ uc, unsigned short* __restrict__ Bph) {
    if (blockIdx.x == 256) {
        int c = threadIdx.x;
        if (c < 128) {
            float u1 = 0.f, c1 = 0.f, u2 = 0.f, c2 = 0.f;
            for (int j = 0; j < 64; ++j) {
                float we = We_enc[j], be = be_enc[j];
                float w1 = We1[j * HC + c], w2 = We2[j * HC + c];
                u1 += we * w1; c1 += be * w1;
                u2 += we * w2; c2 += be * w2;
            }
            uc[c] = u1; uc[HC + c] = c1; uc[2 * HC + c] = u2; uc[3 * HC + c] = c2;
        }
        return;
    }
    int t = blockIdx.x * 256 + threadIdx.x;   // 0..65535
    int nn = t >> 7;
    int kk = t & 127;
    int mat = nn >> 7, c = nn & 127;
    const float* W = (mat == 0) ? Wq : (mat == 1) ? Wk : (mat == 2) ? Wv : Ws;
    Bph[nn * 128 + kk] = (unsigned short)bf16_rne(W[kk * 128 + c]);
}

// ---------- CSR build (counting sort by dst; bucket order = atomic order) ----------
__global__ __launch_bounds__(256) void k_hist(const int* __restrict__ ei, int* __restrict__ deg, int E) {
    int t = blockIdx.x * blockDim.x + threadIdx.x;
    if (t < E) atomicAdd(&deg[ei[E + t]], 1);
}

__global__ __launch_bounds__(256) void k_scan1(const int* __restrict__ deg, int* __restrict__ bsum, int n) {
    int t = blockIdx.x * 256 + threadIdx.x;
    int v = (t < n) ? deg[t] : 0;
#pragma unroll
    for (int off = 1; off < 64; off <<= 1) v += __shfl_xor(v, off);
    __shared__ int wsum[4];
    int lane = threadIdx.x & 63, w = threadIdx.x >> 6;
    if (lane == 0) wsum[w] = v;
    __syncthreads();
    if (threadIdx.x == 0) bsum[blockIdx.x] = wsum[0] + wsum[1] + wsum[2] + wsum[3];
}

__global__ __launch_bounds__(256) void k_scan2(int* __restrict__ bsum, int nb) {
    __shared__ int sh[256];
    int t = threadIdx.x;
    int v = (t < nb) ? bsum[t] : 0;
    sh[t] = v;
    __syncthreads();
    for (int off = 1; off < 256; off <<= 1) {
        int x = (t >= off) ? sh[t - off] : 0;
        __syncthreads();
        sh[t] += x;
        __syncthreads();
    }
    if (t < nb) bsum[t] = sh[t] - v;   // exclusive
}

// scan3 also zeroes deg (reused as the scatter cursor).
__global__ __launch_bounds__(256) void k_scan3(int* __restrict__ deg, const int* __restrict__ bsum,
                                               int* __restrict__ rowptr, int n, int E) {
    int t = blockIdx.x * 256 + threadIdx.x;
    int tid = threadIdx.x;
    int v = (t < n) ? deg[t] : 0;
    __shared__ int sh[256];
    sh[tid] = v;
    __syncthreads();
    for (int off = 1; off < 256; off <<= 1) {
        int x = (tid >= off) ? sh[tid - off] : 0;
        __syncthreads();
        sh[tid] += x;
        __syncthreads();
    }
    if (t < n) { rowptr[t] = bsum[blockIdx.x] + sh[tid] - v; deg[t] = 0; }
    if (t == 0) rowptr[n] = E;
}

// fused scatter + gather: (src, ea) packed int2, written to bucket slots.
// Threads 0..15 also zero-fill the 16-entry pad so attn prefetch is unclamped.
__global__ __launch_bounds__(256) void k_scatter(
    const int* __restrict__ ei, const float* __restrict__ ea,
    const int* __restrict__ rowptr, int* __restrict__ cursor,
    int2* __restrict__ sep, int E) {
    int t = blockIdx.x * blockDim.x + threadIdx.x;
    if (t < 16 && blockIdx.x == 0) sep[E + t] = make_int2(0, 0);
    if (t >= E) return;
    int dst = ei[E + t];
    int pos = rowptr[dst] + atomicAdd(&cursor[dst], 1);
    sep[pos] = make_int2(ei[t], __float_as_int(ea[t]));
}

// ---------- layer-1 node linears (K=6, vector ALU) ----------
// q bf16, k/v bf16 interleaved, skip bf16.
__global__ __launch_bounds__(256) void k_lin6(
    const float* __restrict__ X, int n,
    const float* __restrict__ Wq, const float* __restrict__ bq,
    const float* __restrict__ Wk, const float* __restrict__ bk,
    const float* __restrict__ Wv, const float* __restrict__ bv,
    const float* __restrict__ Ws, const float* __restrict__ bs,
    unsigned short* __restrict__ q16, unsigned short* __restrict__ kv,
    unsigned short* __restrict__ sk) {
    __shared__ float xs[16][6];
    const int base = blockIdx.x * 16;
    const int tid = threadIdx.x;
    for (int i = tid; i < 16 * 6; i += 256) {
        int ni = base + i / 6;
        xs[i / 6][i % 6] = (ni < n) ? X[(size_t)ni * 6 + (i % 6)] : 0.f;
    }
    __syncthreads();
    const int c = tid & 127;
    const int m = tid >> 7;  // 0 -> (q,k), 1 -> (v,sk)
    const float* WA = m ? Wv : Wq;
    const float* WB = m ? Ws : Wk;
    float accA[16], accB[16];
#pragma unroll
    for (int i = 0; i < 16; ++i) { accA[i] = 0.f; accB[i] = 0.f; }
    for (int j = 0; j < 6; ++j) {
        float w0 = WA[j * HC + c];
        float w1 = WB[j * HC + c];
#pragma unroll
        for (int i = 0; i < 16; ++i) {
            float xv = xs[i][j];
            accA[i] += xv * w0;
            accB[i] += xv * w1;
        }
    }
    if (m == 0) {
        const float bA = bq[c], bB = bk[c];
#pragma unroll
        for (int i = 0; i < 16; ++i) {
            int ni = base + i;
            if (ni < n) {
                q16[(size_t)ni * HC + c] = (unsigned short)bf16_rne(accA[i] + bA);
                kv[(size_t)ni * 256 + c] = (unsigned short)bf16_rne(accB[i] + bB);
            }
        }
    } else {
        const float bA = bv[c], bB = bs[c];
#pragma unroll
        for (int i = 0; i < 16; ++i) {
            int ni = base + i;
            if (ni < n) {
                kv[(size_t)ni * 256 + 128 + c] = (unsigned short)bf16_rne(accA[i] + bA);
                sk[(size_t)ni * HC + c] = (unsigned short)bf16_rne(accB[i] + bB);
            }
        }
    }
}

// ---------- layer-2 node linears: pure-bf16 MFMA GEMM, LDS-staged B ----------
__global__ __launch_bounds__(256, 4) void k_lin2(
    const unsigned short* __restrict__ hb, const unsigned short* __restrict__ Bph,
    const float* __restrict__ bq, const float* __restrict__ bk,
    const float* __restrict__ bv, const float* __restrict__ bs,
    unsigned short* __restrict__ q16, unsigned short* __restrict__ kv,
    unsigned short* __restrict__ sk, int n) {
    __shared__ unsigned short Bs[128][128];   // 32 KB
    const int tid = threadIdx.x;
    const int wid = tid >> 6, l = tid & 63;
    const int la = l & 15, lk = l >> 4;
    const int mb = blockIdx.x * 64;
    int nodeA = mb + wid * 16 + la;
    if (nodeA >= n) nodeA = n - 1;
    const int sw = (la & 7) << 3;
    const int crow0 = mb + wid * 16 + lk * 4;

    bf16x8 areg[4];
#pragma unroll
    for (int ks = 0; ks < 4; ++ks)
        areg[ks] = *(const bf16x8*)&hb[(size_t)nodeA * 128 + lk * 8 + ks * 32];

    for (int cq = 0; cq < 4; ++cq) {
        if (cq) __syncthreads();
        for (int i = tid; i < 128 * 16; i += 256) {
            int kk8 = i & 15;
            int nnl = i >> 4;
            bf16x8 val = *(const bf16x8*)&Bph[((size_t)(cq * 128 + nnl)) * 128 + kk8 * 8];
            int swk = (kk8 ^ (nnl & 7)) * 8;
            *(bf16x8*)&Bs[nnl][swk] = val;
        }
        __syncthreads();

        f32x4 acc[8];
#pragma unroll
        for (int nt = 0; nt < 8; ++nt) acc[nt] = (f32x4){0.f, 0.f, 0.f, 0.f};
#pragma unroll
        for (int ks = 0; ks < 4; ++ks) {
            const int rk = (lk * 8 + ks * 32) ^ sw;
#pragma unroll
            for (int nt = 0; nt < 8; ++nt) {
                bf16x8 Bh = *(const bf16x8*)&Bs[nt * 16 + la][rk];
                acc[nt] = __builtin_amdgcn_mfma_f32_16x16x32_bf16(areg[ks], Bh, acc[nt], 0, 0, 0);
            }
        }
        const float* bias = (cq == 0) ? bq : (cq == 1) ? bk : (cq == 2) ? bv : bs;
#pragma unroll
        for (int nt = 0; nt < 8; ++nt) {
            const int col = nt * 16 + la;
            const float bb = bias[col];
            if (cq == 0 || cq == 3) {
                unsigned short* out = (cq == 0) ? q16 : sk;
#pragma unroll
                for (int j = 0; j < 4; ++j) {
                    int n0 = crow0 + j;
                    if (n0 < n) out[(size_t)n0 * 128 + col] = (unsigned short)bf16_rne(acc[nt][j] + bb);
                }
            } else {
                const int co = (cq == 1) ? col : 128 + col;
#pragma unroll
                for (int j = 0; j < 4; ++j) {
                    int n0 = crow0 + j;
                    if (n0 < n) kv[(size_t)n0 * 256 + co] = (unsigned short)bf16_rne(acc[nt][j] + bb);
                }
            }
        }
    }
}

// ---------- fused attention (sum-of-exp), ONE WAVE PER BLOCK per dst node ----------
// 4 x 16-lane edge streams; lane = 8 channels; 2-deep prefetch, no clamps
// (sep padded by 16). MODE 1: relu(attn+skip) -> bf16 h. MODE 0: fc fused.
template <int MODE>
__global__ __launch_bounds__(64) void k_attn(
    const unsigned short* __restrict__ q16, const unsigned short* __restrict__ kvp,
    const int* __restrict__ rowptr, const int2* __restrict__ sep,
    const float* __restrict__ ucu, const float* __restrict__ ucc,
    const unsigned short* __restrict__ io, unsigned short* __restrict__ hb,
    const float* __restrict__ Wfc, const float* __restrict__ bfc,
    float* __restrict__ out, int n) {
    int wid = blockIdx.x;
    int lane = threadIdx.x & 63;
    if (wid >= n) return;
    const int grp = lane >> 4;          // 0..3 edge stream
    const int hl = lane & 15;
    const int ch = hl * 8;

    uint4 qp = *(const uint4*)&q16[(size_t)wid * 128 + ch];   // 8 bf16
    float qu, qc;
    {
        float qf0 = blo(qp.x), qf1 = bhi(qp.x), qf2 = blo(qp.y), qf3 = bhi(qp.y);
        float qf4 = blo(qp.z), qf5 = bhi(qp.z), qf6 = blo(qp.w), qf7 = bhi(qp.w);
        float4 uA = *(const float4*)&ucu[ch], uB = *(const float4*)&ucu[ch + 4];
        float4 cA = *(const float4*)&ucc[ch], cB = *(const float4*)&ucc[ch + 4];
        qu = qf0 * uA.x + qf1 * uA.y + qf2 * uA.z + qf3 * uA.w
           + qf4 * uB.x + qf5 * uB.y + qf6 * uB.z + qf7 * uB.w;
        qc = qf0 * cA.x + qf1 * cA.y + qf2 * cA.z + qf3 * cA.w
           + qf4 * cB.x + qf5 * cB.y + qf6 * cB.z + qf7 * cB.w;
#pragma unroll
        for (int off = 1; off < 8; off <<= 1) {
            qu += __shfl_xor(qu, off);
            qc += __shfl_xor(qc, off);
        }
    }

    int b = rowptr[wid], e = rowptr[wid + 1];
    float s = 0.f, sea = 0.f;
    float av0 = 0.f, av1 = 0.f, av2 = 0.f, av3 = 0.f;
    float av4 = 0.f, av5 = 0.f, av6 = 0.f, av7 = 0.f;

    if (b < e) {
        // 2-deep pipeline, unclamped indices (sep padded by 16 entries)
        int p0 = b + grp;      bool v0 = p0 < e;
        int p1 = p0 + 4;       bool v1 = p1 < e;
        int2 se0 = sep[p0];
        int2 se1 = sep[p1];
        const unsigned short* r0p = &kvp[(size_t)se0.x * 256 + ch];
        const unsigned short* r1p = &kvp[(size_t)se1.x * 256 + ch];
        uint4 ku0 = *(const uint4*)r0p, vu0 = *(const uint4*)(r0p + 128);
        uint4 ku1 = *(const uint4*)r1p, vu1 = *(const uint4*)(r1p + 128);
        for (int p = b; p < e; p += 4) {
            int p2 = p + 8 + grp;
            bool v2 = p2 < e;
            int2 se2 = sep[p2];
            const unsigned short* r2p = &kvp[(size_t)se2.x * 256 + ch];
            uint4 ku2 = *(const uint4*)r2p, vu2 = *(const uint4*)(r2p + 128);

            float ea0 = __int_as_float(se0.y);
            float d;
#if HAS_DOT2
            d = __builtin_amdgcn_fdot2_f32_bf16(
                    __builtin_bit_cast(bf16x2, ku0.x), __builtin_bit_cast(bf16x2, qp.x),
                __builtin_amdgcn_fdot2_f32_bf16(
                    __builtin_bit_cast(bf16x2, ku0.y), __builtin_bit_cast(bf16x2, qp.y),
                __builtin_amdgcn_fdot2_f32_bf16(
                    __builtin_bit_cast(bf16x2, ku0.z), __builtin_bit_cast(bf16x2, qp.z),
                __builtin_amdgcn_fdot2_f32_bf16(
                    __builtin_bit_cast(bf16x2, ku0.w), __builtin_bit_cast(bf16x2, qp.w),
                    0.f, false), false), false), false);
#else
            d = blo(qp.x) * blo(ku0.x) + bhi(qp.x) * bhi(ku0.x)
              + blo(qp.y) * blo(ku0.y) + bhi(qp.y) * bhi(ku0.y)
              + blo(qp.z) * blo(ku0.z) + bhi(qp.z) * bhi(ku0.z)
              + blo(qp.w) * blo(ku0.w) + bhi(qp.w) * bhi(ku0.w);
#endif
            d += __shfl_xor(d, 1); d += __shfl_xor(d, 2); d += __shfl_xor(d, 4);
            float a = v0 ? fminf((d + fmaf(ea0, qu, qc)) * 0.125f, 80.f) : -INFINITY;
            float pw = __expf(a);      // exp(-inf) = 0 for invalid lanes
            s += pw;
            sea = fmaf(pw, ea0, sea);
            av0 = fmaf(pw, blo(vu0.x), av0);
            av1 = fmaf(pw, bhi(vu0.x), av1);
            av2 = fmaf(pw, blo(vu0.y), av2);
            av3 = fmaf(pw, bhi(vu0.y), av3);
            av4 = fmaf(pw, blo(vu0.z), av4);
            av5 = fmaf(pw, bhi(vu0.z), av5);
            av6 = fmaf(pw, blo(vu0.w), av6);
            av7 = fmaf(pw, bhi(vu0.w), av7);
            ku0 = ku1; vu0 = vu1; se0 = se1; v0 = v1;
            ku1 = ku2; vu1 = vu2; se1 = se2; v1 = v2;
        }
    }

    // merge streams: plain sums over xor 16 then xor 32
#pragma unroll
    for (int M = 16; M <= 32; M <<= 1) {
        s += __shfl_xor(s, M);
        sea += __shfl_xor(sea, M);
        av0 += __shfl_xor(av0, M); av1 += __shfl_xor(av1, M);
        av2 += __shfl_xor(av2, M); av3 += __shfl_xor(av3, M);
        av4 += __shfl_xor(av4, M); av5 += __shfl_xor(av5, M);
        av6 += __shfl_xor(av6, M); av7 += __shfl_xor(av7, M);
    }

    float4 uuA = *(const float4*)&ucu[ch], uuB = *(const float4*)&ucu[ch + 4];
    float4 ccA = *(const float4*)&ucc[ch], ccB = *(const float4*)&ucc[ch + 4];
    float inv = 1.f / (s + 1e-16f);
    uint4 skp = *(const uint4*)&io[(size_t)wid * 128 + ch];
    float r0 = fmaxf((av0 + uuA.x * sea + ccA.x * s) * inv + blo(skp.x), 0.f);
    float r1 = fmaxf((av1 + uuA.y * sea + ccA.y * s) * inv + bhi(skp.x), 0.f);
    float r2 = fmaxf((av2 + uuA.z * sea + ccA.z * s) * inv + blo(skp.y), 0.f);
    float r3 = fmaxf((av3 + uuA.w * sea + ccA.w * s) * inv + bhi(skp.y), 0.f);
    float r4 = fmaxf((av4 + uuB.x * sea + ccB.x * s) * inv + blo(skp.z), 0.f);
    float r5 = fmaxf((av5 + uuB.y * sea + ccB.y * s) * inv + bhi(skp.z), 0.f);
    float r6 = fmaxf((av6 + uuB.z * sea + ccB.z * s) * inv + blo(skp.w), 0.f);
    float r7 = fmaxf((av7 + uuB.w * sea + ccB.w * s) * inv + bhi(skp.w), 0.f);

    if (MODE == 1) {
        if (grp == 0) {
            uint4 hv;
            hv.x = bf16_rne(r0) | (bf16_rne(r1) << 16);
            hv.y = bf16_rne(r2) | (bf16_rne(r3) << 16);
            hv.z = bf16_rne(r4) | (bf16_rne(r5) << 16);
            hv.w = bf16_rne(r6) | (bf16_rne(r7) << 16);
            *(uint4*)&hb[(size_t)wid * 128 + ch] = hv;
        }
    } else {
        float4 wfA = *(const float4*)&Wfc[ch];
        float4 wfB = *(const float4*)&Wfc[ch + 4];
        float rr = r0 * wfA.x + r1 * wfA.y + r2 * wfA.z + r3 * wfA.w
                 + r4 * wfB.x + r5 * wfB.y + r6 * wfB.z + r7 * wfB.w;
#pragma unroll
        for (int off = 1; off < 16; off <<= 1) rr += __shfl_xor(rr, off);
        if (lane == 0) out[wid] = rr + bfc[0];
    }
}

extern "C" void kernel_launch(void* const* d_in, const int* in_sizes, int n_in,
                              void* d_out, int out_size, void* d_ws, size_t ws_size,
                              hipStream_t stream) {
    const float* x      = (const float*)d_in[0];
    const int*   ei     = (const int*)d_in[1];
    const float* ea     = (const float*)d_in[2];
    const float* We_enc = (const float*)d_in[3];
    const float* be_enc = (const float*)d_in[4];
    const float* Wq1 = (const float*)d_in[5],  *bq1 = (const float*)d_in[6];
    const float* Wk1 = (const float*)d_in[7],  *bk1 = (const float*)d_in[8];
    const float* Wv1 = (const float*)d_in[9],  *bv1 = (const float*)d_in[10];
    const float* We1 = (const float*)d_in[11];
    const float* Ws1 = (const float*)d_in[12], *bs1 = (const float*)d_in[13];
    const float* Wq2 = (const float*)d_in[14], *bq2 = (const float*)d_in[15];
    const float* Wk2 = (const float*)d_in[16], *bk2 = (const float*)d_in[17];
    const float* Wv2 = (const float*)d_in[18], *bv2 = (const float*)d_in[19];
    const float* We2 = (const float*)d_in[20];
    const float* Ws2 = (const float*)d_in[21], *bs2 = (const float*)d_in[22];
    const float* Wfc = (const float*)d_in[23], *bfc = (const float*)d_in[24];

    const int n = in_sizes[0] / 6;   // 50000
    const int E = in_sizes[2];       // 409600

    float* ws = (float*)d_ws;
    size_t off = 0;
    unsigned short* qb16 = (unsigned short*)(ws + off); off += (size_t)n * HC / 2;  // q bf16
    unsigned short* sk16 = (unsigned short*)(ws + off); off += (size_t)n * HC / 2;  // skip bf16
    unsigned short* kv16 = (unsigned short*)(ws + off); off += (size_t)n * HC;      // k|v bf16
    int* rowptr = (int*)(ws + off); off += (size_t)(n + 1);
    int* deg    = (int*)(ws + off); off += (size_t)n;   // also scatter cursor
    int* bsum   = (int*)(ws + off); off += 256;
    int2* sep   = (int2*)(ws + off); off += 2 * ((size_t)E + 16);   // (src, ea) packed, +16 pad
    float* uc   = ws + off; off += 512;
    unsigned short* hb16 = (unsigned short*)(ws + off); off += (size_t)n * HC / 2;  // h bf16
    unsigned short* Bph = (unsigned short*)(ws + off); off += 512 * 128 / 2;

    const int eb = (E + 255) / 256;
    const int nb = (n + 255) / 256;

    hipLaunchKernelGGL(k_prep, dim3(257), dim3(256), 0, stream,
                       We_enc, be_enc, We1, We2, Wq2, Wk2, Wv2, Ws2, uc, Bph);

    // ---- CSR build (shared by both layers) ----
    hipMemsetAsync(deg, 0, (size_t)n * sizeof(int), stream);
    hipLaunchKernelGGL(k_hist, dim3(eb), dim3(256), 0, stream, ei, deg, E);
    hipLaunchKernelGGL(k_scan1, dim3(nb), dim3(256), 0, stream, deg, bsum, n);
    hipLaunchKernelGGL(k_scan2, dim3(1), dim3(256), 0, stream, bsum, nb);
    hipLaunchKernelGGL(k_scan3, dim3(nb), dim3(256), 0, stream, deg, bsum, rowptr, n, E);
    hipLaunchKernelGGL(k_scatter, dim3(eb), dim3(256), 0, stream, ei, ea, rowptr, deg, sep, E);

    // ---- layer 1 ----
    hipLaunchKernelGGL(k_lin6, dim3((n + 15) / 16), dim3(256), 0, stream,
                       x, n, Wq1, bq1, Wk1, bk1, Wv1, bv1, Ws1, bs1, qb16, kv16, sk16);
    hipLaunchKernelGGL((k_attn<1>), dim3(n), dim3(64), 0, stream,
                       qb16, kv16, rowptr, sep, uc, uc + HC, sk16, hb16,
                       Wfc, bfc, (float*)d_out, n);

    // ---- layer 2 (pure-bf16 MFMA GEMM; q/k/v/skip all bf16) ----
    hipLaunchKernelGGL(k_lin2, dim3((n + 63) / 64), dim3(256), 0, stream,
                       hb16, Bph, bq2, bk2, bv2, bs2, qb16, kv16, sk16, n);
    // ---- layer-2 attn with fused fc head ----
    hipLaunchKernelGGL((k_attn<0>), dim3(n), dim3(64), 0, stream,
                       qb16, kv16, rowptr, sep, uc + 2 * HC, uc + 3 * HC, sk16,
                       (unsigned short*)nullptr, Wfc, bfc, (float*)d_out, n);
}